// Round 9
// baseline (388.274 us; speedup 1.0000x reference)
//
#include <hip/hip_runtime.h>
#include <math.h>

// Dims: B=2, N=4096, C=256, nc=150, T=4, TN=16384, heads=8, hd=32, hid=1024, H=W=64

typedef __attribute__((ext_vector_type(8))) short bf16x8;
typedef __attribute__((ext_vector_type(4))) short bf16x4;
typedef __attribute__((ext_vector_type(4))) float f32x4;

__device__ __forceinline__ short f2b(float f) {
  union { float f; unsigned int u; } c; c.f = f;
  unsigned int r = (c.u + 0x7fffu + ((c.u >> 16) & 1u)) >> 16;
  return (short)r;
}

// ---------------- block reduction helpers (blockDim.x == 256) ----------------
__device__ __forceinline__ float bred_sum(float v, float* red) {
  int tid = threadIdx.x;
  red[tid] = v; __syncthreads();
  #pragma unroll
  for (int s = 128; s > 0; s >>= 1) {
    if (tid < s) red[tid] += red[tid + s];
    __syncthreads();
  }
  float r = red[0]; __syncthreads();
  return r;
}

// ---------------- bf16 MFMA GEMM, 64x64 tile: out[m][n] = alpha*(A@W^T + bias) ----------------
// grid (M/64, N/64); 4 waves: wm=row-half(32), wn=col-half(32), 2x2 16x16 frags each.
__global__ __launch_bounds__(256) void gemm_mfma(
    const float* __restrict__ A, const float* __restrict__ W,
    const float* __restrict__ bias, float* __restrict__ out,
    int M, int N, int K, float alpha)
{
  __shared__ __align__(16) short As[64 * 72];
  __shared__ __align__(16) short Bs[64 * 72];
  const int tid = threadIdx.x;
  const int m0 = blockIdx.x * 64;
  const int n0 = blockIdx.y * 64;
  const int wave = tid >> 6;
  const int lane = tid & 63;
  const int wm = wave & 1, wn = wave >> 1;
  const int t16 = lane & 15;
  const int k8 = (lane >> 4) * 8;

  f32x4 acc[2][2];
  #pragma unroll
  for (int i = 0; i < 2; ++i)
    #pragma unroll
    for (int j = 0; j < 2; ++j)
      acc[i][j] = (f32x4){0.f, 0.f, 0.f, 0.f};

  const int sr = tid >> 2;
  const int sk = (tid & 3) * 16;

  for (int k0 = 0; k0 < K; k0 += 64) {
    {
      const float* ap = &A[(size_t)(m0 + sr) * K + k0 + sk];
      float4 v0 = *(const float4*)&ap[0];
      float4 v1 = *(const float4*)&ap[4];
      float4 v2 = *(const float4*)&ap[8];
      float4 v3 = *(const float4*)&ap[12];
      bf16x8 w0, w1;
      w0[0] = f2b(v0.x); w0[1] = f2b(v0.y); w0[2] = f2b(v0.z); w0[3] = f2b(v0.w);
      w0[4] = f2b(v1.x); w0[5] = f2b(v1.y); w0[6] = f2b(v1.z); w0[7] = f2b(v1.w);
      w1[0] = f2b(v2.x); w1[1] = f2b(v2.y); w1[2] = f2b(v2.z); w1[3] = f2b(v2.w);
      w1[4] = f2b(v3.x); w1[5] = f2b(v3.y); w1[6] = f2b(v3.z); w1[7] = f2b(v3.w);
      *(bf16x8*)&As[sr * 72 + sk] = w0;
      *(bf16x8*)&As[sr * 72 + sk + 8] = w1;
    }
    {
      const float* wp = &W[(size_t)(n0 + sr) * K + k0 + sk];
      float4 v0 = *(const float4*)&wp[0];
      float4 v1 = *(const float4*)&wp[4];
      float4 v2 = *(const float4*)&wp[8];
      float4 v3 = *(const float4*)&wp[12];
      bf16x8 w0, w1;
      w0[0] = f2b(v0.x); w0[1] = f2b(v0.y); w0[2] = f2b(v0.z); w0[3] = f2b(v0.w);
      w0[4] = f2b(v1.x); w0[5] = f2b(v1.y); w0[6] = f2b(v1.z); w0[7] = f2b(v1.w);
      w1[0] = f2b(v2.x); w1[1] = f2b(v2.y); w1[2] = f2b(v2.z); w1[3] = f2b(v2.w);
      w1[4] = f2b(v3.x); w1[5] = f2b(v3.y); w1[6] = f2b(v3.z); w1[7] = f2b(v3.w);
      *(bf16x8*)&Bs[sr * 72 + sk] = w0;
      *(bf16x8*)&Bs[sr * 72 + sk + 8] = w1;
    }
    __syncthreads();
    #pragma unroll
    for (int ks = 0; ks < 2; ++ks) {
      const int kofs = ks * 32 + k8;
      bf16x8 af0 = *(const bf16x8*)&As[(wm * 32 +  0 + t16) * 72 + kofs];
      bf16x8 af1 = *(const bf16x8*)&As[(wm * 32 + 16 + t16) * 72 + kofs];
      bf16x8 bf0 = *(const bf16x8*)&Bs[(wn * 32 +  0 + t16) * 72 + kofs];
      bf16x8 bf1 = *(const bf16x8*)&Bs[(wn * 32 + 16 + t16) * 72 + kofs];
      acc[0][0] = __builtin_amdgcn_mfma_f32_16x16x32_bf16(af0, bf0, acc[0][0], 0, 0, 0);
      acc[1][0] = __builtin_amdgcn_mfma_f32_16x16x32_bf16(af1, bf0, acc[1][0], 0, 0, 0);
      acc[0][1] = __builtin_amdgcn_mfma_f32_16x16x32_bf16(af0, bf1, acc[0][1], 0, 0, 0);
      acc[1][1] = __builtin_amdgcn_mfma_f32_16x16x32_bf16(af1, bf1, acc[1][1], 0, 0, 0);
    }
    __syncthreads();
  }
  const int r4 = (lane >> 4) * 4;
  #pragma unroll
  for (int ni = 0; ni < 2; ++ni) {
    const int gcol = n0 + wn * 32 + ni * 16 + t16;
    const float bb = bias[gcol];
    #pragma unroll
    for (int mi = 0; mi < 2; ++mi) {
      #pragma unroll
      for (int r = 0; r < 4; ++r) {
        const int gm = m0 + wm * 32 + mi * 16 + r4 + r;
        out[(size_t)gm * N + gcol] = alpha * (acc[mi][ni][r] + bb);
      }
    }
  }
}

// ---------------- fp32-A MFMA GEMM, bf16 OUT (q-proj: consumer rounds anyway) ----------------
__global__ __launch_bounds__(256) void gemm_mfma_bfout(
    const float* __restrict__ A, const float* __restrict__ W,
    const float* __restrict__ bias, short* __restrict__ out,
    int M, int N, int K, float alpha)
{
  __shared__ __align__(16) short As[64 * 72];
  __shared__ __align__(16) short Bs[64 * 72];
  const int tid = threadIdx.x;
  const int m0 = blockIdx.x * 64;
  const int n0 = blockIdx.y * 64;
  const int wave = tid >> 6;
  const int lane = tid & 63;
  const int wm = wave & 1, wn = wave >> 1;
  const int t16 = lane & 15;
  const int k8 = (lane >> 4) * 8;

  f32x4 acc[2][2];
  #pragma unroll
  for (int i = 0; i < 2; ++i)
    #pragma unroll
    for (int j = 0; j < 2; ++j)
      acc[i][j] = (f32x4){0.f, 0.f, 0.f, 0.f};

  const int sr = tid >> 2;
  const int sk = (tid & 3) * 16;

  for (int k0 = 0; k0 < K; k0 += 64) {
    {
      const float* ap = &A[(size_t)(m0 + sr) * K + k0 + sk];
      float4 v0 = *(const float4*)&ap[0];
      float4 v1 = *(const float4*)&ap[4];
      float4 v2 = *(const float4*)&ap[8];
      float4 v3 = *(const float4*)&ap[12];
      bf16x8 w0, w1;
      w0[0] = f2b(v0.x); w0[1] = f2b(v0.y); w0[2] = f2b(v0.z); w0[3] = f2b(v0.w);
      w0[4] = f2b(v1.x); w0[5] = f2b(v1.y); w0[6] = f2b(v1.z); w0[7] = f2b(v1.w);
      w1[0] = f2b(v2.x); w1[1] = f2b(v2.y); w1[2] = f2b(v2.z); w1[3] = f2b(v2.w);
      w1[4] = f2b(v3.x); w1[5] = f2b(v3.y); w1[6] = f2b(v3.z); w1[7] = f2b(v3.w);
      *(bf16x8*)&As[sr * 72 + sk] = w0;
      *(bf16x8*)&As[sr * 72 + sk + 8] = w1;
    }
    {
      const float* wp = &W[(size_t)(n0 + sr) * K + k0 + sk];
      float4 v0 = *(const float4*)&wp[0];
      float4 v1 = *(const float4*)&wp[4];
      float4 v2 = *(const float4*)&wp[8];
      float4 v3 = *(const float4*)&wp[12];
      bf16x8 w0, w1;
      w0[0] = f2b(v0.x); w0[1] = f2b(v0.y); w0[2] = f2b(v0.z); w0[3] = f2b(v0.w);
      w0[4] = f2b(v1.x); w0[5] = f2b(v1.y); w0[6] = f2b(v1.z); w0[7] = f2b(v1.w);
      w1[0] = f2b(v2.x); w1[1] = f2b(v2.y); w1[2] = f2b(v2.z); w1[3] = f2b(v2.w);
      w1[4] = f2b(v3.x); w1[5] = f2b(v3.y); w1[6] = f2b(v3.z); w1[7] = f2b(v3.w);
      *(bf16x8*)&Bs[sr * 72 + sk] = w0;
      *(bf16x8*)&Bs[sr * 72 + sk + 8] = w1;
    }
    __syncthreads();
    #pragma unroll
    for (int ks = 0; ks < 2; ++ks) {
      const int kofs = ks * 32 + k8;
      bf16x8 af0 = *(const bf16x8*)&As[(wm * 32 +  0 + t16) * 72 + kofs];
      bf16x8 af1 = *(const bf16x8*)&As[(wm * 32 + 16 + t16) * 72 + kofs];
      bf16x8 bf0 = *(const bf16x8*)&Bs[(wn * 32 +  0 + t16) * 72 + kofs];
      bf16x8 bf1 = *(const bf16x8*)&Bs[(wn * 32 + 16 + t16) * 72 + kofs];
      acc[0][0] = __builtin_amdgcn_mfma_f32_16x16x32_bf16(af0, bf0, acc[0][0], 0, 0, 0);
      acc[1][0] = __builtin_amdgcn_mfma_f32_16x16x32_bf16(af1, bf0, acc[1][0], 0, 0, 0);
      acc[0][1] = __builtin_amdgcn_mfma_f32_16x16x32_bf16(af0, bf1, acc[0][1], 0, 0, 0);
      acc[1][1] = __builtin_amdgcn_mfma_f32_16x16x32_bf16(af1, bf1, acc[1][1], 0, 0, 0);
    }
    __syncthreads();
  }
  const int r4 = (lane >> 4) * 4;
  #pragma unroll
  for (int ni = 0; ni < 2; ++ni) {
    const int gcol = n0 + wn * 32 + ni * 16 + t16;
    const float bb = bias[gcol];
    #pragma unroll
    for (int mi = 0; mi < 2; ++mi) {
      #pragma unroll
      for (int r = 0; r < 4; ++r) {
        const int gm = m0 + wm * 32 + mi * 16 + r4 + r;
        out[(size_t)gm * N + gcol] = f2b(alpha * (acc[mi][ni][r] + bb));
      }
    }
  }
}

// ---------------- bf16-A MFMA GEMM, 64x64 tile (proj/fc2: A pre-rounded bf16) ----------------
__global__ __launch_bounds__(256) void gemm_mfma_bfA(
    const short* __restrict__ A, const float* __restrict__ W,
    const float* __restrict__ bias, float* __restrict__ out,
    int M, int N, int K, float alpha)
{
  __shared__ __align__(16) short As[64 * 72];
  __shared__ __align__(16) short Bs[64 * 72];
  const int tid = threadIdx.x;
  const int m0 = blockIdx.x * 64;
  const int n0 = blockIdx.y * 64;
  const int wave = tid >> 6;
  const int lane = tid & 63;
  const int wm = wave & 1, wn = wave >> 1;
  const int t16 = lane & 15;
  const int k8 = (lane >> 4) * 8;

  f32x4 acc[2][2];
  #pragma unroll
  for (int i = 0; i < 2; ++i)
    #pragma unroll
    for (int j = 0; j < 2; ++j)
      acc[i][j] = (f32x4){0.f, 0.f, 0.f, 0.f};

  const int sr = tid >> 2;
  const int sk = (tid & 3) * 16;

  for (int k0 = 0; k0 < K; k0 += 64) {
    {
      const short* ap = &A[(size_t)(m0 + sr) * K + k0 + sk];
      *(bf16x8*)&As[sr * 72 + sk] = *(const bf16x8*)&ap[0];
      *(bf16x8*)&As[sr * 72 + sk + 8] = *(const bf16x8*)&ap[8];
    }
    {
      const float* wp = &W[(size_t)(n0 + sr) * K + k0 + sk];
      float4 v0 = *(const float4*)&wp[0];
      float4 v1 = *(const float4*)&wp[4];
      float4 v2 = *(const float4*)&wp[8];
      float4 v3 = *(const float4*)&wp[12];
      bf16x8 w0, w1;
      w0[0] = f2b(v0.x); w0[1] = f2b(v0.y); w0[2] = f2b(v0.z); w0[3] = f2b(v0.w);
      w0[4] = f2b(v1.x); w0[5] = f2b(v1.y); w0[6] = f2b(v1.z); w0[7] = f2b(v1.w);
      w1[0] = f2b(v2.x); w1[1] = f2b(v2.y); w1[2] = f2b(v2.z); w1[3] = f2b(v2.w);
      w1[4] = f2b(v3.x); w1[5] = f2b(v3.y); w1[6] = f2b(v3.z); w1[7] = f2b(v3.w);
      *(bf16x8*)&Bs[sr * 72 + sk] = w0;
      *(bf16x8*)&Bs[sr * 72 + sk + 8] = w1;
    }
    __syncthreads();
    #pragma unroll
    for (int ks = 0; ks < 2; ++ks) {
      const int kofs = ks * 32 + k8;
      bf16x8 af0 = *(const bf16x8*)&As[(wm * 32 +  0 + t16) * 72 + kofs];
      bf16x8 af1 = *(const bf16x8*)&As[(wm * 32 + 16 + t16) * 72 + kofs];
      bf16x8 bf0 = *(const bf16x8*)&Bs[(wn * 32 +  0 + t16) * 72 + kofs];
      bf16x8 bf1 = *(const bf16x8*)&Bs[(wn * 32 + 16 + t16) * 72 + kofs];
      acc[0][0] = __builtin_amdgcn_mfma_f32_16x16x32_bf16(af0, bf0, acc[0][0], 0, 0, 0);
      acc[1][0] = __builtin_amdgcn_mfma_f32_16x16x32_bf16(af1, bf0, acc[1][0], 0, 0, 0);
      acc[0][1] = __builtin_amdgcn_mfma_f32_16x16x32_bf16(af0, bf1, acc[0][1], 0, 0, 0);
      acc[1][1] = __builtin_amdgcn_mfma_f32_16x16x32_bf16(af1, bf1, acc[1][1], 0, 0, 0);
    }
    __syncthreads();
  }
  const int r4 = (lane >> 4) * 4;
  #pragma unroll
  for (int ni = 0; ni < 2; ++ni) {
    const int gcol = n0 + wn * 32 + ni * 16 + t16;
    const float bb = bias[gcol];
    #pragma unroll
    for (int mi = 0; mi < 2; ++mi) {
      #pragma unroll
      for (int r = 0; r < 4; ++r) {
        const int gm = m0 + wm * 32 + mi * 16 + r4 + r;
        out[(size_t)gm * N + gcol] = alpha * (acc[mi][ni][r] + bb);
      }
    }
  }
}

// ---------------- prep: cwb[160][256] bf16, TT[160][320] bf16, wt[tap][1024] ----------------
// TT[kc][kk] = kk<150 ? tdt2[kk][kc] : (160<=kk<310 ? tdt1[kk-160][kc] : 0), kc<150 else 0
__global__ __launch_bounds__(256) void prep_bt(
    const float* __restrict__ cw, const float* __restrict__ tdt2, const float* __restrict__ tdt1,
    const float* __restrict__ dww,
    short* __restrict__ cwb, short* __restrict__ TT, float* __restrict__ wt)
{
  int idx = blockIdx.x * 256 + threadIdx.x;   // grid 200*256 = 51200
  if (idx < 160 * 256) {
    int kc = idx >> 8, k = idx & 255;
    float v = (kc < 150) ? cw[kc * 256 + k] : 0.f;
    cwb[idx] = f2b(v);
  }
  if (idx < 160 * 320) {
    int kc = idx / 320, kk = idx - kc * 320;
    float t = 0.f;
    if (kc < 150) {
      if (kk < 150) t = tdt2[kk * 150 + kc];
      else if (kk >= 160 && kk < 310) t = tdt1[(kk - 160) * 150 + kc];
    }
    TT[idx] = f2b(t);
  }
  if (idx < 9216) {
    int ch = idx / 9, tap = idx - ch * 9;
    wt[tap * 1024 + ch] = dww[idx];
  }
}

// ---------------- xf transpose to bf16: xfT[bt][c][n] (8 x 256 x 4096) ----------------
__global__ __launch_bounds__(256) void xf_t(
    const float* __restrict__ x, const float* __restrict__ mem, short* __restrict__ xfT)
{
  __shared__ float tile[64][257];
  const int bt = blockIdx.y;
  const int n0 = blockIdx.x * 64;
  const int b = bt >> 2, ti = bt & 3;
  const float* xf = (ti < 3) ? (mem + (size_t)(b * 3 + ti) * 4096 * 256)
                             : (x + (size_t)b * 4096 * 256);
  const int tid = threadIdx.x;
  const int r = tid >> 2, cofs = (tid & 3) * 64;
  const float* src = xf + (size_t)(n0 + r) * 256 + cofs;
  #pragma unroll
  for (int i = 0; i < 16; ++i) {
    float4 v = *(const float4*)&src[i * 4];
    tile[r][cofs + i * 4 + 0] = v.x;
    tile[r][cofs + i * 4 + 1] = v.y;
    tile[r][cofs + i * 4 + 2] = v.z;
    tile[r][cofs + i * 4 + 3] = v.w;
  }
  __syncthreads();
  short* dst = xfT + ((size_t)bt * 256 + tid) * 4096 + n0;
  #pragma unroll
  for (int seg = 0; seg < 8; ++seg) {
    bf16x8 w;
    #pragma unroll
    for (int j = 0; j < 8; ++j) w[j] = f2b(tile[seg * 8 + j][tid]);
    *(bf16x8*)&dst[seg * 8] = w;
  }
}

// ---------------- fused cluster front-end: cl GEMM + cosines + csz GEMM, LDS-only Acat ----------------
// Block = 64 flat rows (b,ti,nn). Phase A: cl = xf @ cwb^T (+coscl fold) -> Acatile[:,0:160].
// Phase B: z columns in regs (+cosz fold) -> Acatile[:,160:320]. Phase C: O = 0.5*Acatile@TT^T.
__global__ __launch_bounds__(256) void fused_csz(
    const float* __restrict__ x, const float* __restrict__ mem, const float* __restrict__ z,
    const short* __restrict__ cwb, const short* __restrict__ TT,
    const float* __restrict__ p1, const float* __restrict__ p2,
    float* __restrict__ csz, float* __restrict__ asg)
{
  __shared__ __align__(16) short Acatile[64 * 328];
  __shared__ float p1s[160], p2s[160];
  __shared__ float sred[4][16][9];
  __shared__ float czs[64];
  const int tid = threadIdx.x;
  const int r0 = blockIdx.x * 64;
  const int b = r0 >> 14;
  const int mmg = r0 & 16383;
  const int ti = mmg >> 12, nn = mmg & 4095;
  const float* Ab = ((ti < 3) ? (mem + (size_t)(b * 3 + ti) * 4096 * 256)
                              : (x + (size_t)b * 4096 * 256)) + (size_t)nn * 256;
  const int wave = tid >> 6, lane = tid & 63;
  const int t16 = lane & 15, quad = lane >> 4, k8 = quad * 8;

  // ---- z loads into regs first (HBM stream overlaps phase A MFMA) ----
  const int kr = tid >> 4, c4 = (tid & 15) * 4;
  float4 zv[10];
  #pragma unroll
  for (int it = 0; it < 10; ++it) {
    const int k = it * 16 + kr;
    zv[it] = make_float4(0.f, 0.f, 0.f, 0.f);
    if (k < 150) zv[it] = *(const float4*)&z[((size_t)b * 150 + k) * 16384 + mmg + c4];
  }
  if (tid < 160) {
    p2s[tid] = (tid < 150) ? p2[tid] : 0.f;
    p1s[tid] = (tid < 150) ? p1[tid] : 0.f;
  }

  // ---- phase A: cl GEMM (each wave: 16 rows x 160 cols, K=256) ----
  f32x4 acc[10];
  #pragma unroll
  for (int i = 0; i < 10; ++i) acc[i] = (f32x4){0.f, 0.f, 0.f, 0.f};
  {
    const float* ap = Ab + (size_t)(wave * 16 + t16) * 256 + k8;
    const short* bp = cwb + t16 * 256 + k8;
    #pragma unroll 2
    for (int ks = 0; ks < 8; ++ks) {
      float4 v0 = *(const float4*)&ap[ks * 32];
      float4 v1 = *(const float4*)&ap[ks * 32 + 4];
      bf16x8 a;
      a[0] = f2b(v0.x); a[1] = f2b(v0.y); a[2] = f2b(v0.z); a[3] = f2b(v0.w);
      a[4] = f2b(v1.x); a[5] = f2b(v1.y); a[6] = f2b(v1.z); a[7] = f2b(v1.w);
      #pragma unroll
      for (int nf = 0; nf < 10; ++nf) {
        bf16x8 bv = *(const bf16x8*)&bp[nf * 4096 + ks * 32];
        acc[nf] = __builtin_amdgcn_mfma_f32_16x16x32_bf16(a, bv, acc[nf], 0, 0, 0);
      }
    }
  }
  __syncthreads();   // p1s/p2s visible

  // ---- phase A cosine (per row, over 160 cols; padded cols are exact zeros) ----
  {
    float d[4] = {0.f, 0.f, 0.f, 0.f}, s[4] = {0.f, 0.f, 0.f, 0.f};
    float pn = 0.f;
    #pragma unroll
    for (int nf = 0; nf < 10; ++nf) {
      float a2 = p2s[nf * 16 + t16];
      pn += a2 * a2;
      #pragma unroll
      for (int r = 0; r < 4; ++r) {
        float v = acc[nf][r];
        d[r] = fmaf(v, a2, d[r]);
        s[r] = fmaf(v, v, s[r]);
      }
    }
    #pragma unroll
    for (int off = 1; off < 16; off <<= 1) {
      pn += __shfl_xor(pn, off);
      #pragma unroll
      for (int r = 0; r < 4; ++r) {
        d[r] += __shfl_xor(d[r], off);
        s[r] += __shfl_xor(s[r], off);
      }
    }
    const float spn = fmaxf(sqrtf(pn), 1e-12f);
    float cs[4];
    #pragma unroll
    for (int r = 0; r < 4; ++r) {
      float c = d[r] / (fmaxf(sqrtf(s[r]), 1e-12f) * spn);
      cs[r] = fminf(fmaxf(c, 0.f), 1.f);
    }
    #pragma unroll
    for (int nf = 0; nf < 10; ++nf)
      #pragma unroll
      for (int r = 0; r < 4; ++r)
        Acatile[(wave * 16 + quad * 4 + r) * 328 + nf * 16 + t16] = f2b(acc[nf][r] * cs[r]);
  }

  // ---- phase B: cosz reduce over k, scale, transpose-write cols 160:320 ----
  {
    float d[4] = {0.f, 0.f, 0.f, 0.f}, sv[4] = {0.f, 0.f, 0.f, 0.f};
    float pn = 0.f;
    #pragma unroll
    for (int it = 0; it < 10; ++it) {
      const int k = it * 16 + kr;
      const float a = p1s[k];
      d[0] = fmaf(zv[it].x, a, d[0]); d[1] = fmaf(zv[it].y, a, d[1]);
      d[2] = fmaf(zv[it].z, a, d[2]); d[3] = fmaf(zv[it].w, a, d[3]);
      sv[0] = fmaf(zv[it].x, zv[it].x, sv[0]); sv[1] = fmaf(zv[it].y, zv[it].y, sv[1]);
      sv[2] = fmaf(zv[it].z, zv[it].z, sv[2]); sv[3] = fmaf(zv[it].w, zv[it].w, sv[3]);
      pn = fmaf(a, a, pn);
    }
    #pragma unroll
    for (int off = 16; off < 64; off <<= 1) {
      pn += __shfl_xor(pn, off);
      #pragma unroll
      for (int r = 0; r < 4; ++r) {
        d[r] += __shfl_xor(d[r], off);
        sv[r] += __shfl_xor(sv[r], off);
      }
    }
    if ((lane >> 4) == 0) {
      #pragma unroll
      for (int r = 0; r < 4; ++r) {
        sred[wave][lane][r] = d[r];
        sred[wave][lane][4 + r] = sv[r];
      }
      sred[wave][lane][8] = pn;
    }
  }
  __syncthreads();
  if (tid < 64) {
    const int cg = tid >> 2, r = tid & 3;
    float dd = 0.f, ss = 0.f, pp = 0.f;
    #pragma unroll
    for (int w = 0; w < 4; ++w) {
      dd += sred[w][cg][r];
      ss += sred[w][cg][4 + r];
      pp += sred[w][cg][8];
    }
    float c = dd / (fmaxf(sqrtf(ss), 1e-12f) * fmaxf(sqrtf(pp), 1e-12f));
    czs[tid] = fminf(fmaxf(c, 0.f), 1.f);
  }
  __syncthreads();
  {
    const float cz0 = czs[c4 + 0], cz1 = czs[c4 + 1], cz2 = czs[c4 + 2], cz3 = czs[c4 + 3];
    #pragma unroll
    for (int it = 0; it < 10; ++it) {
      const int k = it * 16 + kr;
      Acatile[(c4 + 0) * 328 + 160 + k] = f2b(zv[it].x * cz0);
      Acatile[(c4 + 1) * 328 + 160 + k] = f2b(zv[it].y * cz1);
      Acatile[(c4 + 2) * 328 + 160 + k] = f2b(zv[it].z * cz2);
      Acatile[(c4 + 3) * 328 + 160 + k] = f2b(zv[it].w * cz3);
    }
  }
  __syncthreads();

  // ---- phase C: O = 0.5 * Acatile @ TT^T  (each wave: 32 rows x 80 cols, K=320) ----
  {
    const int wm = wave & 1, wn = wave >> 1;
    f32x4 c2[2][5];
    #pragma unroll
    for (int i = 0; i < 2; ++i)
      #pragma unroll
      for (int j = 0; j < 5; ++j)
        c2[i][j] = (f32x4){0.f, 0.f, 0.f, 0.f};
    const short* bp = TT + (size_t)(wn * 80 + t16) * 320 + k8;
    #pragma unroll 2
    for (int ks = 0; ks < 10; ++ks) {
      bf16x8 a0 = *(const bf16x8*)&Acatile[(wm * 32 + t16) * 328 + ks * 32 + k8];
      bf16x8 a1 = *(const bf16x8*)&Acatile[(wm * 32 + 16 + t16) * 328 + ks * 32 + k8];
      #pragma unroll
      for (int nf = 0; nf < 5; ++nf) {
        bf16x8 bv = *(const bf16x8*)&bp[nf * 5120 + ks * 32];
        c2[0][nf] = __builtin_amdgcn_mfma_f32_16x16x32_bf16(a0, bv, c2[0][nf], 0, 0, 0);
        c2[1][nf] = __builtin_amdgcn_mfma_f32_16x16x32_bf16(a1, bv, c2[1][nf], 0, 0, 0);
      }
    }
    #pragma unroll
    for (int nf = 0; nf < 5; ++nf) {
      const int kc = wn * 80 + nf * 16 + t16;
      if (kc < 150) {
        #pragma unroll
        for (int mf = 0; mf < 2; ++mf) {
          const int moff = wm * 32 + mf * 16 + quad * 4;
          float4 r4;
          r4.x = 0.5f * c2[mf][nf][0];
          r4.y = 0.5f * c2[mf][nf][1];
          r4.z = 0.5f * c2[mf][nf][2];
          r4.w = 0.5f * c2[mf][nf][3];
          *(float4*)&csz[((size_t)b * 150 + kc) * 16384 + mmg + moff] = r4;
          *(float4*)&asg[(((size_t)b * 4 + ti) * 150 + kc) * 4096 + nn + moff] = r4;
        }
      }
    }
  }
}

// ---------------- softmax stats + exp materialization (bf16) ----------------
// row = bt*150+k; writes ecsz[bt][160pad][4096] bf16 = exp(csz - rowmax); lr = rowsum
__global__ __launch_bounds__(256) void softmax_stats_e(
    const float* __restrict__ csz, float* __restrict__ lr_, short* __restrict__ ecsz)
{
  __shared__ float wred[8];
  const int row = blockIdx.x;
  const int bt = row / 150, k = row - bt * 150;
  const int b = bt >> 2, ti = bt & 3;
  const float* p = csz + ((size_t)b * 150 + k) * 16384 + ti * 4096;
  const int base = threadIdx.x * 16;
  float4 v[4];
  #pragma unroll
  for (int i = 0; i < 4; ++i) v[i] = *(const float4*)&p[base + i * 4];
  float mx = -1e30f;
  #pragma unroll
  for (int i = 0; i < 4; ++i)
    mx = fmaxf(mx, fmaxf(fmaxf(v[i].x, v[i].y), fmaxf(v[i].z, v[i].w)));
  #pragma unroll
  for (int off = 1; off < 64; off <<= 1) mx = fmaxf(mx, __shfl_xor(mx, off));
  const int wave = threadIdx.x >> 6, lane = threadIdx.x & 63;
  if (lane == 0) wred[wave] = mx;
  __syncthreads();
  mx = fmaxf(fmaxf(wred[0], wred[1]), fmaxf(wred[2], wred[3]));
  const float L = 1.4426950408889634f;
  float s = 0.f;
  bf16x8 e0, e1;
  #pragma unroll
  for (int i = 0; i < 2; ++i) {
    float a = exp2f((v[i].x - mx) * L);
    float bq = exp2f((v[i].y - mx) * L);
    float cq = exp2f((v[i].z - mx) * L);
    float dq = exp2f((v[i].w - mx) * L);
    s += a + bq + cq + dq;
    e0[i * 4 + 0] = f2b(a); e0[i * 4 + 1] = f2b(bq); e0[i * 4 + 2] = f2b(cq); e0[i * 4 + 3] = f2b(dq);
  }
  #pragma unroll
  for (int i = 2; i < 4; ++i) {
    float a = exp2f((v[i].x - mx) * L);
    float bq = exp2f((v[i].y - mx) * L);
    float cq = exp2f((v[i].z - mx) * L);
    float dq = exp2f((v[i].w - mx) * L);
    s += a + bq + cq + dq;
    e1[(i - 2) * 4 + 0] = f2b(a); e1[(i - 2) * 4 + 1] = f2b(bq);
    e1[(i - 2) * 4 + 2] = f2b(cq); e1[(i - 2) * 4 + 3] = f2b(dq);
  }
  #pragma unroll
  for (int off = 1; off < 64; off <<= 1) s += __shfl_xor(s, off);
  if (lane == 0) wred[4 + wave] = s;
  __syncthreads();
  short* er = ecsz + ((size_t)bt * 160 + k) * 4096 + base;
  *(bf16x8*)&er[0] = e0;
  *(bf16x8*)&er[8] = e1;
  if (threadIdx.x == 0) lr_[row] = wred[4] + wred[5] + wred[6] + wred[7];
}

// ---------------- cen numerator via MFMA + atomic split-K ----------------
// grid (2 chalf, 8 bt, 32 sp); block 256 = 4 waves; M=160(k) x N=128(c-half) x K=128(n)
__global__ __launch_bounds__(256) void gemm_cen_at(
    const short* __restrict__ ecsz, const short* __restrict__ xfT,
    float* __restrict__ cen)
{
  __shared__ __align__(16) short As[160 * 136];
  const int tid = threadIdx.x;
  const int chalf = blockIdx.x;
  const int bt = blockIdx.y;
  const int sp = blockIdx.z;
  const int n0 = sp * 128;
  const int wave = tid >> 6, lane = tid & 63;
  const int t16 = lane & 15, quad = lane >> 4, k8 = quad * 8;
  const int cbase = chalf * 128 + wave * 32;

  f32x4 acc[10][2];
  #pragma unroll
  for (int i = 0; i < 10; ++i) {
    acc[i][0] = (f32x4){0.f, 0.f, 0.f, 0.f};
    acc[i][1] = (f32x4){0.f, 0.f, 0.f, 0.f};
  }

  const short* erow = ecsz + (size_t)bt * 160 * 4096 + n0;
  // stage A: 160 rows x 128 k-cols (b128 in/out)
  #pragma unroll
  for (int p = 0; p < 10; ++p) {
    const int g = p * 256 + tid;
    const int row = g >> 4;
    const int col8 = (g & 15) * 8;
    *(bf16x8*)&As[row * 136 + col8] = *(const bf16x8*)&erow[(size_t)row * 4096 + col8];
  }
  __syncthreads();
  const short* xrow = xfT + (size_t)bt * 256 * 4096 + n0;
  #pragma unroll
  for (int kc = 0; kc < 4; ++kc) {
    bf16x8 b0 = *(const bf16x8*)&xrow[(size_t)(cbase + t16) * 4096 + kc * 32 + k8];
    bf16x8 b1 = *(const bf16x8*)&xrow[(size_t)(cbase + 16 + t16) * 4096 + kc * 32 + k8];
    #pragma unroll
    for (int mt = 0; mt < 10; ++mt) {
      bf16x8 aA = *(const bf16x8*)&As[(mt * 16 + t16) * 136 + kc * 32 + k8];
      acc[mt][0] = __builtin_amdgcn_mfma_f32_16x16x32_bf16(aA, b0, acc[mt][0], 0, 0, 0);
      acc[mt][1] = __builtin_amdgcn_mfma_f32_16x16x32_bf16(aA, b1, acc[mt][1], 0, 0, 0);
    }
  }
  #pragma unroll
  for (int mt = 0; mt < 10; ++mt) {
    #pragma unroll
    for (int r = 0; r < 4; ++r) {
      const int grow = mt * 16 + quad * 4 + r;
      if (grow < 150) {
        atomicAdd(&cen[((size_t)bt * 150 + grow) * 256 + cbase + t16], acc[mt][0][r]);
        atomicAdd(&cen[((size_t)bt * 150 + grow) * 256 + cbase + 16 + t16], acc[mt][1][r]);
      }
    }
  }
}

// ---------------- similarity gate + LN -> C_in (cen holds numerators; /lr here) ----------------
__global__ __launch_bounds__(256) void gate_ln(
    const float* __restrict__ cen, const float* __restrict__ lr_,
    const float* __restrict__ alpha_, const float* __restrict__ beta_,
    const float* __restrict__ nw, const float* __restrict__ nb, float* __restrict__ cin)
{
  __shared__ float red[256];
  int bk = blockIdx.x;
  int b = bk / 150, k = bk % 150;
  int c = threadIdx.x;
  const float* base = cen + ((size_t)b * 4 * 150) * 256;
  const float* lrb = lr_ + (size_t)b * 4 * 150;
  float lc  = base[((size_t)3 * 150 + k) * 256 + c] / lrb[3 * 150 + k];
  float p0  = base[((size_t)0 * 150 + k) * 256 + c] / lrb[0 * 150 + k];
  float p1v = base[((size_t)1 * 150 + k) * 256 + c] / lrb[1 * 150 + k];
  float p2v = base[((size_t)2 * 150 + k) * 256 + c] / lrb[2 * 150 + k];
  float nl = bred_sum(lc * lc, red);
  float q0 = bred_sum(p0 * p0, red);
  float q1 = bred_sum(p1v * p1v, red);
  float q2 = bred_sum(p2v * p2v, red);
  float d0 = bred_sum(lc * p0, red);
  float d1 = bred_sum(lc * p1v, red);
  float d2 = bred_sum(lc * p2v, red);
  float al = alpha_[0], be = beta_[0];
  float snl = sqrtf(nl);
  float g0 = 1.f / (1.f + expf(-(be + al * (d0 / fmaxf(snl * sqrtf(q0), 1e-8f)))));
  float g1 = 1.f / (1.f + expf(-(be + al * (d1 / fmaxf(snl * sqrtf(q1), 1e-8f)))));
  float g2 = 1.f / (1.f + expf(-(be + al * (d2 / fmaxf(snl * sqrtf(q2), 1e-8f)))));
  float ci = lc + g0 * p0 + g1 * p1v + g2 * p2v;
  float mu = bred_sum(ci, red) * (1.f / 256.f);
  float df = ci - mu;
  float var = bred_sum(df * df, red) * (1.f / 256.f);
  cin[(size_t)bk * 256 + c] = df * rsqrtf(var + 1e-5f) * nw[c] + nb[c];
}

// ---------------- merged k/v fp32 GEMM (M=300, N=256, K=256) ----------------
// grid (3, 8): blockIdx.y<4 -> K-proj, else V-proj; n0 = (y&3)*64
__global__ __launch_bounds__(256) void gemm_kv(
    const float* __restrict__ A,
    const float* __restrict__ Wk, const float* __restrict__ bk, float* __restrict__ outk,
    const float* __restrict__ Wv, const float* __restrict__ bv_, float* __restrict__ outv)
{
  __shared__ __align__(16) float As[16][132];
  __shared__ __align__(16) float Ws[16][68];
  const int tid = threadIdx.x;
  const int m0 = blockIdx.x * 128;
  const bool isv = blockIdx.y >= 4;
  const float* W = isv ? Wv : Wk;
  const float* bias = isv ? bv_ : bk;
  float* out = isv ? outv : outk;
  const int n0 = (blockIdx.y & 3) * 64;
  const int M = 300, K = 256;
  const int tm = tid & 15;
  const int tn = tid >> 4;
  float acc[8][4];
  #pragma unroll
  for (int i = 0; i < 8; ++i)
    #pragma unroll
    for (int j = 0; j < 4; ++j) acc[i][j] = 0.f;

  const int lr = tid >> 2;
  const int lk = (tid & 3) * 4;

  for (int k0 = 0; k0 < K; k0 += 16) {
    #pragma unroll
    for (int p = 0; p < 2; ++p) {
      int r = lr + p * 64;
      int gm = m0 + r;
      float4 v = make_float4(0.f, 0.f, 0.f, 0.f);
      if (gm < M) v = *(const float4*)&A[(size_t)gm * K + k0 + lk];
      As[lk + 0][r] = v.x; As[lk + 1][r] = v.y; As[lk + 2][r] = v.z; As[lk + 3][r] = v.w;
    }
    {
      float4 v = *(const float4*)&W[(size_t)(n0 + lr) * K + k0 + lk];
      Ws[lk + 0][lr] = v.x; Ws[lk + 1][lr] = v.y; Ws[lk + 2][lr] = v.z; Ws[lk + 3][lr] = v.w;
    }
    __syncthreads();
    #pragma unroll
    for (int kk = 0; kk < 16; ++kk) {
      float4 a0 = *(const float4*)&As[kk][tm * 8];
      float4 a1 = *(const float4*)&As[kk][tm * 8 + 4];
      float4 w0 = *(const float4*)&Ws[kk][tn * 4];
      float av[8] = {a0.x, a0.y, a0.z, a0.w, a1.x, a1.y, a1.z, a1.w};
      float wv[4] = {w0.x, w0.y, w0.z, w0.w};
      #pragma unroll
      for (int i = 0; i < 8; ++i)
        #pragma unroll
        for (int j = 0; j < 4; ++j)
          acc[i][j] = fmaf(av[i], wv[j], acc[i][j]);
    }
    __syncthreads();
  }
  float4 bv4 = *(const float4*)&bias[n0 + tn * 4];
  float bb[4] = {bv4.x, bv4.y, bv4.z, bv4.w};
  #pragma unroll
  for (int i = 0; i < 8; ++i) {
    int gm = m0 + tm * 8 + i;
    if (gm >= M) continue;
    float4 r;
    r.x = acc[i][0] + bb[0];
    r.y = acc[i][1] + bb[1];
    r.z = acc[i][2] + bb[2];
    r.w = acc[i][3] + bb[3];
    *(float4*)&out[(size_t)gm * 256 + n0 + tn * 4] = r;
  }
}

// ---------------- MFMA attention: 128 Q-rows/block, per (b,h); q bf16 in, o bf16 out ----------------
__global__ __launch_bounds__(256) void attn_mfma(
    const short* __restrict__ q, const float* __restrict__ ks, const float* __restrict__ vs,
    short* __restrict__ o)
{
  __shared__ __align__(16) short Ps[128 * 168];
  __shared__ __align__(16) short VT[32 * 168];
  __shared__ float lrow[128];
  const int tid = threadIdx.x;
  const int bid = blockIdx.x;
  const int ntile = bid & 31;
  const int bh = bid >> 5;
  const int b = bh >> 3, h = bh & 7;
  const int n0 = ntile * 128;
  const int wave = tid >> 6, lane = tid & 63;
  const int t16 = lane & 15, quad = lane >> 4;
  const int k8 = quad * 8;
  const int wr = wave * 32;

  for (int i = tid; i < 5120; i += 256) {
    int d = i / 160, kc = i - d * 160;
    VT[d * 168 + kc] = (kc < 150) ? f2b(vs[((size_t)b * 150 + kc) * 256 + h * 32 + d]) : (short)0;
  }

  bf16x8 aQ[2];
  #pragma unroll
  for (int mt = 0; mt < 2; ++mt)
    aQ[mt] = *(const bf16x8*)&q[((size_t)b * 4096 + n0 + wr + mt * 16 + t16) * 256 + h * 32 + k8];

  f32x4 s[2][10];
  #pragma unroll
  for (int ct = 0; ct < 10; ++ct) {
    const int c = ct * 16 + t16;
    bf16x8 bK = {0, 0, 0, 0, 0, 0, 0, 0};
    if (c < 150) {
      const float* kp = &ks[((size_t)b * 150 + c) * 256 + h * 32 + k8];
      float4 v0 = *(const float4*)&kp[0];
      float4 v1 = *(const float4*)&kp[4];
      bK[0] = f2b(v0.x); bK[1] = f2b(v0.y); bK[2] = f2b(v0.z); bK[3] = f2b(v0.w);
      bK[4] = f2b(v1.x); bK[5] = f2b(v1.y); bK[6] = f2b(v1.z); bK[7] = f2b(v1.w);
    }
    f32x4 zero = (f32x4){0.f, 0.f, 0.f, 0.f};
    s[0][ct] = __builtin_amdgcn_mfma_f32_16x16x32_bf16(aQ[0], bK, zero, 0, 0, 0);
    s[1][ct] = __builtin_amdgcn_mfma_f32_16x16x32_bf16(aQ[1], bK, zero, 0, 0, 0);
  }

  #pragma unroll
  for (int mt = 0; mt < 2; ++mt) {
    #pragma unroll
    for (int r = 0; r < 4; ++r) {
      float mx = -1e30f;
      #pragma unroll
      for (int ct = 0; ct < 10; ++ct) {
        float v = s[mt][ct][r];
        if (ct == 9 && t16 >= 6) { v = -1e30f; s[mt][ct][r] = v; }
        mx = fmaxf(mx, v);
      }
      mx = fmaxf(mx, __shfl_xor(mx, 1));
      mx = fmaxf(mx, __shfl_xor(mx, 2));
      mx = fmaxf(mx, __shfl_xor(mx, 4));
      mx = fmaxf(mx, __shfl_xor(mx, 8));
      float ls = 0.f;
      #pragma unroll
      for (int ct = 0; ct < 10; ++ct) {
        float e = expf(s[mt][ct][r] - mx);
        s[mt][ct][r] = e;
        ls += e;
      }
      ls += __shfl_xor(ls, 1);
      ls += __shfl_xor(ls, 2);
      ls += __shfl_xor(ls, 4);
      ls += __shfl_xor(ls, 8);
      if (t16 == 0) lrow[wr + mt * 16 + quad * 4 + r] = 1.f / ls;
      #pragma unroll
      for (int ct = 0; ct < 10; ++ct)
        Ps[(wr + mt * 16 + quad * 4 + r) * 168 + ct * 16 + t16] = f2b(s[mt][ct][r]);
    }
  }
  __syncthreads();

  f32x4 oacc[2][2];
  #pragma unroll
  for (int i = 0; i < 2; ++i)
    #pragma unroll
    for (int j = 0; j < 2; ++j)
      oacc[i][j] = (f32x4){0.f, 0.f, 0.f, 0.f};
  #pragma unroll
  for (int kstep = 0; kstep < 5; ++kstep) {
    bf16x8 bV0 = *(const bf16x8*)&VT[( 0 + t16) * 168 + kstep * 32 + k8];
    bf16x8 bV1 = *(const bf16x8*)&VT[(16 + t16) * 168 + kstep * 32 + k8];
    #pragma unroll
    for (int mt = 0; mt < 2; ++mt) {
      bf16x8 aP = *(const bf16x8*)&Ps[(wr + mt * 16 + t16) * 168 + kstep * 32 + k8];
      oacc[mt][0] = __builtin_amdgcn_mfma_f32_16x16x32_bf16(aP, bV0, oacc[mt][0], 0, 0, 0);
      oacc[mt][1] = __builtin_amdgcn_mfma_f32_16x16x32_bf16(aP, bV1, oacc[mt][1], 0, 0, 0);
    }
  }
  #pragma unroll
  for (int mt = 0; mt < 2; ++mt) {
    #pragma unroll
    for (int nt = 0; nt < 2; ++nt) {
      const int d = nt * 16 + t16;
      #pragma unroll
      for (int r = 0; r < 4; ++r) {
        const int row = wr + mt * 16 + quad * 4 + r;
        o[((size_t)b * 4096 + n0 + row) * 256 + h * 32 + d] = f2b(oacc[mt][nt][r] * lrow[row]);
      }
    }
  }
}

// ---------------- dst = res + LN(src), wave-per-row (row=256 cols) ----------------
__global__ __launch_bounds__(256) void ln_res(
    const float* __restrict__ src, const float* __restrict__ res,
    const float* __restrict__ nw, const float* __restrict__ nb, float* __restrict__ dst)
{
  const int wave = threadIdx.x >> 6;
  const int lane = threadIdx.x & 63;
  const size_t row = (size_t)blockIdx.x * 4 + wave;
  const int c = lane * 4;
  float4 v = *(const float4*)&src[row * 256 + c];
  float s  = v.x + v.y + v.z + v.w;
  float s2 = v.x * v.x + v.y * v.y + v.z * v.z + v.w * v.w;
  #pragma unroll
  for (int off = 1; off < 64; off <<= 1) {
    s  += __shfl_xor(s, off);
    s2 += __shfl_xor(s2, off);
  }
  const float mu = s * (1.f / 256.f);
  const float var = s2 * (1.f / 256.f) - mu * mu;
  const float inv = rsqrtf(var + 1e-5f);
  float4 w = *(const float4*)&nw[c];
  float4 bb = *(const float4*)&nb[c];
  float4 rr = *(const float4*)&res[row * 256 + c];
  float4 d;
  d.x = rr.x + (v.x - mu) * inv * w.x + bb.x;
  d.y = rr.y + (v.y - mu) * inv * w.y + bb.y;
  d.z = rr.z + (v.z - mu) * inv * w.z + bb.z;
  d.w = rr.w + (v.w - mu) * inv * w.w + bb.w;
  *(float4*)&dst[row * 256 + c] = d;
}

// ---------------- depthwise 3x3 conv + bias + exact gelu, 4 pixels/block, bf16 out ----------------
// grid 2048 = b(2) x y(64) x xg(16); each block does pixels (y, 4*xg .. 4*xg+3),
// 256 threads x 4 channels. 3x6 tap window shared across the 4 outputs.
__global__ __launch_bounds__(256) void conv_gelu(
    const float* __restrict__ h, const float* __restrict__ wt, const float* __restrict__ bias,
    short* __restrict__ hc)
{
  const int bid = blockIdx.x;
  const int xg = bid & 15;
  const int y  = (bid >> 4) & 63;
  const int b  = bid >> 10;
  const int x0 = xg * 4;
  const int c4 = threadIdx.x * 4;
  const float* hb = h + ((size_t)b * 4096) * 1024 + c4;

  float4 tap[3][6];
  #pragma unroll
  for (int dy = 0; dy < 3; ++dy) {
    const int yy = y + dy - 1;
    #pragma unroll
    for (int dx = 0; dx < 6; ++dx) {
      const int xv = x0 + dx - 1;
      tap[dy][dx] = make_float4(0.f, 0.f, 0.f, 0.f);
      if (yy >= 0 && yy <= 63 && xv >= 0 && xv <= 63)
        tap[dy][dx] = *(const float4*)&hb[(size_t)(yy * 64 + xv) * 1024];
    }
  }
  float4 wv[3][3];
  #pragma unroll
  for (int dy = 0; dy < 3; ++dy)
    #pragma unroll
    for (int dx = 0; dx < 3; ++dx)
      wv[dy][dx] = *(const float4*)&wt[(dy * 3 + dx) * 1024 + c4];
  const float4 bv = *(const float4*)&bias[c4];

  #pragma unroll
  for (int p = 0; p < 4; ++p) {
    float4 acc = bv;
    #pragma unroll
    for (int dy = 0; dy < 3; ++dy) {
      #pragma unroll
      for (int dx = 0; dx < 3; ++dx) {
        const float4 hv = tap[dy][p + dx];
        const float4 w = wv[dy][dx];
        acc.x = fmaf(hv.x, w.x, acc.x);
        acc.y = fmaf(hv.y, w.y, acc.y);
        acc.z = fmaf(hv.z, w.z, acc.z);
        acc.w = fmaf(hv.w, w.w, acc.w);
      }
    }
    bf16x4 g;
    g[0] = f2b(0.5f * acc.x * (1.f + erff(acc.x * 0.70710678118654752f)));
    g[1] = f2b(0.5f * acc.y * (1.f + erff(acc.y * 0.70710678118654752f)));
    g[2] = f2b(0.5f * acc.z * (1.f + erff(acc.z * 0.70710678118654752f)));
    g[3] = f2b(0.5f * acc.w * (1.f + erff(acc.w * 0.70710678118654752f)));
    *(bf16x4*)&hc[((size_t)b * 4096 + y * 64 + x0 + p) * 1024 + c4] = g;
  }
}

extern "C" void kernel_launch(void* const* d_in, const int* in_sizes, int n_in,
                              void* d_out, int out_size, void* d_ws, size_t ws_size,
                              hipStream_t stream)
{
  (void)in_sizes; (void)n_in; (void)out_size; (void)ws_size;
  const float* x    = (const float*)d_in[0];
  const float* z    = (const float*)d_in[1];
  const float* mem  = (const float*)d_in[2];
  const float* cw   = (const float*)d_in[3];
  const float* p1   = (const float*)d_in[4];
  const float* tdt1 = (const float*)d_in[5];
  const float* p2   = (const float*)d_in[6];
  const float* tdt2 = (const float*)d_in[7];
  const float* sal  = (const float*)d_in[8];
  const float* sbe  = (const float*)d_in[9];
  const float* q_w  = (const float*)d_in[10];
  const float* q_b  = (const float*)d_in[11];
  const float* k_w  = (const float*)d_in[12];
  const float* k_b  = (const float*)d_in[13];
  const float* v_w  = (const float*)d_in[14];
  const float* v_b  = (const float*)d_in[15];
  const float* pj_w = (const float*)d_in[16];
  const float* pj_b = (const float*)d_in[17];
  const float* nw   = (const float*)d_in[18];
  const float* nb   = (const float*)d_in[19];
  const float* f1w  = (const float*)d_in[20];
  const float* f1b  = (const float*)d_in[21];
  const float* dww  = (const float*)d_in[22];
  const float* dwb  = (const float*)d_in[23];
  const float* f2w  = (const float*)d_in[24];
  const float* f2b_ = (const float*)d_in[25];

  float* out = (float*)d_out;                  // (2,4096,256)
  float* csz = out + 2097152;                  // (2,150,16384)
  float* asg = csz + 4915200;                  // (2,4,150,4096)

  float* ws    = (float*)d_ws;
  short* ecsz  = (short*)ws;         // 5,242,880 shorts, written by softmax step
  short* TT    = (short*)(ws + 5242880);   // 160x320 bf16 = 25,600 float-slots
  short* cwb   = (short*)(ws + 5275648);   // 160x256 bf16 = 20,480 float-slots
  float* lr_   = ws + 5308416;       // 1,200
  float* cen   = ws + 5310816;       // 307,200
  float* cin   = ws + 5618016;       // 76,800
  short* q     = (short*)(ws + 5694816);   // 8192x256 bf16 = 1,048,576 float-slots
  float* ksb   = ws + 7791968;       // 76,800
  float* vsb   = ws + 7868768;       // 76,800
  short* o     = (short*)(ws + 7945568);   // 8192x256 bf16 (ends 8,994,144)
  short* xfT   = (short*)(ws + 10042720);  // 8x256x4096 bf16 = 4,194,304 float-slots (ends 14,237,024)
  float* h     = ws;                 // 8,388,608 reuse (ecsz/TT/cwb/q dead by fc1)
  short* hc    = (short*)(ws + 8388608);   // 8,388,608 shorts = 4,194,304 float-slots (o/xfT dead before conv_gelu? o used by proj which precedes fc1; safe: hc written after proj done)
  float* tmp   = ws + 16777216;
  float* out1  = ws + 18874368;
  float* wt    = ws + 20971520;      // 9,216

  dim3 blk(256);
  // 1. weight packs: cwb + TT + wt (conv weight transpose folded in)
  prep_bt<<<dim3(200), blk, 0, stream>>>(cw, tdt2, tdt1, dww, cwb, TT, wt);
  // 2. xf -> bf16 transpose [bt][c][n] (for cen's vector B-operand; also warms L3 with xf)
  xf_t<<<dim3(64, 8), blk, 0, stream>>>(x, mem, xfT);
  // 3. fused cluster front-end: cl GEMM + cosines + csz GEMM (64-row tiles — verified config)
  fused_csz<<<dim3(512), blk, 0, stream>>>(x, mem, z, cwb, TT, p1, p2, csz, asg);
  // 4. softmax stats + exp(csz-m) materialized bf16
  softmax_stats_e<<<dim3(1200), blk, 0, stream>>>(csz, lr_, ecsz);
  // 5. cen numerators via MFMA + atomics (cen zeroed first)
  hipMemsetAsync(cen, 0, (size_t)1200 * 256 * sizeof(float), stream);
  gemm_cen_at<<<dim3(2, 8, 32), blk, 0, stream>>>(ecsz, xfT, cen);
  // 6. gate + LN -> C_in (divides by lr)
  gate_ln<<<dim3(300), blk, 0, stream>>>(cen, lr_, sal, sbe, nw, nb, cin);
  // 7. q (MFMA, bf16 out — attn rounds anyway) + merged k/v (one launch)
  gemm_mfma_bfout<<<dim3(128, 4), blk, 0, stream>>>(x, q_w, q_b, q, 8192, 256, 256, 0.17677669529663687f);
  gemm_kv<<<dim3(3, 8), blk, 0, stream>>>(cin, k_w, k_b, ksb, v_w, v_b, vsb);
  // 8. attention [MFMA]; o written bf16 (proj rounds anyway — bit-identical)
  attn_mfma<<<dim3(512), blk, 0, stream>>>(q, ksb, vsb, o);
  // 9. proj (bf16 A) + LN + residual
  gemm_mfma_bfA<<<dim3(128, 4), blk, 0, stream>>>(o, pj_w, pj_b, tmp, 8192, 256, 256, 1.f);
  ln_res<<<dim3(2048), blk, 0, stream>>>(tmp, x, nw, nb, out1);
  // 10. MLP (hc is bf16: conv stores rounded, fc2 consumes directly — bit-identical)
  gemm_mfma<<<dim3(128, 16), blk, 0, stream>>>(out1, f1w, f1b, h, 8192, 1024, 256, 1.f);
  conv_gelu<<<dim3(2048), blk, 0, stream>>>(h, wt, dwb, hc);
  gemm_mfma_bfA<<<dim3(128, 4), blk, 0, stream>>>(hc, f2w, f2b_, tmp, 8192, 256, 1024, 1.f);
  ln_res<<<dim3(2048), blk, 0, stream>>>(tmp, out1, nw, nb, out);
}

// Round 10
// 385.316 us; speedup vs baseline: 1.0077x; 1.0077x over previous
//
#include <hip/hip_runtime.h>
#include <math.h>

// Dims: B=2, N=4096, C=256, nc=150, T=4, TN=16384, heads=8, hd=32, hid=1024, H=W=64

typedef __attribute__((ext_vector_type(8))) short bf16x8;
typedef __attribute__((ext_vector_type(4))) short bf16x4;
typedef __attribute__((ext_vector_type(4))) float f32x4;

__device__ __forceinline__ short f2b(float f) {
  union { float f; unsigned int u; } c; c.f = f;
  unsigned int r = (c.u + 0x7fffu + ((c.u >> 16) & 1u)) >> 16;
  return (short)r;
}

// ---------------- block reduction helpers (blockDim.x == 256) ----------------
__device__ __forceinline__ float bred_sum(float v, float* red) {
  int tid = threadIdx.x;
  red[tid] = v; __syncthreads();
  #pragma unroll
  for (int s = 128; s > 0; s >>= 1) {
    if (tid < s) red[tid] += red[tid + s];
    __syncthreads();
  }
  float r = red[0]; __syncthreads();
  return r;
}

// ---------------- bf16 MFMA GEMM, 64x64 tile: out[m][n] = alpha*(A@W^T + bias) ----------------
// grid (M/64, N/64); 4 waves: wm=row-half(32), wn=col-half(32), 2x2 16x16 frags each.
__global__ __launch_bounds__(256) void gemm_mfma(
    const float* __restrict__ A, const float* __restrict__ W,
    const float* __restrict__ bias, float* __restrict__ out,
    int M, int N, int K, float alpha)
{
  __shared__ __align__(16) short As[64 * 72];
  __shared__ __align__(16) short Bs[64 * 72];
  const int tid = threadIdx.x;
  const int m0 = blockIdx.x * 64;
  const int n0 = blockIdx.y * 64;
  const int wave = tid >> 6;
  const int lane = tid & 63;
  const int wm = wave & 1, wn = wave >> 1;
  const int t16 = lane & 15;
  const int k8 = (lane >> 4) * 8;

  f32x4 acc[2][2];
  #pragma unroll
  for (int i = 0; i < 2; ++i)
    #pragma unroll
    for (int j = 0; j < 2; ++j)
      acc[i][j] = (f32x4){0.f, 0.f, 0.f, 0.f};

  const int sr = tid >> 2;
  const int sk = (tid & 3) * 16;

  for (int k0 = 0; k0 < K; k0 += 64) {
    {
      const float* ap = &A[(size_t)(m0 + sr) * K + k0 + sk];
      float4 v0 = *(const float4*)&ap[0];
      float4 v1 = *(const float4*)&ap[4];
      float4 v2 = *(const float4*)&ap[8];
      float4 v3 = *(const float4*)&ap[12];
      bf16x8 w0, w1;
      w0[0] = f2b(v0.x); w0[1] = f2b(v0.y); w0[2] = f2b(v0.z); w0[3] = f2b(v0.w);
      w0[4] = f2b(v1.x); w0[5] = f2b(v1.y); w0[6] = f2b(v1.z); w0[7] = f2b(v1.w);
      w1[0] = f2b(v2.x); w1[1] = f2b(v2.y); w1[2] = f2b(v2.z); w1[3] = f2b(v2.w);
      w1[4] = f2b(v3.x); w1[5] = f2b(v3.y); w1[6] = f2b(v3.z); w1[7] = f2b(v3.w);
      *(bf16x8*)&As[sr * 72 + sk] = w0;
      *(bf16x8*)&As[sr * 72 + sk + 8] = w1;
    }
    {
      const float* wp = &W[(size_t)(n0 + sr) * K + k0 + sk];
      float4 v0 = *(const float4*)&wp[0];
      float4 v1 = *(const float4*)&wp[4];
      float4 v2 = *(const float4*)&wp[8];
      float4 v3 = *(const float4*)&wp[12];
      bf16x8 w0, w1;
      w0[0] = f2b(v0.x); w0[1] = f2b(v0.y); w0[2] = f2b(v0.z); w0[3] = f2b(v0.w);
      w0[4] = f2b(v1.x); w0[5] = f2b(v1.y); w0[6] = f2b(v1.z); w0[7] = f2b(v1.w);
      w1[0] = f2b(v2.x); w1[1] = f2b(v2.y); w1[2] = f2b(v2.z); w1[3] = f2b(v2.w);
      w1[4] = f2b(v3.x); w1[5] = f2b(v3.y); w1[6] = f2b(v3.z); w1[7] = f2b(v3.w);
      *(bf16x8*)&Bs[sr * 72 + sk] = w0;
      *(bf16x8*)&Bs[sr * 72 + sk + 8] = w1;
    }
    __syncthreads();
    #pragma unroll
    for (int ks = 0; ks < 2; ++ks) {
      const int kofs = ks * 32 + k8;
      bf16x8 af0 = *(const bf16x8*)&As[(wm * 32 +  0 + t16) * 72 + kofs];
      bf16x8 af1 = *(const bf16x8*)&As[(wm * 32 + 16 + t16) * 72 + kofs];
      bf16x8 bf0 = *(const bf16x8*)&Bs[(wn * 32 +  0 + t16) * 72 + kofs];
      bf16x8 bf1 = *(const bf16x8*)&Bs[(wn * 32 + 16 + t16) * 72 + kofs];
      acc[0][0] = __builtin_amdgcn_mfma_f32_16x16x32_bf16(af0, bf0, acc[0][0], 0, 0, 0);
      acc[1][0] = __builtin_amdgcn_mfma_f32_16x16x32_bf16(af1, bf0, acc[1][0], 0, 0, 0);
      acc[0][1] = __builtin_amdgcn_mfma_f32_16x16x32_bf16(af0, bf1, acc[0][1], 0, 0, 0);
      acc[1][1] = __builtin_amdgcn_mfma_f32_16x16x32_bf16(af1, bf1, acc[1][1], 0, 0, 0);
    }
    __syncthreads();
  }
  const int r4 = (lane >> 4) * 4;
  #pragma unroll
  for (int ni = 0; ni < 2; ++ni) {
    const int gcol = n0 + wn * 32 + ni * 16 + t16;
    const float bb = bias[gcol];
    #pragma unroll
    for (int mi = 0; mi < 2; ++mi) {
      #pragma unroll
      for (int r = 0; r < 4; ++r) {
        const int gm = m0 + wm * 32 + mi * 16 + r4 + r;
        out[(size_t)gm * N + gcol] = alpha * (acc[mi][ni][r] + bb);
      }
    }
  }
}

// ---------------- fp32-A MFMA GEMM, bf16 OUT (q-proj: consumer rounds anyway) ----------------
__global__ __launch_bounds__(256) void gemm_mfma_bfout(
    const float* __restrict__ A, const float* __restrict__ W,
    const float* __restrict__ bias, short* __restrict__ out,
    int M, int N, int K, float alpha)
{
  __shared__ __align__(16) short As[64 * 72];
  __shared__ __align__(16) short Bs[64 * 72];
  const int tid = threadIdx.x;
  const int m0 = blockIdx.x * 64;
  const int n0 = blockIdx.y * 64;
  const int wave = tid >> 6;
  const int lane = tid & 63;
  const int wm = wave & 1, wn = wave >> 1;
  const int t16 = lane & 15;
  const int k8 = (lane >> 4) * 8;

  f32x4 acc[2][2];
  #pragma unroll
  for (int i = 0; i < 2; ++i)
    #pragma unroll
    for (int j = 0; j < 2; ++j)
      acc[i][j] = (f32x4){0.f, 0.f, 0.f, 0.f};

  const int sr = tid >> 2;
  const int sk = (tid & 3) * 16;

  for (int k0 = 0; k0 < K; k0 += 64) {
    {
      const float* ap = &A[(size_t)(m0 + sr) * K + k0 + sk];
      float4 v0 = *(const float4*)&ap[0];
      float4 v1 = *(const float4*)&ap[4];
      float4 v2 = *(const float4*)&ap[8];
      float4 v3 = *(const float4*)&ap[12];
      bf16x8 w0, w1;
      w0[0] = f2b(v0.x); w0[1] = f2b(v0.y); w0[2] = f2b(v0.z); w0[3] = f2b(v0.w);
      w0[4] = f2b(v1.x); w0[5] = f2b(v1.y); w0[6] = f2b(v1.z); w0[7] = f2b(v1.w);
      w1[0] = f2b(v2.x); w1[1] = f2b(v2.y); w1[2] = f2b(v2.z); w1[3] = f2b(v2.w);
      w1[4] = f2b(v3.x); w1[5] = f2b(v3.y); w1[6] = f2b(v3.z); w1[7] = f2b(v3.w);
      *(bf16x8*)&As[sr * 72 + sk] = w0;
      *(bf16x8*)&As[sr * 72 + sk + 8] = w1;
    }
    {
      const float* wp = &W[(size_t)(n0 + sr) * K + k0 + sk];
      float4 v0 = *(const float4*)&wp[0];
      float4 v1 = *(const float4*)&wp[4];
      float4 v2 = *(const float4*)&wp[8];
      float4 v3 = *(const float4*)&wp[12];
      bf16x8 w0, w1;
      w0[0] = f2b(v0.x); w0[1] = f2b(v0.y); w0[2] = f2b(v0.z); w0[3] = f2b(v0.w);
      w0[4] = f2b(v1.x); w0[5] = f2b(v1.y); w0[6] = f2b(v1.z); w0[7] = f2b(v1.w);
      w1[0] = f2b(v2.x); w1[1] = f2b(v2.y); w1[2] = f2b(v2.z); w1[3] = f2b(v2.w);
      w1[4] = f2b(v3.x); w1[5] = f2b(v3.y); w1[6] = f2b(v3.z); w1[7] = f2b(v3.w);
      *(bf16x8*)&Bs[sr * 72 + sk] = w0;
      *(bf16x8*)&Bs[sr * 72 + sk + 8] = w1;
    }
    __syncthreads();
    #pragma unroll
    for (int ks = 0; ks < 2; ++ks) {
      const int kofs = ks * 32 + k8;
      bf16x8 af0 = *(const bf16x8*)&As[(wm * 32 +  0 + t16) * 72 + kofs];
      bf16x8 af1 = *(const bf16x8*)&As[(wm * 32 + 16 + t16) * 72 + kofs];
      bf16x8 bf0 = *(const bf16x8*)&Bs[(wn * 32 +  0 + t16) * 72 + kofs];
      bf16x8 bf1 = *(const bf16x8*)&Bs[(wn * 32 + 16 + t16) * 72 + kofs];
      acc[0][0] = __builtin_amdgcn_mfma_f32_16x16x32_bf16(af0, bf0, acc[0][0], 0, 0, 0);
      acc[1][0] = __builtin_amdgcn_mfma_f32_16x16x32_bf16(af1, bf0, acc[1][0], 0, 0, 0);
      acc[0][1] = __builtin_amdgcn_mfma_f32_16x16x32_bf16(af0, bf1, acc[0][1], 0, 0, 0);
      acc[1][1] = __builtin_amdgcn_mfma_f32_16x16x32_bf16(af1, bf1, acc[1][1], 0, 0, 0);
    }
    __syncthreads();
  }
  const int r4 = (lane >> 4) * 4;
  #pragma unroll
  for (int ni = 0; ni < 2; ++ni) {
    const int gcol = n0 + wn * 32 + ni * 16 + t16;
    const float bb = bias[gcol];
    #pragma unroll
    for (int mi = 0; mi < 2; ++mi) {
      #pragma unroll
      for (int r = 0; r < 4; ++r) {
        const int gm = m0 + wm * 32 + mi * 16 + r4 + r;
        out[(size_t)gm * N + gcol] = f2b(alpha * (acc[mi][ni][r] + bb));
      }
    }
  }
}

// ---------------- bf16-A MFMA GEMM, 64x64 tile (proj/fc1/fc2: A pre-rounded bf16) ----------------
__global__ __launch_bounds__(256) void gemm_mfma_bfA(
    const short* __restrict__ A, const float* __restrict__ W,
    const float* __restrict__ bias, float* __restrict__ out,
    int M, int N, int K, float alpha)
{
  __shared__ __align__(16) short As[64 * 72];
  __shared__ __align__(16) short Bs[64 * 72];
  const int tid = threadIdx.x;
  const int m0 = blockIdx.x * 64;
  const int n0 = blockIdx.y * 64;
  const int wave = tid >> 6;
  const int lane = tid & 63;
  const int wm = wave & 1, wn = wave >> 1;
  const int t16 = lane & 15;
  const int k8 = (lane >> 4) * 8;

  f32x4 acc[2][2];
  #pragma unroll
  for (int i = 0; i < 2; ++i)
    #pragma unroll
    for (int j = 0; j < 2; ++j)
      acc[i][j] = (f32x4){0.f, 0.f, 0.f, 0.f};

  const int sr = tid >> 2;
  const int sk = (tid & 3) * 16;

  for (int k0 = 0; k0 < K; k0 += 64) {
    {
      const short* ap = &A[(size_t)(m0 + sr) * K + k0 + sk];
      *(bf16x8*)&As[sr * 72 + sk] = *(const bf16x8*)&ap[0];
      *(bf16x8*)&As[sr * 72 + sk + 8] = *(const bf16x8*)&ap[8];
    }
    {
      const float* wp = &W[(size_t)(n0 + sr) * K + k0 + sk];
      float4 v0 = *(const float4*)&wp[0];
      float4 v1 = *(const float4*)&wp[4];
      float4 v2 = *(const float4*)&wp[8];
      float4 v3 = *(const float4*)&wp[12];
      bf16x8 w0, w1;
      w0[0] = f2b(v0.x); w0[1] = f2b(v0.y); w0[2] = f2b(v0.z); w0[3] = f2b(v0.w);
      w0[4] = f2b(v1.x); w0[5] = f2b(v1.y); w0[6] = f2b(v1.z); w0[7] = f2b(v1.w);
      w1[0] = f2b(v2.x); w1[1] = f2b(v2.y); w1[2] = f2b(v2.z); w1[3] = f2b(v2.w);
      w1[4] = f2b(v3.x); w1[5] = f2b(v3.y); w1[6] = f2b(v3.z); w1[7] = f2b(v3.w);
      *(bf16x8*)&Bs[sr * 72 + sk] = w0;
      *(bf16x8*)&Bs[sr * 72 + sk + 8] = w1;
    }
    __syncthreads();
    #pragma unroll
    for (int ks = 0; ks < 2; ++ks) {
      const int kofs = ks * 32 + k8;
      bf16x8 af0 = *(const bf16x8*)&As[(wm * 32 +  0 + t16) * 72 + kofs];
      bf16x8 af1 = *(const bf16x8*)&As[(wm * 32 + 16 + t16) * 72 + kofs];
      bf16x8 bf0 = *(const bf16x8*)&Bs[(wn * 32 +  0 + t16) * 72 + kofs];
      bf16x8 bf1 = *(const bf16x8*)&Bs[(wn * 32 + 16 + t16) * 72 + kofs];
      acc[0][0] = __builtin_amdgcn_mfma_f32_16x16x32_bf16(af0, bf0, acc[0][0], 0, 0, 0);
      acc[1][0] = __builtin_amdgcn_mfma_f32_16x16x32_bf16(af1, bf0, acc[1][0], 0, 0, 0);
      acc[0][1] = __builtin_amdgcn_mfma_f32_16x16x32_bf16(af0, bf1, acc[0][1], 0, 0, 0);
      acc[1][1] = __builtin_amdgcn_mfma_f32_16x16x32_bf16(af1, bf1, acc[1][1], 0, 0, 0);
    }
    __syncthreads();
  }
  const int r4 = (lane >> 4) * 4;
  #pragma unroll
  for (int ni = 0; ni < 2; ++ni) {
    const int gcol = n0 + wn * 32 + ni * 16 + t16;
    const float bb = bias[gcol];
    #pragma unroll
    for (int mi = 0; mi < 2; ++mi) {
      #pragma unroll
      for (int r = 0; r < 4; ++r) {
        const int gm = m0 + wm * 32 + mi * 16 + r4 + r;
        out[(size_t)gm * N + gcol] = alpha * (acc[mi][ni][r] + bb);
      }
    }
  }
}

// ---------------- merged prep (bid<200) + xf transpose (bid>=200) ----------------
// prep: cwb[160][256] bf16 (cw zero-padded), TT[160][320] bf16, wt[tap][1024].
// xf_t: xfT[bt][c][n] bf16 (8 x 256 x 4096), bt = (bid-200)>>6, n0 = ((bid-200)&63)*64.
__global__ __launch_bounds__(256) void prep_all(
    const float* __restrict__ cw, const float* __restrict__ tdt2, const float* __restrict__ tdt1,
    const float* __restrict__ dww, const float* __restrict__ x, const float* __restrict__ mem,
    short* __restrict__ cwb, short* __restrict__ TT, float* __restrict__ wt,
    short* __restrict__ xfT)
{
  if (blockIdx.x < 200) {
    int idx = blockIdx.x * 256 + threadIdx.x;
    if (idx < 160 * 256) {
      int kc = idx >> 8, k = idx & 255;
      float v = (kc < 150) ? cw[kc * 256 + k] : 0.f;
      cwb[idx] = f2b(v);
    }
    if (idx < 160 * 320) {
      int kc = idx / 320, kk = idx - kc * 320;
      float t = 0.f;
      if (kc < 150) {
        if (kk < 150) t = tdt2[kk * 150 + kc];
        else if (kk >= 160 && kk < 310) t = tdt1[(kk - 160) * 150 + kc];
      }
      TT[idx] = f2b(t);
    }
    if (idx < 9216) {
      int ch = idx / 9, tap = idx - ch * 9;
      wt[tap * 1024 + ch] = dww[idx];
    }
  } else {
    __shared__ float tile[64][257];
    const int bid = blockIdx.x - 200;
    const int bt = bid >> 6;
    const int n0 = (bid & 63) * 64;
    const int b = bt >> 2, ti = bt & 3;
    const float* xf = (ti < 3) ? (mem + (size_t)(b * 3 + ti) * 4096 * 256)
                               : (x + (size_t)b * 4096 * 256);
    const int tid = threadIdx.x;
    const int r = tid >> 2, cofs = (tid & 3) * 64;
    const float* src = xf + (size_t)(n0 + r) * 256 + cofs;
    #pragma unroll
    for (int i = 0; i < 16; ++i) {
      float4 v = *(const float4*)&src[i * 4];
      tile[r][cofs + i * 4 + 0] = v.x;
      tile[r][cofs + i * 4 + 1] = v.y;
      tile[r][cofs + i * 4 + 2] = v.z;
      tile[r][cofs + i * 4 + 3] = v.w;
    }
    __syncthreads();
    short* dst = xfT + ((size_t)bt * 256 + tid) * 4096 + n0;
    #pragma unroll
    for (int seg = 0; seg < 8; ++seg) {
      bf16x8 w;
      #pragma unroll
      for (int j = 0; j < 8; ++j) w[j] = f2b(tile[seg * 8 + j][tid]);
      *(bf16x8*)&dst[seg * 8] = w;
    }
  }
}

// ---------------- fused cluster front-end: cl GEMM + cosines + csz GEMM, LDS-only Acat ----------------
// Block = 64 flat rows (b,ti,nn). Phase A: cl = xf @ cwb^T (+coscl fold) -> Acatile[:,0:160].
// Phase B: z columns in regs (+cosz fold) -> Acatile[:,160:320]. Phase C: O = 0.5*Acatile@TT^T.
__global__ __launch_bounds__(256) void fused_csz(
    const float* __restrict__ x, const float* __restrict__ mem, const float* __restrict__ z,
    const short* __restrict__ cwb, const short* __restrict__ TT,
    const float* __restrict__ p1, const float* __restrict__ p2,
    float* __restrict__ csz, float* __restrict__ asg)
{
  __shared__ __align__(16) short Acatile[64 * 328];
  __shared__ float p1s[160], p2s[160];
  __shared__ float sred[4][16][9];
  __shared__ float czs[64];
  const int tid = threadIdx.x;
  const int r0 = blockIdx.x * 64;
  const int b = r0 >> 14;
  const int mmg = r0 & 16383;
  const int ti = mmg >> 12, nn = mmg & 4095;
  const float* Ab = ((ti < 3) ? (mem + (size_t)(b * 3 + ti) * 4096 * 256)
                              : (x + (size_t)b * 4096 * 256)) + (size_t)nn * 256;
  const int wave = tid >> 6, lane = tid & 63;
  const int t16 = lane & 15, quad = lane >> 4, k8 = quad * 8;

  // ---- z loads into regs first (HBM stream overlaps phase A MFMA) ----
  const int kr = tid >> 4, c4 = (tid & 15) * 4;
  float4 zv[10];
  #pragma unroll
  for (int it = 0; it < 10; ++it) {
    const int k = it * 16 + kr;
    zv[it] = make_float4(0.f, 0.f, 0.f, 0.f);
    if (k < 150) zv[it] = *(const float4*)&z[((size_t)b * 150 + k) * 16384 + mmg + c4];
  }
  if (tid < 160) {
    p2s[tid] = (tid < 150) ? p2[tid] : 0.f;
    p1s[tid] = (tid < 150) ? p1[tid] : 0.f;
  }

  // ---- phase A: cl GEMM (each wave: 16 rows x 160 cols, K=256); FULL unroll so all
  //      16 global A-loads issue ahead of the MFMA chain (occupancy is grid-limited,
  //      extra VGPRs are free at 2 blocks/CU) ----
  f32x4 acc[10];
  #pragma unroll
  for (int i = 0; i < 10; ++i) acc[i] = (f32x4){0.f, 0.f, 0.f, 0.f};
  {
    const float* ap = Ab + (size_t)(wave * 16 + t16) * 256 + k8;
    const short* bp = cwb + t16 * 256 + k8;
    #pragma unroll
    for (int ks = 0; ks < 8; ++ks) {
      float4 v0 = *(const float4*)&ap[ks * 32];
      float4 v1 = *(const float4*)&ap[ks * 32 + 4];
      bf16x8 a;
      a[0] = f2b(v0.x); a[1] = f2b(v0.y); a[2] = f2b(v0.z); a[3] = f2b(v0.w);
      a[4] = f2b(v1.x); a[5] = f2b(v1.y); a[6] = f2b(v1.z); a[7] = f2b(v1.w);
      #pragma unroll
      for (int nf = 0; nf < 10; ++nf) {
        bf16x8 bv = *(const bf16x8*)&bp[nf * 4096 + ks * 32];
        acc[nf] = __builtin_amdgcn_mfma_f32_16x16x32_bf16(a, bv, acc[nf], 0, 0, 0);
      }
    }
  }
  __syncthreads();   // p1s/p2s visible

  // ---- phase A cosine (per row, over 160 cols; padded cols are exact zeros) ----
  {
    float d[4] = {0.f, 0.f, 0.f, 0.f}, s[4] = {0.f, 0.f, 0.f, 0.f};
    float pn = 0.f;
    #pragma unroll
    for (int nf = 0; nf < 10; ++nf) {
      float a2 = p2s[nf * 16 + t16];
      pn += a2 * a2;
      #pragma unroll
      for (int r = 0; r < 4; ++r) {
        float v = acc[nf][r];
        d[r] = fmaf(v, a2, d[r]);
        s[r] = fmaf(v, v, s[r]);
      }
    }
    #pragma unroll
    for (int off = 1; off < 16; off <<= 1) {
      pn += __shfl_xor(pn, off);
      #pragma unroll
      for (int r = 0; r < 4; ++r) {
        d[r] += __shfl_xor(d[r], off);
        s[r] += __shfl_xor(s[r], off);
      }
    }
    const float spn = fmaxf(sqrtf(pn), 1e-12f);
    float cs[4];
    #pragma unroll
    for (int r = 0; r < 4; ++r) {
      float c = d[r] / (fmaxf(sqrtf(s[r]), 1e-12f) * spn);
      cs[r] = fminf(fmaxf(c, 0.f), 1.f);
    }
    #pragma unroll
    for (int nf = 0; nf < 10; ++nf)
      #pragma unroll
      for (int r = 0; r < 4; ++r)
        Acatile[(wave * 16 + quad * 4 + r) * 328 + nf * 16 + t16] = f2b(acc[nf][r] * cs[r]);
  }

  // ---- phase B: cosz reduce over k, scale, transpose-write cols 160:320 ----
  {
    float d[4] = {0.f, 0.f, 0.f, 0.f}, sv[4] = {0.f, 0.f, 0.f, 0.f};
    float pn = 0.f;
    #pragma unroll
    for (int it = 0; it < 10; ++it) {
      const int k = it * 16 + kr;
      const float a = p1s[k];
      d[0] = fmaf(zv[it].x, a, d[0]); d[1] = fmaf(zv[it].y, a, d[1]);
      d[2] = fmaf(zv[it].z, a, d[2]); d[3] = fmaf(zv[it].w, a, d[3]);
      sv[0] = fmaf(zv[it].x, zv[it].x, sv[0]); sv[1] = fmaf(zv[it].y, zv[it].y, sv[1]);
      sv[2] = fmaf(zv[it].z, zv[it].z, sv[2]); sv[3] = fmaf(zv[it].w, zv[it].w, sv[3]);
      pn = fmaf(a, a, pn);
    }
    #pragma unroll
    for (int off = 16; off < 64; off <<= 1) {
      pn += __shfl_xor(pn, off);
      #pragma unroll
      for (int r = 0; r < 4; ++r) {
        d[r] += __shfl_xor(d[r], off);
        sv[r] += __shfl_xor(sv[r], off);
      }
    }
    if ((lane >> 4) == 0) {
      #pragma unroll
      for (int r = 0; r < 4; ++r) {
        sred[wave][lane][r] = d[r];
        sred[wave][lane][4 + r] = sv[r];
      }
      sred[wave][lane][8] = pn;
    }
  }
  __syncthreads();
  if (tid < 64) {
    const int cg = tid >> 2, r = tid & 3;
    float dd = 0.f, ss = 0.f, pp = 0.f;
    #pragma unroll
    for (int w = 0; w < 4; ++w) {
      dd += sred[w][cg][r];
      ss += sred[w][cg][4 + r];
      pp += sred[w][cg][8];
    }
    float c = dd / (fmaxf(sqrtf(ss), 1e-12f) * fmaxf(sqrtf(pp), 1e-12f));
    czs[tid] = fminf(fmaxf(c, 0.f), 1.f);
  }
  __syncthreads();
  {
    const float cz0 = czs[c4 + 0], cz1 = czs[c4 + 1], cz2 = czs[c4 + 2], cz3 = czs[c4 + 3];
    #pragma unroll
    for (int it = 0; it < 10; ++it) {
      const int k = it * 16 + kr;
      Acatile[(c4 + 0) * 328 + 160 + k] = f2b(zv[it].x * cz0);
      Acatile[(c4 + 1) * 328 + 160 + k] = f2b(zv[it].y * cz1);
      Acatile[(c4 + 2) * 328 + 160 + k] = f2b(zv[it].z * cz2);
      Acatile[(c4 + 3) * 328 + 160 + k] = f2b(zv[it].w * cz3);
    }
  }
  __syncthreads();

  // ---- phase C: O = 0.5 * Acatile @ TT^T  (each wave: 32 rows x 80 cols, K=320) ----
  {
    const int wm = wave & 1, wn = wave >> 1;
    f32x4 c2[2][5];
    #pragma unroll
    for (int i = 0; i < 2; ++i)
      #pragma unroll
      for (int j = 0; j < 5; ++j)
        c2[i][j] = (f32x4){0.f, 0.f, 0.f, 0.f};
    const short* bp = TT + (size_t)(wn * 80 + t16) * 320 + k8;
    #pragma unroll 2
    for (int ks = 0; ks < 10; ++ks) {
      bf16x8 a0 = *(const bf16x8*)&Acatile[(wm * 32 + t16) * 328 + ks * 32 + k8];
      bf16x8 a1 = *(const bf16x8*)&Acatile[(wm * 32 + 16 + t16) * 328 + ks * 32 + k8];
      #pragma unroll
      for (int nf = 0; nf < 5; ++nf) {
        bf16x8 bv = *(const bf16x8*)&bp[nf * 5120 + ks * 32];
        c2[0][nf] = __builtin_amdgcn_mfma_f32_16x16x32_bf16(a0, bv, c2[0][nf], 0, 0, 0);
        c2[1][nf] = __builtin_amdgcn_mfma_f32_16x16x32_bf16(a1, bv, c2[1][nf], 0, 0, 0);
      }
    }
    #pragma unroll
    for (int nf = 0; nf < 5; ++nf) {
      const int kc = wn * 80 + nf * 16 + t16;
      if (kc < 150) {
        #pragma unroll
        for (int mf = 0; mf < 2; ++mf) {
          const int moff = wm * 32 + mf * 16 + quad * 4;
          float4 r4;
          r4.x = 0.5f * c2[mf][nf][0];
          r4.y = 0.5f * c2[mf][nf][1];
          r4.z = 0.5f * c2[mf][nf][2];
          r4.w = 0.5f * c2[mf][nf][3];
          *(float4*)&csz[((size_t)b * 150 + kc) * 16384 + mmg + moff] = r4;
          *(float4*)&asg[(((size_t)b * 4 + ti) * 150 + kc) * 4096 + nn + moff] = r4;
        }
      }
    }
  }
}

// ---------------- softmax stats + exp materialization (bf16) ----------------
// row = bt*150+k; writes ecsz[bt][160pad][4096] bf16 = exp(csz - rowmax); lr = rowsum
__global__ __launch_bounds__(256) void softmax_stats_e(
    const float* __restrict__ csz, float* __restrict__ lr_, short* __restrict__ ecsz)
{
  __shared__ float wred[8];
  const int row = blockIdx.x;
  const int bt = row / 150, k = row - bt * 150;
  const int b = bt >> 2, ti = bt & 3;
  const float* p = csz + ((size_t)b * 150 + k) * 16384 + ti * 4096;
  const int base = threadIdx.x * 16;
  float4 v[4];
  #pragma unroll
  for (int i = 0; i < 4; ++i) v[i] = *(const float4*)&p[base + i * 4];
  float mx = -1e30f;
  #pragma unroll
  for (int i = 0; i < 4; ++i)
    mx = fmaxf(mx, fmaxf(fmaxf(v[i].x, v[i].y), fmaxf(v[i].z, v[i].w)));
  #pragma unroll
  for (int off = 1; off < 64; off <<= 1) mx = fmaxf(mx, __shfl_xor(mx, off));
  const int wave = threadIdx.x >> 6, lane = threadIdx.x & 63;
  if (lane == 0) wred[wave] = mx;
  __syncthreads();
  mx = fmaxf(fmaxf(wred[0], wred[1]), fmaxf(wred[2], wred[3]));
  const float L = 1.4426950408889634f;
  float s = 0.f;
  bf16x8 e0, e1;
  #pragma unroll
  for (int i = 0; i < 2; ++i) {
    float a = exp2f((v[i].x - mx) * L);
    float bq = exp2f((v[i].y - mx) * L);
    float cq = exp2f((v[i].z - mx) * L);
    float dq = exp2f((v[i].w - mx) * L);
    s += a + bq + cq + dq;
    e0[i * 4 + 0] = f2b(a); e0[i * 4 + 1] = f2b(bq); e0[i * 4 + 2] = f2b(cq); e0[i * 4 + 3] = f2b(dq);
  }
  #pragma unroll
  for (int i = 2; i < 4; ++i) {
    float a = exp2f((v[i].x - mx) * L);
    float bq = exp2f((v[i].y - mx) * L);
    float cq = exp2f((v[i].z - mx) * L);
    float dq = exp2f((v[i].w - mx) * L);
    s += a + bq + cq + dq;
    e1[(i - 2) * 4 + 0] = f2b(a); e1[(i - 2) * 4 + 1] = f2b(bq);
    e1[(i - 2) * 4 + 2] = f2b(cq); e1[(i - 2) * 4 + 3] = f2b(dq);
  }
  #pragma unroll
  for (int off = 1; off < 64; off <<= 1) s += __shfl_xor(s, off);
  if (lane == 0) wred[4 + wave] = s;
  __syncthreads();
  short* er = ecsz + ((size_t)bt * 160 + k) * 4096 + base;
  *(bf16x8*)&er[0] = e0;
  *(bf16x8*)&er[8] = e1;
  if (threadIdx.x == 0) lr_[row] = wred[4] + wred[5] + wred[6] + wred[7];
}

// ---------------- cen numerator via MFMA + atomic split-K ----------------
// grid (2 chalf, 8 bt, 32 sp); block 256 = 4 waves; M=160(k) x N=128(c-half) x K=128(n)
__global__ __launch_bounds__(256) void gemm_cen_at(
    const short* __restrict__ ecsz, const short* __restrict__ xfT,
    float* __restrict__ cen)
{
  __shared__ __align__(16) short As[160 * 136];
  const int tid = threadIdx.x;
  const int chalf = blockIdx.x;
  const int bt = blockIdx.y;
  const int sp = blockIdx.z;
  const int n0 = sp * 128;
  const int wave = tid >> 6, lane = tid & 63;
  const int t16 = lane & 15, quad = lane >> 4, k8 = quad * 8;
  const int cbase = chalf * 128 + wave * 32;

  f32x4 acc[10][2];
  #pragma unroll
  for (int i = 0; i < 10; ++i) {
    acc[i][0] = (f32x4){0.f, 0.f, 0.f, 0.f};
    acc[i][1] = (f32x4){0.f, 0.f, 0.f, 0.f};
  }

  const short* erow = ecsz + (size_t)bt * 160 * 4096 + n0;
  // stage A: 160 rows x 128 k-cols (b128 in/out)
  #pragma unroll
  for (int p = 0; p < 10; ++p) {
    const int g = p * 256 + tid;
    const int row = g >> 4;
    const int col8 = (g & 15) * 8;
    *(bf16x8*)&As[row * 136 + col8] = *(const bf16x8*)&erow[(size_t)row * 4096 + col8];
  }
  __syncthreads();
  const short* xrow = xfT + (size_t)bt * 256 * 4096 + n0;
  #pragma unroll
  for (int kc = 0; kc < 4; ++kc) {
    bf16x8 b0 = *(const bf16x8*)&xrow[(size_t)(cbase + t16) * 4096 + kc * 32 + k8];
    bf16x8 b1 = *(const bf16x8*)&xrow[(size_t)(cbase + 16 + t16) * 4096 + kc * 32 + k8];
    #pragma unroll
    for (int mt = 0; mt < 10; ++mt) {
      bf16x8 aA = *(const bf16x8*)&As[(mt * 16 + t16) * 136 + kc * 32 + k8];
      acc[mt][0] = __builtin_amdgcn_mfma_f32_16x16x32_bf16(aA, b0, acc[mt][0], 0, 0, 0);
      acc[mt][1] = __builtin_amdgcn_mfma_f32_16x16x32_bf16(aA, b1, acc[mt][1], 0, 0, 0);
    }
  }
  #pragma unroll
  for (int mt = 0; mt < 10; ++mt) {
    #pragma unroll
    for (int r = 0; r < 4; ++r) {
      const int grow = mt * 16 + quad * 4 + r;
      if (grow < 150) {
        atomicAdd(&cen[((size_t)bt * 150 + grow) * 256 + cbase + t16], acc[mt][0][r]);
        atomicAdd(&cen[((size_t)bt * 150 + grow) * 256 + cbase + 16 + t16], acc[mt][1][r]);
      }
    }
  }
}

// ---------------- similarity gate + LN -> C_in (cen holds numerators; /lr here) ----------------
__global__ __launch_bounds__(256) void gate_ln(
    const float* __restrict__ cen, const float* __restrict__ lr_,
    const float* __restrict__ alpha_, const float* __restrict__ beta_,
    const float* __restrict__ nw, const float* __restrict__ nb, float* __restrict__ cin)
{
  __shared__ float red[256];
  int bk = blockIdx.x;
  int b = bk / 150, k = bk % 150;
  int c = threadIdx.x;
  const float* base = cen + ((size_t)b * 4 * 150) * 256;
  const float* lrb = lr_ + (size_t)b * 4 * 150;
  float lc  = base[((size_t)3 * 150 + k) * 256 + c] / lrb[3 * 150 + k];
  float p0  = base[((size_t)0 * 150 + k) * 256 + c] / lrb[0 * 150 + k];
  float p1v = base[((size_t)1 * 150 + k) * 256 + c] / lrb[1 * 150 + k];
  float p2v = base[((size_t)2 * 150 + k) * 256 + c] / lrb[2 * 150 + k];
  float nl = bred_sum(lc * lc, red);
  float q0 = bred_sum(p0 * p0, red);
  float q1 = bred_sum(p1v * p1v, red);
  float q2 = bred_sum(p2v * p2v, red);
  float d0 = bred_sum(lc * p0, red);
  float d1 = bred_sum(lc * p1v, red);
  float d2 = bred_sum(lc * p2v, red);
  float al = alpha_[0], be = beta_[0];
  float snl = sqrtf(nl);
  float g0 = 1.f / (1.f + expf(-(be + al * (d0 / fmaxf(snl * sqrtf(q0), 1e-8f)))));
  float g1 = 1.f / (1.f + expf(-(be + al * (d1 / fmaxf(snl * sqrtf(q1), 1e-8f)))));
  float g2 = 1.f / (1.f + expf(-(be + al * (d2 / fmaxf(snl * sqrtf(q2), 1e-8f)))));
  float ci = lc + g0 * p0 + g1 * p1v + g2 * p2v;
  float mu = bred_sum(ci, red) * (1.f / 256.f);
  float df = ci - mu;
  float var = bred_sum(df * df, red) * (1.f / 256.f);
  cin[(size_t)bk * 256 + c] = df * rsqrtf(var + 1e-5f) * nw[c] + nb[c];
}

// ---------------- merged k/v fp32 GEMM (M=300, N=256, K=256) ----------------
// grid (3, 8): blockIdx.y<4 -> K-proj, else V-proj; n0 = (y&3)*64
__global__ __launch_bounds__(256) void gemm_kv(
    const float* __restrict__ A,
    const float* __restrict__ Wk, const float* __restrict__ bk, float* __restrict__ outk,
    const float* __restrict__ Wv, const float* __restrict__ bv_, float* __restrict__ outv)
{
  __shared__ __align__(16) float As[16][132];
  __shared__ __align__(16) float Ws[16][68];
  const int tid = threadIdx.x;
  const int m0 = blockIdx.x * 128;
  const bool isv = blockIdx.y >= 4;
  const float* W = isv ? Wv : Wk;
  const float* bias = isv ? bv_ : bk;
  float* out = isv ? outv : outk;
  const int n0 = (blockIdx.y & 3) * 64;
  const int M = 300, K = 256;
  const int tm = tid & 15;
  const int tn = tid >> 4;
  float acc[8][4];
  #pragma unroll
  for (int i = 0; i < 8; ++i)
    #pragma unroll
    for (int j = 0; j < 4; ++j) acc[i][j] = 0.f;

  const int lr = tid >> 2;
  const int lk = (tid & 3) * 4;

  for (int k0 = 0; k0 < K; k0 += 16) {
    #pragma unroll
    for (int p = 0; p < 2; ++p) {
      int r = lr + p * 64;
      int gm = m0 + r;
      float4 v = make_float4(0.f, 0.f, 0.f, 0.f);
      if (gm < M) v = *(const float4*)&A[(size_t)gm * K + k0 + lk];
      As[lk + 0][r] = v.x; As[lk + 1][r] = v.y; As[lk + 2][r] = v.z; As[lk + 3][r] = v.w;
    }
    {
      float4 v = *(const float4*)&W[(size_t)(n0 + lr) * K + k0 + lk];
      Ws[lk + 0][lr] = v.x; Ws[lk + 1][lr] = v.y; Ws[lk + 2][lr] = v.z; Ws[lk + 3][lr] = v.w;
    }
    __syncthreads();
    #pragma unroll
    for (int kk = 0; kk < 16; ++kk) {
      float4 a0 = *(const float4*)&As[kk][tm * 8];
      float4 a1 = *(const float4*)&As[kk][tm * 8 + 4];
      float4 w0 = *(const float4*)&Ws[kk][tn * 4];
      float av[8] = {a0.x, a0.y, a0.z, a0.w, a1.x, a1.y, a1.z, a1.w};
      float wv[4] = {w0.x, w0.y, w0.z, w0.w};
      #pragma unroll
      for (int i = 0; i < 8; ++i)
        #pragma unroll
        for (int j = 0; j < 4; ++j)
          acc[i][j] = fmaf(av[i], wv[j], acc[i][j]);
    }
    __syncthreads();
  }
  float4 bv4 = *(const float4*)&bias[n0 + tn * 4];
  float bb[4] = {bv4.x, bv4.y, bv4.z, bv4.w};
  #pragma unroll
  for (int i = 0; i < 8; ++i) {
    int gm = m0 + tm * 8 + i;
    if (gm >= M) continue;
    float4 r;
    r.x = acc[i][0] + bb[0];
    r.y = acc[i][1] + bb[1];
    r.z = acc[i][2] + bb[2];
    r.w = acc[i][3] + bb[3];
    *(float4*)&out[(size_t)gm * 256 + n0 + tn * 4] = r;
  }
}

// ---------------- MFMA attention: 128 Q-rows/block, per (b,h); q bf16 in, o bf16 out ----------------
__global__ __launch_bounds__(256) void attn_mfma(
    const short* __restrict__ q, const float* __restrict__ ks, const float* __restrict__ vs,
    short* __restrict__ o)
{
  __shared__ __align__(16) short Ps[128 * 168];
  __shared__ __align__(16) short VT[32 * 168];
  __shared__ float lrow[128];
  const int tid = threadIdx.x;
  const int bid = blockIdx.x;
  const int ntile = bid & 31;
  const int bh = bid >> 5;
  const int b = bh >> 3, h = bh & 7;
  const int n0 = ntile * 128;
  const int wave = tid >> 6, lane = tid & 63;
  const int t16 = lane & 15, quad = lane >> 4;
  const int k8 = quad * 8;
  const int wr = wave * 32;

  for (int i = tid; i < 5120; i += 256) {
    int d = i / 160, kc = i - d * 160;
    VT[d * 168 + kc] = (kc < 150) ? f2b(vs[((size_t)b * 150 + kc) * 256 + h * 32 + d]) : (short)0;
  }

  bf16x8 aQ[2];
  #pragma unroll
  for (int mt = 0; mt < 2; ++mt)
    aQ[mt] = *(const bf16x8*)&q[((size_t)b * 4096 + n0 + wr + mt * 16 + t16) * 256 + h * 32 + k8];

  f32x4 s[2][10];
  #pragma unroll
  for (int ct = 0; ct < 10; ++ct) {
    const int c = ct * 16 + t16;
    bf16x8 bK = {0, 0, 0, 0, 0, 0, 0, 0};
    if (c < 150) {
      const float* kp = &ks[((size_t)b * 150 + c) * 256 + h * 32 + k8];
      float4 v0 = *(const float4*)&kp[0];
      float4 v1 = *(const float4*)&kp[4];
      bK[0] = f2b(v0.x); bK[1] = f2b(v0.y); bK[2] = f2b(v0.z); bK[3] = f2b(v0.w);
      bK[4] = f2b(v1.x); bK[5] = f2b(v1.y); bK[6] = f2b(v1.z); bK[7] = f2b(v1.w);
    }
    f32x4 zero = (f32x4){0.f, 0.f, 0.f, 0.f};
    s[0][ct] = __builtin_amdgcn_mfma_f32_16x16x32_bf16(aQ[0], bK, zero, 0, 0, 0);
    s[1][ct] = __builtin_amdgcn_mfma_f32_16x16x32_bf16(aQ[1], bK, zero, 0, 0, 0);
  }

  #pragma unroll
  for (int mt = 0; mt < 2; ++mt) {
    #pragma unroll
    for (int r = 0; r < 4; ++r) {
      float mx = -1e30f;
      #pragma unroll
      for (int ct = 0; ct < 10; ++ct) {
        float v = s[mt][ct][r];
        if (ct == 9 && t16 >= 6) { v = -1e30f; s[mt][ct][r] = v; }
        mx = fmaxf(mx, v);
      }
      mx = fmaxf(mx, __shfl_xor(mx, 1));
      mx = fmaxf(mx, __shfl_xor(mx, 2));
      mx = fmaxf(mx, __shfl_xor(mx, 4));
      mx = fmaxf(mx, __shfl_xor(mx, 8));
      float ls = 0.f;
      #pragma unroll
      for (int ct = 0; ct < 10; ++ct) {
        float e = expf(s[mt][ct][r] - mx);
        s[mt][ct][r] = e;
        ls += e;
      }
      ls += __shfl_xor(ls, 1);
      ls += __shfl_xor(ls, 2);
      ls += __shfl_xor(ls, 4);
      ls += __shfl_xor(ls, 8);
      if (t16 == 0) lrow[wr + mt * 16 + quad * 4 + r] = 1.f / ls;
      #pragma unroll
      for (int ct = 0; ct < 10; ++ct)
        Ps[(wr + mt * 16 + quad * 4 + r) * 168 + ct * 16 + t16] = f2b(s[mt][ct][r]);
    }
  }
  __syncthreads();

  f32x4 oacc[2][2];
  #pragma unroll
  for (int i = 0; i < 2; ++i)
    #pragma unroll
    for (int j = 0; j < 2; ++j)
      oacc[i][j] = (f32x4){0.f, 0.f, 0.f, 0.f};
  #pragma unroll
  for (int kstep = 0; kstep < 5; ++kstep) {
    bf16x8 bV0 = *(const bf16x8*)&VT[( 0 + t16) * 168 + kstep * 32 + k8];
    bf16x8 bV1 = *(const bf16x8*)&VT[(16 + t16) * 168 + kstep * 32 + k8];
    #pragma unroll
    for (int mt = 0; mt < 2; ++mt) {
      bf16x8 aP = *(const bf16x8*)&Ps[(wr + mt * 16 + t16) * 168 + kstep * 32 + k8];
      oacc[mt][0] = __builtin_amdgcn_mfma_f32_16x16x32_bf16(aP, bV0, oacc[mt][0], 0, 0, 0);
      oacc[mt][1] = __builtin_amdgcn_mfma_f32_16x16x32_bf16(aP, bV1, oacc[mt][1], 0, 0, 0);
    }
  }
  #pragma unroll
  for (int mt = 0; mt < 2; ++mt) {
    #pragma unroll
    for (int nt = 0; nt < 2; ++nt) {
      const int d = nt * 16 + t16;
      #pragma unroll
      for (int r = 0; r < 4; ++r) {
        const int row = wr + mt * 16 + quad * 4 + r;
        o[((size_t)b * 4096 + n0 + row) * 256 + h * 32 + d] = f2b(oacc[mt][nt][r] * lrow[row]);
      }
    }
  }
}

// ---------------- dst = res + LN(src), wave-per-row (row=256 cols) ----------------
__global__ __launch_bounds__(256) void ln_res(
    const float* __restrict__ src, const float* __restrict__ res,
    const float* __restrict__ nw, const float* __restrict__ nb, float* __restrict__ dst)
{
  const int wave = threadIdx.x >> 6;
  const int lane = threadIdx.x & 63;
  const size_t row = (size_t)blockIdx.x * 4 + wave;
  const int c = lane * 4;
  float4 v = *(const float4*)&src[row * 256 + c];
  float s  = v.x + v.y + v.z + v.w;
  float s2 = v.x * v.x + v.y * v.y + v.z * v.z + v.w * v.w;
  #pragma unroll
  for (int off = 1; off < 64; off <<= 1) {
    s  += __shfl_xor(s, off);
    s2 += __shfl_xor(s2, off);
  }
  const float mu = s * (1.f / 256.f);
  const float var = s2 * (1.f / 256.f) - mu * mu;
  const float inv = rsqrtf(var + 1e-5f);
  float4 w = *(const float4*)&nw[c];
  float4 bb = *(const float4*)&nb[c];
  float4 rr = *(const float4*)&res[row * 256 + c];
  float4 d;
  d.x = rr.x + (v.x - mu) * inv * w.x + bb.x;
  d.y = rr.y + (v.y - mu) * inv * w.y + bb.y;
  d.z = rr.z + (v.z - mu) * inv * w.z + bb.z;
  d.w = rr.w + (v.w - mu) * inv * w.w + bb.w;
  *(float4*)&dst[row * 256 + c] = d;
}

// ---------------- dual-output ln_res: fp32 dst + bf16 dstb (for fc1's bfA path) ----------------
__global__ __launch_bounds__(256) void ln_res_dual(
    const float* __restrict__ src, const float* __restrict__ res,
    const float* __restrict__ nw, const float* __restrict__ nb,
    float* __restrict__ dst, short* __restrict__ dstb)
{
  const int wave = threadIdx.x >> 6;
  const int lane = threadIdx.x & 63;
  const size_t row = (size_t)blockIdx.x * 4 + wave;
  const int c = lane * 4;
  float4 v = *(const float4*)&src[row * 256 + c];
  float s  = v.x + v.y + v.z + v.w;
  float s2 = v.x * v.x + v.y * v.y + v.z * v.z + v.w * v.w;
  #pragma unroll
  for (int off = 1; off < 64; off <<= 1) {
    s  += __shfl_xor(s, off);
    s2 += __shfl_xor(s2, off);
  }
  const float mu = s * (1.f / 256.f);
  const float var = s2 * (1.f / 256.f) - mu * mu;
  const float inv = rsqrtf(var + 1e-5f);
  float4 w = *(const float4*)&nw[c];
  float4 bb = *(const float4*)&nb[c];
  float4 rr = *(const float4*)&res[row * 256 + c];
  float4 d;
  d.x = rr.x + (v.x - mu) * inv * w.x + bb.x;
  d.y = rr.y + (v.y - mu) * inv * w.y + bb.y;
  d.z = rr.z + (v.z - mu) * inv * w.z + bb.z;
  d.w = rr.w + (v.w - mu) * inv * w.w + bb.w;
  *(float4*)&dst[row * 256 + c] = d;
  bf16x4 db;
  db[0] = f2b(d.x); db[1] = f2b(d.y); db[2] = f2b(d.z); db[3] = f2b(d.w);
  *(bf16x4*)&dstb[row * 256 + c] = db;
}

// ---------------- depthwise 3x3 conv + bias + exact gelu, 4 pixels/block, bf16 out ----------------
// grid 2048 = b(2) x y(64) x xg(16); each block does pixels (y, 4*xg .. 4*xg+3),
// 256 threads x 4 channels. 3x6 tap window shared across the 4 outputs.
__global__ __launch_bounds__(256) void conv_gelu(
    const float* __restrict__ h, const float* __restrict__ wt, const float* __restrict__ bias,
    short* __restrict__ hc)
{
  const int bid = blockIdx.x;
  const int xg = bid & 15;
  const int y  = (bid >> 4) & 63;
  const int b  = bid >> 10;
  const int x0 = xg * 4;
  const int c4 = threadIdx.x * 4;
  const float* hb = h + ((size_t)b * 4096) * 1024 + c4;

  float4 tap[3][6];
  #pragma unroll
  for (int dy = 0; dy < 3; ++dy) {
    const int yy = y + dy - 1;
    #pragma unroll
    for (int dx = 0; dx < 6; ++dx) {
      const int xv = x0 + dx - 1;
      tap[dy][dx] = make_float4(0.f, 0.f, 0.f, 0.f);
      if (yy >= 0 && yy <= 63 && xv >= 0 && xv <= 63)
        tap[dy][dx] = *(const float4*)&hb[(size_t)(yy * 64 + xv) * 1024];
    }
  }
  float4 wv[3][3];
  #pragma unroll
  for (int dy = 0; dy < 3; ++dy)
    #pragma unroll
    for (int dx = 0; dx < 3; ++dx)
      wv[dy][dx] = *(const float4*)&wt[(dy * 3 + dx) * 1024 + c4];
  const float4 bv = *(const float4*)&bias[c4];

  #pragma unroll
  for (int p = 0; p < 4; ++p) {
    float4 acc = bv;
    #pragma unroll
    for (int dy = 0; dy < 3; ++dy) {
      #pragma unroll
      for (int dx = 0; dx < 3; ++dx) {
        const float4 hv = tap[dy][p + dx];
        const float4 w = wv[dy][dx];
        acc.x = fmaf(hv.x, w.x, acc.x);
        acc.y = fmaf(hv.y, w.y, acc.y);
        acc.z = fmaf(hv.z, w.z, acc.z);
        acc.w = fmaf(hv.w, w.w, acc.w);
      }
    }
    bf16x4 g;
    g[0] = f2b(0.5f * acc.x * (1.f + erff(acc.x * 0.70710678118654752f)));
    g[1] = f2b(0.5f * acc.y * (1.f + erff(acc.y * 0.70710678118654752f)));
    g[2] = f2b(0.5f * acc.z * (1.f + erff(acc.z * 0.70710678118654752f)));
    g[3] = f2b(0.5f * acc.w * (1.f + erff(acc.w * 0.70710678118654752f)));
    *(bf16x4*)&hc[((size_t)b * 4096 + y * 64 + x0 + p) * 1024 + c4] = g;
  }
}

extern "C" void kernel_launch(void* const* d_in, const int* in_sizes, int n_in,
                              void* d_out, int out_size, void* d_ws, size_t ws_size,
                              hipStream_t stream)
{
  (void)in_sizes; (void)n_in; (void)out_size; (void)ws_size;
  const float* x    = (const float*)d_in[0];
  const float* z    = (const float*)d_in[1];
  const float* mem  = (const float*)d_in[2];
  const float* cw   = (const float*)d_in[3];
  const float* p1   = (const float*)d_in[4];
  const float* tdt1 = (const float*)d_in[5];
  const float* p2   = (const float*)d_in[6];
  const float* tdt2 = (const float*)d_in[7];
  const float* sal  = (const float*)d_in[8];
  const float* sbe  = (const float*)d_in[9];
  const float* q_w  = (const float*)d_in[10];
  const float* q_b  = (const float*)d_in[11];
  const float* k_w  = (const float*)d_in[12];
  const float* k_b  = (const float*)d_in[13];
  const float* v_w  = (const float*)d_in[14];
  const float* v_b  = (const float*)d_in[15];
  const float* pj_w = (const float*)d_in[16];
  const float* pj_b = (const float*)d_in[17];
  const float* nw   = (const float*)d_in[18];
  const float* nb   = (const float*)d_in[19];
  const float* f1w  = (const float*)d_in[20];
  const float* f1b  = (const float*)d_in[21];
  const float* dww  = (const float*)d_in[22];
  const float* dwb  = (const float*)d_in[23];
  const float* f2w  = (const float*)d_in[24];
  const float* f2b_ = (const float*)d_in[25];

  float* out = (float*)d_out;                  // (2,4096,256)
  float* csz = out + 2097152;                  // (2,150,16384)
  float* asg = csz + 4915200;                  // (2,4,150,4096)

  float* ws    = (float*)d_ws;
  short* ecsz  = (short*)ws;         // 5,242,880 shorts, written by softmax step
  short* TT    = (short*)(ws + 5242880);   // 160x320 bf16 = 25,600 float-slots
  short* cwb   = (short*)(ws + 5275648);   // 160x256 bf16 = 20,480 float-slots
  float* lr_   = ws + 5308416;       // 1,200
  float* cen   = ws + 5310816;       // 307,200
  float* cin   = ws + 5618016;       // 76,800
  short* q     = (short*)(ws + 5694816);   // 8192x256 bf16 = 1,048,576 float-slots
  float* ksb   = ws + 7791968;       // 76,800
  float* vsb   = ws + 7868768;       // 76,800
  short* o     = (short*)(ws + 7945568);   // 8192x256 bf16 (ends 8,994,144)
  short* xfT   = (short*)(ws + 10042720);  // 8x256x4096 bf16 = 4,194,304 float-slots (ends 14,237,024; dead after cen)
  float* h     = ws;                 // 8,388,608 reuse (ecsz/TT/cwb/q dead by fc1)
  short* hc    = (short*)(ws + 8388608);   // 8,388,608 shorts = 4,194,304 float-slots
  short* out1b = (short*)(ws + 14237024);  // 8192x256 bf16 = 1,048,576 float-slots (ends 15,285,600; xfT dead)
  float* tmp   = ws + 16777216;
  float* out1  = ws + 18874368;
  float* wt    = ws + 20971520;      // 9,216

  dim3 blk(256);
  // 1. merged weight packs (cwb/TT/wt) + xf bf16 transpose — one launch
  prep_all<<<dim3(712), blk, 0, stream>>>(cw, tdt2, tdt1, dww, x, mem, cwb, TT, wt, xfT);
  // 2. fused cluster front-end: cl GEMM + cosines + csz GEMM (full-unroll phase A)
  fused_csz<<<dim3(512), blk, 0, stream>>>(x, mem, z, cwb, TT, p1, p2, csz, asg);
  // 3. softmax stats + exp(csz-m) materialized bf16
  softmax_stats_e<<<dim3(1200), blk, 0, stream>>>(csz, lr_, ecsz);
  // 4. cen numerators via MFMA + atomics (cen zeroed first)
  hipMemsetAsync(cen, 0, (size_t)1200 * 256 * sizeof(float), stream);
  gemm_cen_at<<<dim3(2, 8, 32), blk, 0, stream>>>(ecsz, xfT, cen);
  // 5. gate + LN -> C_in (divides by lr)
  gate_ln<<<dim3(300), blk, 0, stream>>>(cen, lr_, sal, sbe, nw, nb, cin);
  // 6. q (MFMA, bf16 out) + merged k/v (one launch)
  gemm_mfma_bfout<<<dim3(128, 4), blk, 0, stream>>>(x, q_w, q_b, q, 8192, 256, 256, 0.17677669529663687f);
  gemm_kv<<<dim3(3, 8), blk, 0, stream>>>(cin, k_w, k_b, ksb, v_w, v_b, vsb);
  // 7. attention [MFMA]; o bf16
  attn_mfma<<<dim3(512), blk, 0, stream>>>(q, ksb, vsb, o);
  // 8. proj (bf16 A) + LN + residual (dual out: fp32 for residual, bf16 for fc1 A)
  gemm_mfma_bfA<<<dim3(128, 4), blk, 0, stream>>>(o, pj_w, pj_b, tmp, 8192, 256, 256, 1.f);
  ln_res_dual<<<dim3(2048), blk, 0, stream>>>(tmp, x, nw, nb, out1, out1b);
  // 9. MLP (fc1 consumes bf16 out1b — same f2b rounding, applied once instead of 16x)
  gemm_mfma_bfA<<<dim3(128, 16), blk, 0, stream>>>(out1b, f1w, f1b, h, 8192, 1024, 256, 1.f);
  conv_gelu<<<dim3(2048), blk, 0, stream>>>(h, wt, dwb, hc);
  gemm_mfma_bfA<<<dim3(128, 4), blk, 0, stream>>>(hc, f2w, f2b_, tmp, 8192, 256, 1024, 1.f);
  ln_res<<<dim3(2048), blk, 0, stream>>>(tmp, out1, nw, nb, out);
}

// Round 11
// 382.373 us; speedup vs baseline: 1.0154x; 1.0077x over previous
//
#include <hip/hip_runtime.h>
#include <math.h>

// Dims: B=2, N=4096, C=256, nc=150, T=4, TN=16384, heads=8, hd=32, hid=1024, H=W=64

typedef __attribute__((ext_vector_type(8))) short bf16x8;
typedef __attribute__((ext_vector_type(4))) short bf16x4;
typedef __attribute__((ext_vector_type(4))) float f32x4;

__device__ __forceinline__ short f2b(float f) {
  union { float f; unsigned int u; } c; c.f = f;
  unsigned int r = (c.u + 0x7fffu + ((c.u >> 16) & 1u)) >> 16;
  return (short)r;
}

// ---------------- block reduction helpers (blockDim.x == 256) ----------------
__device__ __forceinline__ float bred_sum(float v, float* red) {
  int tid = threadIdx.x;
  red[tid] = v; __syncthreads();
  #pragma unroll
  for (int s = 128; s > 0; s >>= 1) {
    if (tid < s) red[tid] += red[tid + s];
    __syncthreads();
  }
  float r = red[0]; __syncthreads();
  return r;
}

// ---------------- bf16 MFMA GEMM, 64x64 tile: out[m][n] = alpha*(A@W^T + bias) ----------------
// grid (M/64, N/64); 4 waves: wm=row-half(32), wn=col-half(32), 2x2 16x16 frags each.
__global__ __launch_bounds__(256) void gemm_mfma(
    const float* __restrict__ A, const float* __restrict__ W,
    const float* __restrict__ bias, float* __restrict__ out,
    int M, int N, int K, float alpha)
{
  __shared__ __align__(16) short As[64 * 72];
  __shared__ __align__(16) short Bs[64 * 72];
  const int tid = threadIdx.x;
  const int m0 = blockIdx.x * 64;
  const int n0 = blockIdx.y * 64;
  const int wave = tid >> 6;
  const int lane = tid & 63;
  const int wm = wave & 1, wn = wave >> 1;
  const int t16 = lane & 15;
  const int k8 = (lane >> 4) * 8;

  f32x4 acc[2][2];
  #pragma unroll
  for (int i = 0; i < 2; ++i)
    #pragma unroll
    for (int j = 0; j < 2; ++j)
      acc[i][j] = (f32x4){0.f, 0.f, 0.f, 0.f};

  const int sr = tid >> 2;
  const int sk = (tid & 3) * 16;

  for (int k0 = 0; k0 < K; k0 += 64) {
    {
      const float* ap = &A[(size_t)(m0 + sr) * K + k0 + sk];
      float4 v0 = *(const float4*)&ap[0];
      float4 v1 = *(const float4*)&ap[4];
      float4 v2 = *(const float4*)&ap[8];
      float4 v3 = *(const float4*)&ap[12];
      bf16x8 w0, w1;
      w0[0] = f2b(v0.x); w0[1] = f2b(v0.y); w0[2] = f2b(v0.z); w0[3] = f2b(v0.w);
      w0[4] = f2b(v1.x); w0[5] = f2b(v1.y); w0[6] = f2b(v1.z); w0[7] = f2b(v1.w);
      w1[0] = f2b(v2.x); w1[1] = f2b(v2.y); w1[2] = f2b(v2.z); w1[3] = f2b(v2.w);
      w1[4] = f2b(v3.x); w1[5] = f2b(v3.y); w1[6] = f2b(v3.z); w1[7] = f2b(v3.w);
      *(bf16x8*)&As[sr * 72 + sk] = w0;
      *(bf16x8*)&As[sr * 72 + sk + 8] = w1;
    }
    {
      const float* wp = &W[(size_t)(n0 + sr) * K + k0 + sk];
      float4 v0 = *(const float4*)&wp[0];
      float4 v1 = *(const float4*)&wp[4];
      float4 v2 = *(const float4*)&wp[8];
      float4 v3 = *(const float4*)&wp[12];
      bf16x8 w0, w1;
      w0[0] = f2b(v0.x); w0[1] = f2b(v0.y); w0[2] = f2b(v0.z); w0[3] = f2b(v0.w);
      w0[4] = f2b(v1.x); w0[5] = f2b(v1.y); w0[6] = f2b(v1.z); w0[7] = f2b(v1.w);
      w1[0] = f2b(v2.x); w1[1] = f2b(v2.y); w1[2] = f2b(v2.z); w1[3] = f2b(v2.w);
      w1[4] = f2b(v3.x); w1[5] = f2b(v3.y); w1[6] = f2b(v3.z); w1[7] = f2b(v3.w);
      *(bf16x8*)&Bs[sr * 72 + sk] = w0;
      *(bf16x8*)&Bs[sr * 72 + sk + 8] = w1;
    }
    __syncthreads();
    #pragma unroll
    for (int ks = 0; ks < 2; ++ks) {
      const int kofs = ks * 32 + k8;
      bf16x8 af0 = *(const bf16x8*)&As[(wm * 32 +  0 + t16) * 72 + kofs];
      bf16x8 af1 = *(const bf16x8*)&As[(wm * 32 + 16 + t16) * 72 + kofs];
      bf16x8 bf0 = *(const bf16x8*)&Bs[(wn * 32 +  0 + t16) * 72 + kofs];
      bf16x8 bf1 = *(const bf16x8*)&Bs[(wn * 32 + 16 + t16) * 72 + kofs];
      acc[0][0] = __builtin_amdgcn_mfma_f32_16x16x32_bf16(af0, bf0, acc[0][0], 0, 0, 0);
      acc[1][0] = __builtin_amdgcn_mfma_f32_16x16x32_bf16(af1, bf0, acc[1][0], 0, 0, 0);
      acc[0][1] = __builtin_amdgcn_mfma_f32_16x16x32_bf16(af0, bf1, acc[0][1], 0, 0, 0);
      acc[1][1] = __builtin_amdgcn_mfma_f32_16x16x32_bf16(af1, bf1, acc[1][1], 0, 0, 0);
    }
    __syncthreads();
  }
  const int r4 = (lane >> 4) * 4;
  #pragma unroll
  for (int ni = 0; ni < 2; ++ni) {
    const int gcol = n0 + wn * 32 + ni * 16 + t16;
    const float bb = bias[gcol];
    #pragma unroll
    for (int mi = 0; mi < 2; ++mi) {
      #pragma unroll
      for (int r = 0; r < 4; ++r) {
        const int gm = m0 + wm * 32 + mi * 16 + r4 + r;
        out[(size_t)gm * N + gcol] = alpha * (acc[mi][ni][r] + bb);
      }
    }
  }
}

// ---------------- fp32-A MFMA GEMM, bf16 OUT (q-proj: consumer rounds anyway) ----------------
__global__ __launch_bounds__(256) void gemm_mfma_bfout(
    const float* __restrict__ A, const float* __restrict__ W,
    const float* __restrict__ bias, short* __restrict__ out,
    int M, int N, int K, float alpha)
{
  __shared__ __align__(16) short As[64 * 72];
  __shared__ __align__(16) short Bs[64 * 72];
  const int tid = threadIdx.x;
  const int m0 = blockIdx.x * 64;
  const int n0 = blockIdx.y * 64;
  const int wave = tid >> 6;
  const int lane = tid & 63;
  const int wm = wave & 1, wn = wave >> 1;
  const int t16 = lane & 15;
  const int k8 = (lane >> 4) * 8;

  f32x4 acc[2][2];
  #pragma unroll
  for (int i = 0; i < 2; ++i)
    #pragma unroll
    for (int j = 0; j < 2; ++j)
      acc[i][j] = (f32x4){0.f, 0.f, 0.f, 0.f};

  const int sr = tid >> 2;
  const int sk = (tid & 3) * 16;

  for (int k0 = 0; k0 < K; k0 += 64) {
    {
      const float* ap = &A[(size_t)(m0 + sr) * K + k0 + sk];
      float4 v0 = *(const float4*)&ap[0];
      float4 v1 = *(const float4*)&ap[4];
      float4 v2 = *(const float4*)&ap[8];
      float4 v3 = *(const float4*)&ap[12];
      bf16x8 w0, w1;
      w0[0] = f2b(v0.x); w0[1] = f2b(v0.y); w0[2] = f2b(v0.z); w0[3] = f2b(v0.w);
      w0[4] = f2b(v1.x); w0[5] = f2b(v1.y); w0[6] = f2b(v1.z); w0[7] = f2b(v1.w);
      w1[0] = f2b(v2.x); w1[1] = f2b(v2.y); w1[2] = f2b(v2.z); w1[3] = f2b(v2.w);
      w1[4] = f2b(v3.x); w1[5] = f2b(v3.y); w1[6] = f2b(v3.z); w1[7] = f2b(v3.w);
      *(bf16x8*)&As[sr * 72 + sk] = w0;
      *(bf16x8*)&As[sr * 72 + sk + 8] = w1;
    }
    {
      const float* wp = &W[(size_t)(n0 + sr) * K + k0 + sk];
      float4 v0 = *(const float4*)&wp[0];
      float4 v1 = *(const float4*)&wp[4];
      float4 v2 = *(const float4*)&wp[8];
      float4 v3 = *(const float4*)&wp[12];
      bf16x8 w0, w1;
      w0[0] = f2b(v0.x); w0[1] = f2b(v0.y); w0[2] = f2b(v0.z); w0[3] = f2b(v0.w);
      w0[4] = f2b(v1.x); w0[5] = f2b(v1.y); w0[6] = f2b(v1.z); w0[7] = f2b(v1.w);
      w1[0] = f2b(v2.x); w1[1] = f2b(v2.y); w1[2] = f2b(v2.z); w1[3] = f2b(v2.w);
      w1[4] = f2b(v3.x); w1[5] = f2b(v3.y); w1[6] = f2b(v3.z); w1[7] = f2b(v3.w);
      *(bf16x8*)&Bs[sr * 72 + sk] = w0;
      *(bf16x8*)&Bs[sr * 72 + sk + 8] = w1;
    }
    __syncthreads();
    #pragma unroll
    for (int ks = 0; ks < 2; ++ks) {
      const int kofs = ks * 32 + k8;
      bf16x8 af0 = *(const bf16x8*)&As[(wm * 32 +  0 + t16) * 72 + kofs];
      bf16x8 af1 = *(const bf16x8*)&As[(wm * 32 + 16 + t16) * 72 + kofs];
      bf16x8 bf0 = *(const bf16x8*)&Bs[(wn * 32 +  0 + t16) * 72 + kofs];
      bf16x8 bf1 = *(const bf16x8*)&Bs[(wn * 32 + 16 + t16) * 72 + kofs];
      acc[0][0] = __builtin_amdgcn_mfma_f32_16x16x32_bf16(af0, bf0, acc[0][0], 0, 0, 0);
      acc[1][0] = __builtin_amdgcn_mfma_f32_16x16x32_bf16(af1, bf0, acc[1][0], 0, 0, 0);
      acc[0][1] = __builtin_amdgcn_mfma_f32_16x16x32_bf16(af0, bf1, acc[0][1], 0, 0, 0);
      acc[1][1] = __builtin_amdgcn_mfma_f32_16x16x32_bf16(af1, bf1, acc[1][1], 0, 0, 0);
    }
    __syncthreads();
  }
  const int r4 = (lane >> 4) * 4;
  #pragma unroll
  for (int ni = 0; ni < 2; ++ni) {
    const int gcol = n0 + wn * 32 + ni * 16 + t16;
    const float bb = bias[gcol];
    #pragma unroll
    for (int mi = 0; mi < 2; ++mi) {
      #pragma unroll
      for (int r = 0; r < 4; ++r) {
        const int gm = m0 + wm * 32 + mi * 16 + r4 + r;
        out[(size_t)gm * N + gcol] = f2b(alpha * (acc[mi][ni][r] + bb));
      }
    }
  }
}

// ---------------- bf16-A MFMA GEMM, 64x64 tile (proj/fc1/fc2: A pre-rounded bf16) ----------------
__global__ __launch_bounds__(256) void gemm_mfma_bfA(
    const short* __restrict__ A, const float* __restrict__ W,
    const float* __restrict__ bias, float* __restrict__ out,
    int M, int N, int K, float alpha)
{
  __shared__ __align__(16) short As[64 * 72];
  __shared__ __align__(16) short Bs[64 * 72];
  const int tid = threadIdx.x;
  const int m0 = blockIdx.x * 64;
  const int n0 = blockIdx.y * 64;
  const int wave = tid >> 6;
  const int lane = tid & 63;
  const int wm = wave & 1, wn = wave >> 1;
  const int t16 = lane & 15;
  const int k8 = (lane >> 4) * 8;

  f32x4 acc[2][2];
  #pragma unroll
  for (int i = 0; i < 2; ++i)
    #pragma unroll
    for (int j = 0; j < 2; ++j)
      acc[i][j] = (f32x4){0.f, 0.f, 0.f, 0.f};

  const int sr = tid >> 2;
  const int sk = (tid & 3) * 16;

  for (int k0 = 0; k0 < K; k0 += 64) {
    {
      const short* ap = &A[(size_t)(m0 + sr) * K + k0 + sk];
      *(bf16x8*)&As[sr * 72 + sk] = *(const bf16x8*)&ap[0];
      *(bf16x8*)&As[sr * 72 + sk + 8] = *(const bf16x8*)&ap[8];
    }
    {
      const float* wp = &W[(size_t)(n0 + sr) * K + k0 + sk];
      float4 v0 = *(const float4*)&wp[0];
      float4 v1 = *(const float4*)&wp[4];
      float4 v2 = *(const float4*)&wp[8];
      float4 v3 = *(const float4*)&wp[12];
      bf16x8 w0, w1;
      w0[0] = f2b(v0.x); w0[1] = f2b(v0.y); w0[2] = f2b(v0.z); w0[3] = f2b(v0.w);
      w0[4] = f2b(v1.x); w0[5] = f2b(v1.y); w0[6] = f2b(v1.z); w0[7] = f2b(v1.w);
      w1[0] = f2b(v2.x); w1[1] = f2b(v2.y); w1[2] = f2b(v2.z); w1[3] = f2b(v2.w);
      w1[4] = f2b(v3.x); w1[5] = f2b(v3.y); w1[6] = f2b(v3.z); w1[7] = f2b(v3.w);
      *(bf16x8*)&Bs[sr * 72 + sk] = w0;
      *(bf16x8*)&Bs[sr * 72 + sk + 8] = w1;
    }
    __syncthreads();
    #pragma unroll
    for (int ks = 0; ks < 2; ++ks) {
      const int kofs = ks * 32 + k8;
      bf16x8 af0 = *(const bf16x8*)&As[(wm * 32 +  0 + t16) * 72 + kofs];
      bf16x8 af1 = *(const bf16x8*)&As[(wm * 32 + 16 + t16) * 72 + kofs];
      bf16x8 bf0 = *(const bf16x8*)&Bs[(wn * 32 +  0 + t16) * 72 + kofs];
      bf16x8 bf1 = *(const bf16x8*)&Bs[(wn * 32 + 16 + t16) * 72 + kofs];
      acc[0][0] = __builtin_amdgcn_mfma_f32_16x16x32_bf16(af0, bf0, acc[0][0], 0, 0, 0);
      acc[1][0] = __builtin_amdgcn_mfma_f32_16x16x32_bf16(af1, bf0, acc[1][0], 0, 0, 0);
      acc[0][1] = __builtin_amdgcn_mfma_f32_16x16x32_bf16(af0, bf1, acc[0][1], 0, 0, 0);
      acc[1][1] = __builtin_amdgcn_mfma_f32_16x16x32_bf16(af1, bf1, acc[1][1], 0, 0, 0);
    }
    __syncthreads();
  }
  const int r4 = (lane >> 4) * 4;
  #pragma unroll
  for (int ni = 0; ni < 2; ++ni) {
    const int gcol = n0 + wn * 32 + ni * 16 + t16;
    const float bb = bias[gcol];
    #pragma unroll
    for (int mi = 0; mi < 2; ++mi) {
      #pragma unroll
      for (int r = 0; r < 4; ++r) {
        const int gm = m0 + wm * 32 + mi * 16 + r4 + r;
        out[(size_t)gm * N + gcol] = alpha * (acc[mi][ni][r] + bb);
      }
    }
  }
}

// ---------------- merged prep (bid<200) + xf transpose (bid>=200) ----------------
// prep: cwb[160][256] bf16 (cw zero-padded), TT[160][320] bf16, wt[tap][1024].
// xf_t: xfT[bt][c][n] bf16 (8 x 256 x 4096), bt = (bid-200)>>6, n0 = ((bid-200)&63)*64.
__global__ __launch_bounds__(256) void prep_all(
    const float* __restrict__ cw, const float* __restrict__ tdt2, const float* __restrict__ tdt1,
    const float* __restrict__ dww, const float* __restrict__ x, const float* __restrict__ mem,
    short* __restrict__ cwb, short* __restrict__ TT, float* __restrict__ wt,
    short* __restrict__ xfT)
{
  if (blockIdx.x < 200) {
    int idx = blockIdx.x * 256 + threadIdx.x;
    if (idx < 160 * 256) {
      int kc = idx >> 8, k = idx & 255;
      float v = (kc < 150) ? cw[kc * 256 + k] : 0.f;
      cwb[idx] = f2b(v);
    }
    if (idx < 160 * 320) {
      int kc = idx / 320, kk = idx - kc * 320;
      float t = 0.f;
      if (kc < 150) {
        if (kk < 150) t = tdt2[kk * 150 + kc];
        else if (kk >= 160 && kk < 310) t = tdt1[(kk - 160) * 150 + kc];
      }
      TT[idx] = f2b(t);
    }
    if (idx < 9216) {
      int ch = idx / 9, tap = idx - ch * 9;
      wt[tap * 1024 + ch] = dww[idx];
    }
  } else {
    __shared__ float tile[64][257];
    const int bid = blockIdx.x - 200;
    const int bt = bid >> 6;
    const int n0 = (bid & 63) * 64;
    const int b = bt >> 2, ti = bt & 3;
    const float* xf = (ti < 3) ? (mem + (size_t)(b * 3 + ti) * 4096 * 256)
                               : (x + (size_t)b * 4096 * 256);
    const int tid = threadIdx.x;
    const int r = tid >> 2, cofs = (tid & 3) * 64;
    const float* src = xf + (size_t)(n0 + r) * 256 + cofs;
    #pragma unroll
    for (int i = 0; i < 16; ++i) {
      float4 v = *(const float4*)&src[i * 4];
      tile[r][cofs + i * 4 + 0] = v.x;
      tile[r][cofs + i * 4 + 1] = v.y;
      tile[r][cofs + i * 4 + 2] = v.z;
      tile[r][cofs + i * 4 + 3] = v.w;
    }
    __syncthreads();
    short* dst = xfT + ((size_t)bt * 256 + tid) * 4096 + n0;
    #pragma unroll
    for (int seg = 0; seg < 8; ++seg) {
      bf16x8 w;
      #pragma unroll
      for (int j = 0; j < 8; ++j) w[j] = f2b(tile[seg * 8 + j][tid]);
      *(bf16x8*)&dst[seg * 8] = w;
    }
  }
}

// ---------------- fused cluster front-end: cl GEMM + cosines + csz GEMM, LDS-only Acat ----------------
// Block = 64 flat rows (b,ti,nn). Phase A: cl = xf @ cwb^T (+coscl fold) -> Acatile[:,0:160].
// Phase B: z columns in regs (+cosz fold) -> Acatile[:,160:320]. Phase C: O = 0.5*Acatile@TT^T.
__global__ __launch_bounds__(256) void fused_csz(
    const float* __restrict__ x, const float* __restrict__ mem, const float* __restrict__ z,
    const short* __restrict__ cwb, const short* __restrict__ TT,
    const float* __restrict__ p1, const float* __restrict__ p2,
    float* __restrict__ csz, float* __restrict__ asg)
{
  __shared__ __align__(16) short Acatile[64 * 328];
  __shared__ float p1s[160], p2s[160];
  __shared__ float sred[4][16][9];
  __shared__ float czs[64];
  const int tid = threadIdx.x;
  const int r0 = blockIdx.x * 64;
  const int b = r0 >> 14;
  const int mmg = r0 & 16383;
  const int ti = mmg >> 12, nn = mmg & 4095;
  const float* Ab = ((ti < 3) ? (mem + (size_t)(b * 3 + ti) * 4096 * 256)
                              : (x + (size_t)b * 4096 * 256)) + (size_t)nn * 256;
  const int wave = tid >> 6, lane = tid & 63;
  const int t16 = lane & 15, quad = lane >> 4, k8 = quad * 8;

  // ---- z loads into regs first (HBM stream overlaps phase A MFMA) ----
  const int kr = tid >> 4, c4 = (tid & 15) * 4;
  float4 zv[10];
  #pragma unroll
  for (int it = 0; it < 10; ++it) {
    const int k = it * 16 + kr;
    zv[it] = make_float4(0.f, 0.f, 0.f, 0.f);
    if (k < 150) zv[it] = *(const float4*)&z[((size_t)b * 150 + k) * 16384 + mmg + c4];
  }
  if (tid < 160) {
    p2s[tid] = (tid < 150) ? p2[tid] : 0.f;
    p1s[tid] = (tid < 150) ? p1[tid] : 0.f;
  }

  // ---- phase A: cl GEMM (each wave: 16 rows x 160 cols, K=256); unroll 2 = verified
  //      47 µs config (full unroll regressed: compiler minimizes liveness, loses pipeline) ----
  f32x4 acc[10];
  #pragma unroll
  for (int i = 0; i < 10; ++i) acc[i] = (f32x4){0.f, 0.f, 0.f, 0.f};
  {
    const float* ap = Ab + (size_t)(wave * 16 + t16) * 256 + k8;
    const short* bp = cwb + t16 * 256 + k8;
    #pragma unroll 2
    for (int ks = 0; ks < 8; ++ks) {
      float4 v0 = *(const float4*)&ap[ks * 32];
      float4 v1 = *(const float4*)&ap[ks * 32 + 4];
      bf16x8 a;
      a[0] = f2b(v0.x); a[1] = f2b(v0.y); a[2] = f2b(v0.z); a[3] = f2b(v0.w);
      a[4] = f2b(v1.x); a[5] = f2b(v1.y); a[6] = f2b(v1.z); a[7] = f2b(v1.w);
      #pragma unroll
      for (int nf = 0; nf < 10; ++nf) {
        bf16x8 bv = *(const bf16x8*)&bp[nf * 4096 + ks * 32];
        acc[nf] = __builtin_amdgcn_mfma_f32_16x16x32_bf16(a, bv, acc[nf], 0, 0, 0);
      }
    }
  }
  __syncthreads();   // p1s/p2s visible

  // ---- phase A cosine (per row, over 160 cols; padded cols are exact zeros) ----
  {
    float d[4] = {0.f, 0.f, 0.f, 0.f}, s[4] = {0.f, 0.f, 0.f, 0.f};
    float pn = 0.f;
    #pragma unroll
    for (int nf = 0; nf < 10; ++nf) {
      float a2 = p2s[nf * 16 + t16];
      pn += a2 * a2;
      #pragma unroll
      for (int r = 0; r < 4; ++r) {
        float v = acc[nf][r];
        d[r] = fmaf(v, a2, d[r]);
        s[r] = fmaf(v, v, s[r]);
      }
    }
    #pragma unroll
    for (int off = 1; off < 16; off <<= 1) {
      pn += __shfl_xor(pn, off);
      #pragma unroll
      for (int r = 0; r < 4; ++r) {
        d[r] += __shfl_xor(d[r], off);
        s[r] += __shfl_xor(s[r], off);
      }
    }
    const float spn = fmaxf(sqrtf(pn), 1e-12f);
    float cs[4];
    #pragma unroll
    for (int r = 0; r < 4; ++r) {
      float c = d[r] / (fmaxf(sqrtf(s[r]), 1e-12f) * spn);
      cs[r] = fminf(fmaxf(c, 0.f), 1.f);
    }
    #pragma unroll
    for (int nf = 0; nf < 10; ++nf)
      #pragma unroll
      for (int r = 0; r < 4; ++r)
        Acatile[(wave * 16 + quad * 4 + r) * 328 + nf * 16 + t16] = f2b(acc[nf][r] * cs[r]);
  }

  // ---- phase B: cosz reduce over k, scale, transpose-write cols 160:320 ----
  {
    float d[4] = {0.f, 0.f, 0.f, 0.f}, sv[4] = {0.f, 0.f, 0.f, 0.f};
    float pn = 0.f;
    #pragma unroll
    for (int it = 0; it < 10; ++it) {
      const int k = it * 16 + kr;
      const float a = p1s[k];
      d[0] = fmaf(zv[it].x, a, d[0]); d[1] = fmaf(zv[it].y, a, d[1]);
      d[2] = fmaf(zv[it].z, a, d[2]); d[3] = fmaf(zv[it].w, a, d[3]);
      sv[0] = fmaf(zv[it].x, zv[it].x, sv[0]); sv[1] = fmaf(zv[it].y, zv[it].y, sv[1]);
      sv[2] = fmaf(zv[it].z, zv[it].z, sv[2]); sv[3] = fmaf(zv[it].w, zv[it].w, sv[3]);
      pn = fmaf(a, a, pn);
    }
    #pragma unroll
    for (int off = 16; off < 64; off <<= 1) {
      pn += __shfl_xor(pn, off);
      #pragma unroll
      for (int r = 0; r < 4; ++r) {
        d[r] += __shfl_xor(d[r], off);
        sv[r] += __shfl_xor(sv[r], off);
      }
    }
    if ((lane >> 4) == 0) {
      #pragma unroll
      for (int r = 0; r < 4; ++r) {
        sred[wave][lane][r] = d[r];
        sred[wave][lane][4 + r] = sv[r];
      }
      sred[wave][lane][8] = pn;
    }
  }
  __syncthreads();
  if (tid < 64) {
    const int cg = tid >> 2, r = tid & 3;
    float dd = 0.f, ss = 0.f, pp = 0.f;
    #pragma unroll
    for (int w = 0; w < 4; ++w) {
      dd += sred[w][cg][r];
      ss += sred[w][cg][4 + r];
      pp += sred[w][cg][8];
    }
    float c = dd / (fmaxf(sqrtf(ss), 1e-12f) * fmaxf(sqrtf(pp), 1e-12f));
    czs[tid] = fminf(fmaxf(c, 0.f), 1.f);
  }
  __syncthreads();
  {
    const float cz0 = czs[c4 + 0], cz1 = czs[c4 + 1], cz2 = czs[c4 + 2], cz3 = czs[c4 + 3];
    #pragma unroll
    for (int it = 0; it < 10; ++it) {
      const int k = it * 16 + kr;
      Acatile[(c4 + 0) * 328 + 160 + k] = f2b(zv[it].x * cz0);
      Acatile[(c4 + 1) * 328 + 160 + k] = f2b(zv[it].y * cz1);
      Acatile[(c4 + 2) * 328 + 160 + k] = f2b(zv[it].z * cz2);
      Acatile[(c4 + 3) * 328 + 160 + k] = f2b(zv[it].w * cz3);
    }
  }
  __syncthreads();

  // ---- phase C: O = 0.5 * Acatile @ TT^T  (each wave: 32 rows x 80 cols, K=320) ----
  {
    const int wm = wave & 1, wn = wave >> 1;
    f32x4 c2[2][5];
    #pragma unroll
    for (int i = 0; i < 2; ++i)
      #pragma unroll
      for (int j = 0; j < 5; ++j)
        c2[i][j] = (f32x4){0.f, 0.f, 0.f, 0.f};
    const short* bp = TT + (size_t)(wn * 80 + t16) * 320 + k8;
    #pragma unroll 2
    for (int ks = 0; ks < 10; ++ks) {
      bf16x8 a0 = *(const bf16x8*)&Acatile[(wm * 32 + t16) * 328 + ks * 32 + k8];
      bf16x8 a1 = *(const bf16x8*)&Acatile[(wm * 32 + 16 + t16) * 328 + ks * 32 + k8];
      #pragma unroll
      for (int nf = 0; nf < 5; ++nf) {
        bf16x8 bv = *(const bf16x8*)&bp[nf * 5120 + ks * 32];
        c2[0][nf] = __builtin_amdgcn_mfma_f32_16x16x32_bf16(a0, bv, c2[0][nf], 0, 0, 0);
        c2[1][nf] = __builtin_amdgcn_mfma_f32_16x16x32_bf16(a1, bv, c2[1][nf], 0, 0, 0);
      }
    }
    #pragma unroll
    for (int nf = 0; nf < 5; ++nf) {
      const int kc = wn * 80 + nf * 16 + t16;
      if (kc < 150) {
        #pragma unroll
        for (int mf = 0; mf < 2; ++mf) {
          const int moff = wm * 32 + mf * 16 + quad * 4;
          float4 r4;
          r4.x = 0.5f * c2[mf][nf][0];
          r4.y = 0.5f * c2[mf][nf][1];
          r4.z = 0.5f * c2[mf][nf][2];
          r4.w = 0.5f * c2[mf][nf][3];
          *(float4*)&csz[((size_t)b * 150 + kc) * 16384 + mmg + moff] = r4;
          *(float4*)&asg[(((size_t)b * 4 + ti) * 150 + kc) * 4096 + nn + moff] = r4;
        }
      }
    }
  }
}

// ---------------- softmax stats + exp materialization (bf16) ----------------
// row = bt*150+k; writes ecsz[bt][160pad][4096] bf16 = exp(csz - rowmax); lr = rowsum
__global__ __launch_bounds__(256) void softmax_stats_e(
    const float* __restrict__ csz, float* __restrict__ lr_, short* __restrict__ ecsz)
{
  __shared__ float wred[8];
  const int row = blockIdx.x;
  const int bt = row / 150, k = row - bt * 150;
  const int b = bt >> 2, ti = bt & 3;
  const float* p = csz + ((size_t)b * 150 + k) * 16384 + ti * 4096;
  const int base = threadIdx.x * 16;
  float4 v[4];
  #pragma unroll
  for (int i = 0; i < 4; ++i) v[i] = *(const float4*)&p[base + i * 4];
  float mx = -1e30f;
  #pragma unroll
  for (int i = 0; i < 4; ++i)
    mx = fmaxf(mx, fmaxf(fmaxf(v[i].x, v[i].y), fmaxf(v[i].z, v[i].w)));
  #pragma unroll
  for (int off = 1; off < 64; off <<= 1) mx = fmaxf(mx, __shfl_xor(mx, off));
  const int wave = threadIdx.x >> 6, lane = threadIdx.x & 63;
  if (lane == 0) wred[wave] = mx;
  __syncthreads();
  mx = fmaxf(fmaxf(wred[0], wred[1]), fmaxf(wred[2], wred[3]));
  const float L = 1.4426950408889634f;
  float s = 0.f;
  bf16x8 e0, e1;
  #pragma unroll
  for (int i = 0; i < 2; ++i) {
    float a = exp2f((v[i].x - mx) * L);
    float bq = exp2f((v[i].y - mx) * L);
    float cq = exp2f((v[i].z - mx) * L);
    float dq = exp2f((v[i].w - mx) * L);
    s += a + bq + cq + dq;
    e0[i * 4 + 0] = f2b(a); e0[i * 4 + 1] = f2b(bq); e0[i * 4 + 2] = f2b(cq); e0[i * 4 + 3] = f2b(dq);
  }
  #pragma unroll
  for (int i = 2; i < 4; ++i) {
    float a = exp2f((v[i].x - mx) * L);
    float bq = exp2f((v[i].y - mx) * L);
    float cq = exp2f((v[i].z - mx) * L);
    float dq = exp2f((v[i].w - mx) * L);
    s += a + bq + cq + dq;
    e1[(i - 2) * 4 + 0] = f2b(a); e1[(i - 2) * 4 + 1] = f2b(bq);
    e1[(i - 2) * 4 + 2] = f2b(cq); e1[(i - 2) * 4 + 3] = f2b(dq);
  }
  #pragma unroll
  for (int off = 1; off < 64; off <<= 1) s += __shfl_xor(s, off);
  if (lane == 0) wred[4 + wave] = s;
  __syncthreads();
  short* er = ecsz + ((size_t)bt * 160 + k) * 4096 + base;
  *(bf16x8*)&er[0] = e0;
  *(bf16x8*)&er[8] = e1;
  if (threadIdx.x == 0) lr_[row] = wred[4] + wred[5] + wred[6] + wred[7];
}

// ---------------- cen numerator via MFMA + atomic split-K ----------------
// grid (2 chalf, 8 bt, 32 sp); block 256 = 4 waves; M=160(k) x N=128(c-half) x K=128(n)
__global__ __launch_bounds__(256) void gemm_cen_at(
    const short* __restrict__ ecsz, const short* __restrict__ xfT,
    float* __restrict__ cen)
{
  __shared__ __align__(16) short As[160 * 136];
  const int tid = threadIdx.x;
  const int chalf = blockIdx.x;
  const int bt = blockIdx.y;
  const int sp = blockIdx.z;
  const int n0 = sp * 128;
  const int wave = tid >> 6, lane = tid & 63;
  const int t16 = lane & 15, quad = lane >> 4, k8 = quad * 8;
  const int cbase = chalf * 128 + wave * 32;

  f32x4 acc[10][2];
  #pragma unroll
  for (int i = 0; i < 10; ++i) {
    acc[i][0] = (f32x4){0.f, 0.f, 0.f, 0.f};
    acc[i][1] = (f32x4){0.f, 0.f, 0.f, 0.f};
  }

  const short* erow = ecsz + (size_t)bt * 160 * 4096 + n0;
  // stage A: 160 rows x 128 k-cols (b128 in/out)
  #pragma unroll
  for (int p = 0; p < 10; ++p) {
    const int g = p * 256 + tid;
    const int row = g >> 4;
    const int col8 = (g & 15) * 8;
    *(bf16x8*)&As[row * 136 + col8] = *(const bf16x8*)&erow[(size_t)row * 4096 + col8];
  }
  __syncthreads();
  const short* xrow = xfT + (size_t)bt * 256 * 4096 + n0;
  #pragma unroll
  for (int kc = 0; kc < 4; ++kc) {
    bf16x8 b0 = *(const bf16x8*)&xrow[(size_t)(cbase + t16) * 4096 + kc * 32 + k8];
    bf16x8 b1 = *(const bf16x8*)&xrow[(size_t)(cbase + 16 + t16) * 4096 + kc * 32 + k8];
    #pragma unroll
    for (int mt = 0; mt < 10; ++mt) {
      bf16x8 aA = *(const bf16x8*)&As[(mt * 16 + t16) * 136 + kc * 32 + k8];
      acc[mt][0] = __builtin_amdgcn_mfma_f32_16x16x32_bf16(aA, b0, acc[mt][0], 0, 0, 0);
      acc[mt][1] = __builtin_amdgcn_mfma_f32_16x16x32_bf16(aA, b1, acc[mt][1], 0, 0, 0);
    }
  }
  #pragma unroll
  for (int mt = 0; mt < 10; ++mt) {
    #pragma unroll
    for (int r = 0; r < 4; ++r) {
      const int grow = mt * 16 + quad * 4 + r;
      if (grow < 150) {
        atomicAdd(&cen[((size_t)bt * 150 + grow) * 256 + cbase + t16], acc[mt][0][r]);
        atomicAdd(&cen[((size_t)bt * 150 + grow) * 256 + cbase + 16 + t16], acc[mt][1][r]);
      }
    }
  }
}

// ---------------- similarity gate + LN -> C_in (cen holds numerators; /lr here) ----------------
__global__ __launch_bounds__(256) void gate_ln(
    const float* __restrict__ cen, const float* __restrict__ lr_,
    const float* __restrict__ alpha_, const float* __restrict__ beta_,
    const float* __restrict__ nw, const float* __restrict__ nb, float* __restrict__ cin)
{
  __shared__ float red[256];
  int bk = blockIdx.x;
  int b = bk / 150, k = bk % 150;
  int c = threadIdx.x;
  const float* base = cen + ((size_t)b * 4 * 150) * 256;
  const float* lrb = lr_ + (size_t)b * 4 * 150;
  float lc  = base[((size_t)3 * 150 + k) * 256 + c] / lrb[3 * 150 + k];
  float p0  = base[((size_t)0 * 150 + k) * 256 + c] / lrb[0 * 150 + k];
  float p1v = base[((size_t)1 * 150 + k) * 256 + c] / lrb[1 * 150 + k];
  float p2v = base[((size_t)2 * 150 + k) * 256 + c] / lrb[2 * 150 + k];
  float nl = bred_sum(lc * lc, red);
  float q0 = bred_sum(p0 * p0, red);
  float q1 = bred_sum(p1v * p1v, red);
  float q2 = bred_sum(p2v * p2v, red);
  float d0 = bred_sum(lc * p0, red);
  float d1 = bred_sum(lc * p1v, red);
  float d2 = bred_sum(lc * p2v, red);
  float al = alpha_[0], be = beta_[0];
  float snl = sqrtf(nl);
  float g0 = 1.f / (1.f + expf(-(be + al * (d0 / fmaxf(snl * sqrtf(q0), 1e-8f)))));
  float g1 = 1.f / (1.f + expf(-(be + al * (d1 / fmaxf(snl * sqrtf(q1), 1e-8f)))));
  float g2 = 1.f / (1.f + expf(-(be + al * (d2 / fmaxf(snl * sqrtf(q2), 1e-8f)))));
  float ci = lc + g0 * p0 + g1 * p1v + g2 * p2v;
  float mu = bred_sum(ci, red) * (1.f / 256.f);
  float df = ci - mu;
  float var = bred_sum(df * df, red) * (1.f / 256.f);
  cin[(size_t)bk * 256 + c] = df * rsqrtf(var + 1e-5f) * nw[c] + nb[c];
}

// ---------------- merged k/v fp32 GEMM (M=300, N=256, K=256) ----------------
// grid (3, 8): blockIdx.y<4 -> K-proj, else V-proj; n0 = (y&3)*64
__global__ __launch_bounds__(256) void gemm_kv(
    const float* __restrict__ A,
    const float* __restrict__ Wk, const float* __restrict__ bk, float* __restrict__ outk,
    const float* __restrict__ Wv, const float* __restrict__ bv_, float* __restrict__ outv)
{
  __shared__ __align__(16) float As[16][132];
  __shared__ __align__(16) float Ws[16][68];
  const int tid = threadIdx.x;
  const int m0 = blockIdx.x * 128;
  const bool isv = blockIdx.y >= 4;
  const float* W = isv ? Wv : Wk;
  const float* bias = isv ? bv_ : bk;
  float* out = isv ? outv : outk;
  const int n0 = (blockIdx.y & 3) * 64;
  const int M = 300, K = 256;
  const int tm = tid & 15;
  const int tn = tid >> 4;
  float acc[8][4];
  #pragma unroll
  for (int i = 0; i < 8; ++i)
    #pragma unroll
    for (int j = 0; j < 4; ++j) acc[i][j] = 0.f;

  const int lr = tid >> 2;
  const int lk = (tid & 3) * 4;

  for (int k0 = 0; k0 < K; k0 += 16) {
    #pragma unroll
    for (int p = 0; p < 2; ++p) {
      int r = lr + p * 64;
      int gm = m0 + r;
      float4 v = make_float4(0.f, 0.f, 0.f, 0.f);
      if (gm < M) v = *(const float4*)&A[(size_t)gm * K + k0 + lk];
      As[lk + 0][r] = v.x; As[lk + 1][r] = v.y; As[lk + 2][r] = v.z; As[lk + 3][r] = v.w;
    }
    {
      float4 v = *(const float4*)&W[(size_t)(n0 + lr) * K + k0 + lk];
      Ws[lk + 0][lr] = v.x; Ws[lk + 1][lr] = v.y; Ws[lk + 2][lr] = v.z; Ws[lk + 3][lr] = v.w;
    }
    __syncthreads();
    #pragma unroll
    for (int kk = 0; kk < 16; ++kk) {
      float4 a0 = *(const float4*)&As[kk][tm * 8];
      float4 a1 = *(const float4*)&As[kk][tm * 8 + 4];
      float4 w0 = *(const float4*)&Ws[kk][tn * 4];
      float av[8] = {a0.x, a0.y, a0.z, a0.w, a1.x, a1.y, a1.z, a1.w};
      float wv[4] = {w0.x, w0.y, w0.z, w0.w};
      #pragma unroll
      for (int i = 0; i < 8; ++i)
        #pragma unroll
        for (int j = 0; j < 4; ++j)
          acc[i][j] = fmaf(av[i], wv[j], acc[i][j]);
    }
    __syncthreads();
  }
  float4 bv4 = *(const float4*)&bias[n0 + tn * 4];
  float bb[4] = {bv4.x, bv4.y, bv4.z, bv4.w};
  #pragma unroll
  for (int i = 0; i < 8; ++i) {
    int gm = m0 + tm * 8 + i;
    if (gm >= M) continue;
    float4 r;
    r.x = acc[i][0] + bb[0];
    r.y = acc[i][1] + bb[1];
    r.z = acc[i][2] + bb[2];
    r.w = acc[i][3] + bb[3];
    *(float4*)&out[(size_t)gm * 256 + n0 + tn * 4] = r;
  }
}

// ---------------- MFMA attention: 128 Q-rows/block, per (b,h); q bf16 in, o bf16 out ----------------
__global__ __launch_bounds__(256) void attn_mfma(
    const short* __restrict__ q, const float* __restrict__ ks, const float* __restrict__ vs,
    short* __restrict__ o)
{
  __shared__ __align__(16) short Ps[128 * 168];
  __shared__ __align__(16) short VT[32 * 168];
  __shared__ float lrow[128];
  const int tid = threadIdx.x;
  const int bid = blockIdx.x;
  const int ntile = bid & 31;
  const int bh = bid >> 5;
  const int b = bh >> 3, h = bh & 7;
  const int n0 = ntile * 128;
  const int wave = tid >> 6, lane = tid & 63;
  const int t16 = lane & 15, quad = lane >> 4;
  const int k8 = quad * 8;
  const int wr = wave * 32;

  for (int i = tid; i < 5120; i += 256) {
    int d = i / 160, kc = i - d * 160;
    VT[d * 168 + kc] = (kc < 150) ? f2b(vs[((size_t)b * 150 + kc) * 256 + h * 32 + d]) : (short)0;
  }

  bf16x8 aQ[2];
  #pragma unroll
  for (int mt = 0; mt < 2; ++mt)
    aQ[mt] = *(const bf16x8*)&q[((size_t)b * 4096 + n0 + wr + mt * 16 + t16) * 256 + h * 32 + k8];

  f32x4 s[2][10];
  #pragma unroll
  for (int ct = 0; ct < 10; ++ct) {
    const int c = ct * 16 + t16;
    bf16x8 bK = {0, 0, 0, 0, 0, 0, 0, 0};
    if (c < 150) {
      const float* kp = &ks[((size_t)b * 150 + c) * 256 + h * 32 + k8];
      float4 v0 = *(const float4*)&kp[0];
      float4 v1 = *(const float4*)&kp[4];
      bK[0] = f2b(v0.x); bK[1] = f2b(v0.y); bK[2] = f2b(v0.z); bK[3] = f2b(v0.w);
      bK[4] = f2b(v1.x); bK[5] = f2b(v1.y); bK[6] = f2b(v1.z); bK[7] = f2b(v1.w);
    }
    f32x4 zero = (f32x4){0.f, 0.f, 0.f, 0.f};
    s[0][ct] = __builtin_amdgcn_mfma_f32_16x16x32_bf16(aQ[0], bK, zero, 0, 0, 0);
    s[1][ct] = __builtin_amdgcn_mfma_f32_16x16x32_bf16(aQ[1], bK, zero, 0, 0, 0);
  }

  #pragma unroll
  for (int mt = 0; mt < 2; ++mt) {
    #pragma unroll
    for (int r = 0; r < 4; ++r) {
      float mx = -1e30f;
      #pragma unroll
      for (int ct = 0; ct < 10; ++ct) {
        float v = s[mt][ct][r];
        if (ct == 9 && t16 >= 6) { v = -1e30f; s[mt][ct][r] = v; }
        mx = fmaxf(mx, v);
      }
      mx = fmaxf(mx, __shfl_xor(mx, 1));
      mx = fmaxf(mx, __shfl_xor(mx, 2));
      mx = fmaxf(mx, __shfl_xor(mx, 4));
      mx = fmaxf(mx, __shfl_xor(mx, 8));
      float ls = 0.f;
      #pragma unroll
      for (int ct = 0; ct < 10; ++ct) {
        float e = expf(s[mt][ct][r] - mx);
        s[mt][ct][r] = e;
        ls += e;
      }
      ls += __shfl_xor(ls, 1);
      ls += __shfl_xor(ls, 2);
      ls += __shfl_xor(ls, 4);
      ls += __shfl_xor(ls, 8);
      if (t16 == 0) lrow[wr + mt * 16 + quad * 4 + r] = 1.f / ls;
      #pragma unroll
      for (int ct = 0; ct < 10; ++ct)
        Ps[(wr + mt * 16 + quad * 4 + r) * 168 + ct * 16 + t16] = f2b(s[mt][ct][r]);
    }
  }
  __syncthreads();

  f32x4 oacc[2][2];
  #pragma unroll
  for (int i = 0; i < 2; ++i)
    #pragma unroll
    for (int j = 0; j < 2; ++j)
      oacc[i][j] = (f32x4){0.f, 0.f, 0.f, 0.f};
  #pragma unroll
  for (int kstep = 0; kstep < 5; ++kstep) {
    bf16x8 bV0 = *(const bf16x8*)&VT[( 0 + t16) * 168 + kstep * 32 + k8];
    bf16x8 bV1 = *(const bf16x8*)&VT[(16 + t16) * 168 + kstep * 32 + k8];
    #pragma unroll
    for (int mt = 0; mt < 2; ++mt) {
      bf16x8 aP = *(const bf16x8*)&Ps[(wr + mt * 16 + t16) * 168 + kstep * 32 + k8];
      oacc[mt][0] = __builtin_amdgcn_mfma_f32_16x16x32_bf16(aP, bV0, oacc[mt][0], 0, 0, 0);
      oacc[mt][1] = __builtin_amdgcn_mfma_f32_16x16x32_bf16(aP, bV1, oacc[mt][1], 0, 0, 0);
    }
  }
  #pragma unroll
  for (int mt = 0; mt < 2; ++mt) {
    #pragma unroll
    for (int nt = 0; nt < 2; ++nt) {
      const int d = nt * 16 + t16;
      #pragma unroll
      for (int r = 0; r < 4; ++r) {
        const int row = wr + mt * 16 + quad * 4 + r;
        o[((size_t)b * 4096 + n0 + row) * 256 + h * 32 + d] = f2b(oacc[mt][nt][r] * lrow[row]);
      }
    }
  }
}

// ---------------- dst = res + LN(src), wave-per-row (row=256 cols) ----------------
__global__ __launch_bounds__(256) void ln_res(
    const float* __restrict__ src, const float* __restrict__ res,
    const float* __restrict__ nw, const float* __restrict__ nb, float* __restrict__ dst)
{
  const int wave = threadIdx.x >> 6;
  const int lane = threadIdx.x & 63;
  const size_t row = (size_t)blockIdx.x * 4 + wave;
  const int c = lane * 4;
  float4 v = *(const float4*)&src[row * 256 + c];
  float s  = v.x + v.y + v.z + v.w;
  float s2 = v.x * v.x + v.y * v.y + v.z * v.z + v.w * v.w;
  #pragma unroll
  for (int off = 1; off < 64; off <<= 1) {
    s  += __shfl_xor(s, off);
    s2 += __shfl_xor(s2, off);
  }
  const float mu = s * (1.f / 256.f);
  const float var = s2 * (1.f / 256.f) - mu * mu;
  const float inv = rsqrtf(var + 1e-5f);
  float4 w = *(const float4*)&nw[c];
  float4 bb = *(const float4*)&nb[c];
  float4 rr = *(const float4*)&res[row * 256 + c];
  float4 d;
  d.x = rr.x + (v.x - mu) * inv * w.x + bb.x;
  d.y = rr.y + (v.y - mu) * inv * w.y + bb.y;
  d.z = rr.z + (v.z - mu) * inv * w.z + bb.z;
  d.w = rr.w + (v.w - mu) * inv * w.w + bb.w;
  *(float4*)&dst[row * 256 + c] = d;
}

// ---------------- dual-output ln_res: fp32 dst + bf16 dstb (for fc1's bfA path) ----------------
__global__ __launch_bounds__(256) void ln_res_dual(
    const float* __restrict__ src, const float* __restrict__ res,
    const float* __restrict__ nw, const float* __restrict__ nb,
    float* __restrict__ dst, short* __restrict__ dstb)
{
  const int wave = threadIdx.x >> 6;
  const int lane = threadIdx.x & 63;
  const size_t row = (size_t)blockIdx.x * 4 + wave;
  const int c = lane * 4;
  float4 v = *(const float4*)&src[row * 256 + c];
  float s  = v.x + v.y + v.z + v.w;
  float s2 = v.x * v.x + v.y * v.y + v.z * v.z + v.w * v.w;
  #pragma unroll
  for (int off = 1; off < 64; off <<= 1) {
    s  += __shfl_xor(s, off);
    s2 += __shfl_xor(s2, off);
  }
  const float mu = s * (1.f / 256.f);
  const float var = s2 * (1.f / 256.f) - mu * mu;
  const float inv = rsqrtf(var + 1e-5f);
  float4 w = *(const float4*)&nw[c];
  float4 bb = *(const float4*)&nb[c];
  float4 rr = *(const float4*)&res[row * 256 + c];
  float4 d;
  d.x = rr.x + (v.x - mu) * inv * w.x + bb.x;
  d.y = rr.y + (v.y - mu) * inv * w.y + bb.y;
  d.z = rr.z + (v.z - mu) * inv * w.z + bb.z;
  d.w = rr.w + (v.w - mu) * inv * w.w + bb.w;
  *(float4*)&dst[row * 256 + c] = d;
  bf16x4 db;
  db[0] = f2b(d.x); db[1] = f2b(d.y); db[2] = f2b(d.z); db[3] = f2b(d.w);
  *(bf16x4*)&dstb[row * 256 + c] = db;
}

// ---------------- depthwise 3x3 conv + bias + exact gelu, 4 pixels/block, bf16 out ----------------
// grid 2048 = b(2) x y(64) x xg(16); each block does pixels (y, 4*xg .. 4*xg+3),
// 256 threads x 4 channels. 3x6 tap window shared across the 4 outputs.
__global__ __launch_bounds__(256) void conv_gelu(
    const float* __restrict__ h, const float* __restrict__ wt, const float* __restrict__ bias,
    short* __restrict__ hc)
{
  const int bid = blockIdx.x;
  const int xg = bid & 15;
  const int y  = (bid >> 4) & 63;
  const int b  = bid >> 10;
  const int x0 = xg * 4;
  const int c4 = threadIdx.x * 4;
  const float* hb = h + ((size_t)b * 4096) * 1024 + c4;

  float4 tap[3][6];
  #pragma unroll
  for (int dy = 0; dy < 3; ++dy) {
    const int yy = y + dy - 1;
    #pragma unroll
    for (int dx = 0; dx < 6; ++dx) {
      const int xv = x0 + dx - 1;
      tap[dy][dx] = make_float4(0.f, 0.f, 0.f, 0.f);
      if (yy >= 0 && yy <= 63 && xv >= 0 && xv <= 63)
        tap[dy][dx] = *(const float4*)&hb[(size_t)(yy * 64 + xv) * 1024];
    }
  }
  float4 wv[3][3];
  #pragma unroll
  for (int dy = 0; dy < 3; ++dy)
    #pragma unroll
    for (int dx = 0; dx < 3; ++dx)
      wv[dy][dx] = *(const float4*)&wt[(dy * 3 + dx) * 1024 + c4];
  const float4 bv = *(const float4*)&bias[c4];

  #pragma unroll
  for (int p = 0; p < 4; ++p) {
    float4 acc = bv;
    #pragma unroll
    for (int dy = 0; dy < 3; ++dy) {
      #pragma unroll
      for (int dx = 0; dx < 3; ++dx) {
        const float4 hv = tap[dy][p + dx];
        const float4 w = wv[dy][dx];
        acc.x = fmaf(hv.x, w.x, acc.x);
        acc.y = fmaf(hv.y, w.y, acc.y);
        acc.z = fmaf(hv.z, w.z, acc.z);
        acc.w = fmaf(hv.w, w.w, acc.w);
      }
    }
    bf16x4 g;
    g[0] = f2b(0.5f * acc.x * (1.f + erff(acc.x * 0.70710678118654752f)));
    g[1] = f2b(0.5f * acc.y * (1.f + erff(acc.y * 0.70710678118654752f)));
    g[2] = f2b(0.5f * acc.z * (1.f + erff(acc.z * 0.70710678118654752f)));
    g[3] = f2b(0.5f * acc.w * (1.f + erff(acc.w * 0.70710678118654752f)));
    *(bf16x4*)&hc[((size_t)b * 4096 + y * 64 + x0 + p) * 1024 + c4] = g;
  }
}

extern "C" void kernel_launch(void* const* d_in, const int* in_sizes, int n_in,
                              void* d_out, int out_size, void* d_ws, size_t ws_size,
                              hipStream_t stream)
{
  (void)in_sizes; (void)n_in; (void)out_size; (void)ws_size;
  const float* x    = (const float*)d_in[0];
  const float* z    = (const float*)d_in[1];
  const float* mem  = (const float*)d_in[2];
  const float* cw   = (const float*)d_in[3];
  const float* p1   = (const float*)d_in[4];
  const float* tdt1 = (const float*)d_in[5];
  const float* p2   = (const float*)d_in[6];
  const float* tdt2 = (const float*)d_in[7];
  const float* sal  = (const float*)d_in[8];
  const float* sbe  = (const float*)d_in[9];
  const float* q_w  = (const float*)d_in[10];
  const float* q_b  = (const float*)d_in[11];
  const float* k_w  = (const float*)d_in[12];
  const float* k_b  = (const float*)d_in[13];
  const float* v_w  = (const float*)d_in[14];
  const float* v_b  = (const float*)d_in[15];
  const float* pj_w = (const float*)d_in[16];
  const float* pj_b = (const float*)d_in[17];
  const float* nw   = (const float*)d_in[18];
  const float* nb   = (const float*)d_in[19];
  const float* f1w  = (const float*)d_in[20];
  const float* f1b  = (const float*)d_in[21];
  const float* dww  = (const float*)d_in[22];
  const float* dwb  = (const float*)d_in[23];
  const float* f2w  = (const float*)d_in[24];
  const float* f2b_ = (const float*)d_in[25];

  float* out = (float*)d_out;                  // (2,4096,256)
  float* csz = out + 2097152;                  // (2,150,16384)
  float* asg = csz + 4915200;                  // (2,4,150,4096)

  float* ws    = (float*)d_ws;
  short* ecsz  = (short*)ws;         // 5,242,880 shorts, written by softmax step
  short* TT    = (short*)(ws + 5242880);   // 160x320 bf16 = 25,600 float-slots
  short* cwb   = (short*)(ws + 5275648);   // 160x256 bf16 = 20,480 float-slots
  float* lr_   = ws + 5308416;       // 1,200
  float* cen   = ws + 5310816;       // 307,200
  float* cin   = ws + 5618016;       // 76,800
  short* q     = (short*)(ws + 5694816);   // 8192x256 bf16 = 1,048,576 float-slots
  float* ksb   = ws + 7791968;       // 76,800
  float* vsb   = ws + 7868768;       // 76,800
  short* o     = (short*)(ws + 7945568);   // 8192x256 bf16 (ends 8,994,144)
  short* xfT   = (short*)(ws + 10042720);  // 8x256x4096 bf16 = 4,194,304 float-slots (ends 14,237,024; dead after cen)
  float* h     = ws;                 // 8,388,608 reuse (ecsz/TT/cwb/q dead by fc1)
  short* hc    = (short*)(ws + 8388608);   // 8,388,608 shorts = 4,194,304 float-slots
  short* out1b = (short*)(ws + 14237024);  // 8192x256 bf16 = 1,048,576 float-slots (ends 15,285,600; xfT dead)
  float* tmp   = ws + 16777216;
  float* out1  = ws + 18874368;
  float* wt    = ws + 20971520;      // 9,216

  dim3 blk(256);
  // 1. merged weight packs (cwb/TT/wt) + xf bf16 transpose — one launch
  prep_all<<<dim3(712), blk, 0, stream>>>(cw, tdt2, tdt1, dww, x, mem, cwb, TT, wt, xfT);
  // 2. fused cluster front-end: cl GEMM + cosines + csz GEMM (unroll-2 phase A — verified config)
  fused_csz<<<dim3(512), blk, 0, stream>>>(x, mem, z, cwb, TT, p1, p2, csz, asg);
  // 3. softmax stats + exp(csz-m) materialized bf16
  softmax_stats_e<<<dim3(1200), blk, 0, stream>>>(csz, lr_, ecsz);
  // 4. cen numerators via MFMA + atomics (cen zeroed first)
  hipMemsetAsync(cen, 0, (size_t)1200 * 256 * sizeof(float), stream);
  gemm_cen_at<<<dim3(2, 8, 32), blk, 0, stream>>>(ecsz, xfT, cen);
  // 5. gate + LN -> C_in (divides by lr)
  gate_ln<<<dim3(300), blk, 0, stream>>>(cen, lr_, sal, sbe, nw, nb, cin);
  // 6. q (MFMA, bf16 out) + merged k/v (one launch)
  gemm_mfma_bfout<<<dim3(128, 4), blk, 0, stream>>>(x, q_w, q_b, q, 8192, 256, 256, 0.17677669529663687f);
  gemm_kv<<<dim3(3, 8), blk, 0, stream>>>(cin, k_w, k_b, ksb, v_w, v_b, vsb);
  // 7. attention [MFMA]; o bf16
  attn_mfma<<<dim3(512), blk, 0, stream>>>(q, ksb, vsb, o);
  // 8. proj (bf16 A) + LN + residual (dual out: fp32 for residual, bf16 for fc1 A)
  gemm_mfma_bfA<<<dim3(128, 4), blk, 0, stream>>>(o, pj_w, pj_b, tmp, 8192, 256, 256, 1.f);
  ln_res_dual<<<dim3(2048), blk, 0, stream>>>(tmp, x, nw, nb, out1, out1b);
  // 9. MLP (fc1 consumes bf16 out1b — same f2b rounding, applied once instead of 16x)
  gemm_mfma_bfA<<<dim3(128, 16), blk, 0, stream>>>(out1b, f1w, f1b, h, 8192, 1024, 256, 1.f);
  conv_gelu<<<dim3(2048), blk, 0, stream>>>(h, wt, dwb, hc);
  gemm_mfma_bfA<<<dim3(128, 4), blk, 0, stream>>>(hc, f2w, f2b_, tmp, 8192, 256, 1024, 1.f);
  ln_res<<<dim3(2048), blk, 0, stream>>>(tmp, out1, nw, nb, out);
}

// Round 12
// 381.623 us; speedup vs baseline: 1.0174x; 1.0020x over previous
//
#include <hip/hip_runtime.h>
#include <math.h>

// Dims: B=2, N=4096, C=256, nc=150, T=4, TN=16384, heads=8, hd=32, hid=1024, H=W=64

typedef __attribute__((ext_vector_type(8))) short bf16x8;
typedef __attribute__((ext_vector_type(4))) short bf16x4;
typedef __attribute__((ext_vector_type(4))) float f32x4;

__device__ __forceinline__ short f2b(float f) {
  union { float f; unsigned int u; } c; c.f = f;
  unsigned int r = (c.u + 0x7fffu + ((c.u >> 16) & 1u)) >> 16;
  return (short)r;
}

// ---------------- bf16 MFMA GEMM, 64x64 tile: out[m][n] = alpha*(A@W^T + bias) ----------------
// grid (M/64, N/64); 4 waves: wm=row-half(32), wn=col-half(32), 2x2 16x16 frags each.
__global__ __launch_bounds__(256) void gemm_mfma(
    const float* __restrict__ A, const float* __restrict__ W,
    const float* __restrict__ bias, float* __restrict__ out,
    int M, int N, int K, float alpha)
{
  __shared__ __align__(16) short As[64 * 72];
  __shared__ __align__(16) short Bs[64 * 72];
  const int tid = threadIdx.x;
  const int m0 = blockIdx.x * 64;
  const int n0 = blockIdx.y * 64;
  const int wave = tid >> 6;
  const int lane = tid & 63;
  const int wm = wave & 1, wn = wave >> 1;
  const int t16 = lane & 15;
  const int k8 = (lane >> 4) * 8;

  f32x4 acc[2][2];
  #pragma unroll
  for (int i = 0; i < 2; ++i)
    #pragma unroll
    for (int j = 0; j < 2; ++j)
      acc[i][j] = (f32x4){0.f, 0.f, 0.f, 0.f};

  const int sr = tid >> 2;
  const int sk = (tid & 3) * 16;

  for (int k0 = 0; k0 < K; k0 += 64) {
    {
      const float* ap = &A[(size_t)(m0 + sr) * K + k0 + sk];
      float4 v0 = *(const float4*)&ap[0];
      float4 v1 = *(const float4*)&ap[4];
      float4 v2 = *(const float4*)&ap[8];
      float4 v3 = *(const float4*)&ap[12];
      bf16x8 w0, w1;
      w0[0] = f2b(v0.x); w0[1] = f2b(v0.y); w0[2] = f2b(v0.z); w0[3] = f2b(v0.w);
      w0[4] = f2b(v1.x); w0[5] = f2b(v1.y); w0[6] = f2b(v1.z); w0[7] = f2b(v1.w);
      w1[0] = f2b(v2.x); w1[1] = f2b(v2.y); w1[2] = f2b(v2.z); w1[3] = f2b(v2.w);
      w1[4] = f2b(v3.x); w1[5] = f2b(v3.y); w1[6] = f2b(v3.z); w1[7] = f2b(v3.w);
      *(bf16x8*)&As[sr * 72 + sk] = w0;
      *(bf16x8*)&As[sr * 72 + sk + 8] = w1;
    }
    {
      const float* wp = &W[(size_t)(n0 + sr) * K + k0 + sk];
      float4 v0 = *(const float4*)&wp[0];
      float4 v1 = *(const float4*)&wp[4];
      float4 v2 = *(const float4*)&wp[8];
      float4 v3 = *(const float4*)&wp[12];
      bf16x8 w0, w1;
      w0[0] = f2b(v0.x); w0[1] = f2b(v0.y); w0[2] = f2b(v0.z); w0[3] = f2b(v0.w);
      w0[4] = f2b(v1.x); w0[5] = f2b(v1.y); w0[6] = f2b(v1.z); w0[7] = f2b(v1.w);
      w1[0] = f2b(v2.x); w1[1] = f2b(v2.y); w1[2] = f2b(v2.z); w1[3] = f2b(v2.w);
      w1[4] = f2b(v3.x); w1[5] = f2b(v3.y); w1[6] = f2b(v3.z); w1[7] = f2b(v3.w);
      *(bf16x8*)&Bs[sr * 72 + sk] = w0;
      *(bf16x8*)&Bs[sr * 72 + sk + 8] = w1;
    }
    __syncthreads();
    #pragma unroll
    for (int ks = 0; ks < 2; ++ks) {
      const int kofs = ks * 32 + k8;
      bf16x8 af0 = *(const bf16x8*)&As[(wm * 32 +  0 + t16) * 72 + kofs];
      bf16x8 af1 = *(const bf16x8*)&As[(wm * 32 + 16 + t16) * 72 + kofs];
      bf16x8 bf0 = *(const bf16x8*)&Bs[(wn * 32 +  0 + t16) * 72 + kofs];
      bf16x8 bf1 = *(const bf16x8*)&Bs[(wn * 32 + 16 + t16) * 72 + kofs];
      acc[0][0] = __builtin_amdgcn_mfma_f32_16x16x32_bf16(af0, bf0, acc[0][0], 0, 0, 0);
      acc[1][0] = __builtin_amdgcn_mfma_f32_16x16x32_bf16(af1, bf0, acc[1][0], 0, 0, 0);
      acc[0][1] = __builtin_amdgcn_mfma_f32_16x16x32_bf16(af0, bf1, acc[0][1], 0, 0, 0);
      acc[1][1] = __builtin_amdgcn_mfma_f32_16x16x32_bf16(af1, bf1, acc[1][1], 0, 0, 0);
    }
    __syncthreads();
  }
  const int r4 = (lane >> 4) * 4;
  #pragma unroll
  for (int ni = 0; ni < 2; ++ni) {
    const int gcol = n0 + wn * 32 + ni * 16 + t16;
    const float bb = bias[gcol];
    #pragma unroll
    for (int mi = 0; mi < 2; ++mi) {
      #pragma unroll
      for (int r = 0; r < 4; ++r) {
        const int gm = m0 + wm * 32 + mi * 16 + r4 + r;
        out[(size_t)gm * N + gcol] = alpha * (acc[mi][ni][r] + bb);
      }
    }
  }
}

// ---------------- fp32-A MFMA GEMM, bf16 OUT (q-proj: consumer rounds anyway) ----------------
__global__ __launch_bounds__(256) void gemm_mfma_bfout(
    const float* __restrict__ A, const float* __restrict__ W,
    const float* __restrict__ bias, short* __restrict__ out,
    int M, int N, int K, float alpha)
{
  __shared__ __align__(16) short As[64 * 72];
  __shared__ __align__(16) short Bs[64 * 72];
  const int tid = threadIdx.x;
  const int m0 = blockIdx.x * 64;
  const int n0 = blockIdx.y * 64;
  const int wave = tid >> 6;
  const int lane = tid & 63;
  const int wm = wave & 1, wn = wave >> 1;
  const int t16 = lane & 15;
  const int k8 = (lane >> 4) * 8;

  f32x4 acc[2][2];
  #pragma unroll
  for (int i = 0; i < 2; ++i)
    #pragma unroll
    for (int j = 0; j < 2; ++j)
      acc[i][j] = (f32x4){0.f, 0.f, 0.f, 0.f};

  const int sr = tid >> 2;
  const int sk = (tid & 3) * 16;

  for (int k0 = 0; k0 < K; k0 += 64) {
    {
      const float* ap = &A[(size_t)(m0 + sr) * K + k0 + sk];
      float4 v0 = *(const float4*)&ap[0];
      float4 v1 = *(const float4*)&ap[4];
      float4 v2 = *(const float4*)&ap[8];
      float4 v3 = *(const float4*)&ap[12];
      bf16x8 w0, w1;
      w0[0] = f2b(v0.x); w0[1] = f2b(v0.y); w0[2] = f2b(v0.z); w0[3] = f2b(v0.w);
      w0[4] = f2b(v1.x); w0[5] = f2b(v1.y); w0[6] = f2b(v1.z); w0[7] = f2b(v1.w);
      w1[0] = f2b(v2.x); w1[1] = f2b(v2.y); w1[2] = f2b(v2.z); w1[3] = f2b(v2.w);
      w1[4] = f2b(v3.x); w1[5] = f2b(v3.y); w1[6] = f2b(v3.z); w1[7] = f2b(v3.w);
      *(bf16x8*)&As[sr * 72 + sk] = w0;
      *(bf16x8*)&As[sr * 72 + sk + 8] = w1;
    }
    {
      const float* wp = &W[(size_t)(n0 + sr) * K + k0 + sk];
      float4 v0 = *(const float4*)&wp[0];
      float4 v1 = *(const float4*)&wp[4];
      float4 v2 = *(const float4*)&wp[8];
      float4 v3 = *(const float4*)&wp[12];
      bf16x8 w0, w1;
      w0[0] = f2b(v0.x); w0[1] = f2b(v0.y); w0[2] = f2b(v0.z); w0[3] = f2b(v0.w);
      w0[4] = f2b(v1.x); w0[5] = f2b(v1.y); w0[6] = f2b(v1.z); w0[7] = f2b(v1.w);
      w1[0] = f2b(v2.x); w1[1] = f2b(v2.y); w1[2] = f2b(v2.z); w1[3] = f2b(v2.w);
      w1[4] = f2b(v3.x); w1[5] = f2b(v3.y); w1[6] = f2b(v3.z); w1[7] = f2b(v3.w);
      *(bf16x8*)&Bs[sr * 72 + sk] = w0;
      *(bf16x8*)&Bs[sr * 72 + sk + 8] = w1;
    }
    __syncthreads();
    #pragma unroll
    for (int ks = 0; ks < 2; ++ks) {
      const int kofs = ks * 32 + k8;
      bf16x8 af0 = *(const bf16x8*)&As[(wm * 32 +  0 + t16) * 72 + kofs];
      bf16x8 af1 = *(const bf16x8*)&As[(wm * 32 + 16 + t16) * 72 + kofs];
      bf16x8 bf0 = *(const bf16x8*)&Bs[(wn * 32 +  0 + t16) * 72 + kofs];
      bf16x8 bf1 = *(const bf16x8*)&Bs[(wn * 32 + 16 + t16) * 72 + kofs];
      acc[0][0] = __builtin_amdgcn_mfma_f32_16x16x32_bf16(af0, bf0, acc[0][0], 0, 0, 0);
      acc[1][0] = __builtin_amdgcn_mfma_f32_16x16x32_bf16(af1, bf0, acc[1][0], 0, 0, 0);
      acc[0][1] = __builtin_amdgcn_mfma_f32_16x16x32_bf16(af0, bf1, acc[0][1], 0, 0, 0);
      acc[1][1] = __builtin_amdgcn_mfma_f32_16x16x32_bf16(af1, bf1, acc[1][1], 0, 0, 0);
    }
    __syncthreads();
  }
  const int r4 = (lane >> 4) * 4;
  #pragma unroll
  for (int ni = 0; ni < 2; ++ni) {
    const int gcol = n0 + wn * 32 + ni * 16 + t16;
    const float bb = bias[gcol];
    #pragma unroll
    for (int mi = 0; mi < 2; ++mi) {
      #pragma unroll
      for (int r = 0; r < 4; ++r) {
        const int gm = m0 + wm * 32 + mi * 16 + r4 + r;
        out[(size_t)gm * N + gcol] = f2b(alpha * (acc[mi][ni][r] + bb));
      }
    }
  }
}

// ---------------- bf16-A MFMA GEMM, 64x64 tile (proj/fc1/fc2: A pre-rounded bf16) ----------------
__global__ __launch_bounds__(256) void gemm_mfma_bfA(
    const short* __restrict__ A, const float* __restrict__ W,
    const float* __restrict__ bias, float* __restrict__ out,
    int M, int N, int K, float alpha)
{
  __shared__ __align__(16) short As[64 * 72];
  __shared__ __align__(16) short Bs[64 * 72];
  const int tid = threadIdx.x;
  const int m0 = blockIdx.x * 64;
  const int n0 = blockIdx.y * 64;
  const int wave = tid >> 6;
  const int lane = tid & 63;
  const int wm = wave & 1, wn = wave >> 1;
  const int t16 = lane & 15;
  const int k8 = (lane >> 4) * 8;

  f32x4 acc[2][2];
  #pragma unroll
  for (int i = 0; i < 2; ++i)
    #pragma unroll
    for (int j = 0; j < 2; ++j)
      acc[i][j] = (f32x4){0.f, 0.f, 0.f, 0.f};

  const int sr = tid >> 2;
  const int sk = (tid & 3) * 16;

  for (int k0 = 0; k0 < K; k0 += 64) {
    {
      const short* ap = &A[(size_t)(m0 + sr) * K + k0 + sk];
      *(bf16x8*)&As[sr * 72 + sk] = *(const bf16x8*)&ap[0];
      *(bf16x8*)&As[sr * 72 + sk + 8] = *(const bf16x8*)&ap[8];
    }
    {
      const float* wp = &W[(size_t)(n0 + sr) * K + k0 + sk];
      float4 v0 = *(const float4*)&wp[0];
      float4 v1 = *(const float4*)&wp[4];
      float4 v2 = *(const float4*)&wp[8];
      float4 v3 = *(const float4*)&wp[12];
      bf16x8 w0, w1;
      w0[0] = f2b(v0.x); w0[1] = f2b(v0.y); w0[2] = f2b(v0.z); w0[3] = f2b(v0.w);
      w0[4] = f2b(v1.x); w0[5] = f2b(v1.y); w0[6] = f2b(v1.z); w0[7] = f2b(v1.w);
      w1[0] = f2b(v2.x); w1[1] = f2b(v2.y); w1[2] = f2b(v2.z); w1[3] = f2b(v2.w);
      w1[4] = f2b(v3.x); w1[5] = f2b(v3.y); w1[6] = f2b(v3.z); w1[7] = f2b(v3.w);
      *(bf16x8*)&Bs[sr * 72 + sk] = w0;
      *(bf16x8*)&Bs[sr * 72 + sk + 8] = w1;
    }
    __syncthreads();
    #pragma unroll
    for (int ks = 0; ks < 2; ++ks) {
      const int kofs = ks * 32 + k8;
      bf16x8 af0 = *(const bf16x8*)&As[(wm * 32 +  0 + t16) * 72 + kofs];
      bf16x8 af1 = *(const bf16x8*)&As[(wm * 32 + 16 + t16) * 72 + kofs];
      bf16x8 bf0 = *(const bf16x8*)&Bs[(wn * 32 +  0 + t16) * 72 + kofs];
      bf16x8 bf1 = *(const bf16x8*)&Bs[(wn * 32 + 16 + t16) * 72 + kofs];
      acc[0][0] = __builtin_amdgcn_mfma_f32_16x16x32_bf16(af0, bf0, acc[0][0], 0, 0, 0);
      acc[1][0] = __builtin_amdgcn_mfma_f32_16x16x32_bf16(af1, bf0, acc[1][0], 0, 0, 0);
      acc[0][1] = __builtin_amdgcn_mfma_f32_16x16x32_bf16(af0, bf1, acc[0][1], 0, 0, 0);
      acc[1][1] = __builtin_amdgcn_mfma_f32_16x16x32_bf16(af1, bf1, acc[1][1], 0, 0, 0);
    }
    __syncthreads();
  }
  const int r4 = (lane >> 4) * 4;
  #pragma unroll
  for (int ni = 0; ni < 2; ++ni) {
    const int gcol = n0 + wn * 32 + ni * 16 + t16;
    const float bb = bias[gcol];
    #pragma unroll
    for (int mi = 0; mi < 2; ++mi) {
      #pragma unroll
      for (int r = 0; r < 4; ++r) {
        const int gm = m0 + wm * 32 + mi * 16 + r4 + r;
        out[(size_t)gm * N + gcol] = alpha * (acc[mi][ni][r] + bb);
      }
    }
  }
}

// ---------------- merged prep (bid<200) + xf transpose (200<=bid<712) + cen zero (bid>=712) ----------------
// prep: cwb[160][256] bf16 (cw zero-padded), TT[160][320] bf16, wt[tap][1024].
// xf_t: xfT[bt][c][n] bf16 (8 x 256 x 4096), bt = (bid-200)>>6, n0 = ((bid-200)&63)*64.
// cen zero: 300 blocks x 1024 floats = 307200 (replaces hipMemsetAsync dispatch).
__global__ __launch_bounds__(256) void prep_all(
    const float* __restrict__ cw, const float* __restrict__ tdt2, const float* __restrict__ tdt1,
    const float* __restrict__ dww, const float* __restrict__ x, const float* __restrict__ mem,
    short* __restrict__ cwb, short* __restrict__ TT, float* __restrict__ wt,
    short* __restrict__ xfT, float* __restrict__ cen)
{
  if (blockIdx.x < 200) {
    int idx = blockIdx.x * 256 + threadIdx.x;
    if (idx < 160 * 256) {
      int kc = idx >> 8, k = idx & 255;
      float v = (kc < 150) ? cw[kc * 256 + k] : 0.f;
      cwb[idx] = f2b(v);
    }
    if (idx < 160 * 320) {
      int kc = idx / 320, kk = idx - kc * 320;
      float t = 0.f;
      if (kc < 150) {
        if (kk < 150) t = tdt2[kk * 150 + kc];
        else if (kk >= 160 && kk < 310) t = tdt1[(kk - 160) * 150 + kc];
      }
      TT[idx] = f2b(t);
    }
    if (idx < 9216) {
      int ch = idx / 9, tap = idx - ch * 9;
      wt[tap * 1024 + ch] = dww[idx];
    }
  } else if (blockIdx.x < 712) {
    __shared__ float tile[64][257];
    const int bid = blockIdx.x - 200;
    const int bt = bid >> 6;
    const int n0 = (bid & 63) * 64;
    const int b = bt >> 2, ti = bt & 3;
    const float* xf = (ti < 3) ? (mem + (size_t)(b * 3 + ti) * 4096 * 256)
                               : (x + (size_t)b * 4096 * 256);
    const int tid = threadIdx.x;
    const int r = tid >> 2, cofs = (tid & 3) * 64;
    const float* src = xf + (size_t)(n0 + r) * 256 + cofs;
    #pragma unroll
    for (int i = 0; i < 16; ++i) {
      float4 v = *(const float4*)&src[i * 4];
      tile[r][cofs + i * 4 + 0] = v.x;
      tile[r][cofs + i * 4 + 1] = v.y;
      tile[r][cofs + i * 4 + 2] = v.z;
      tile[r][cofs + i * 4 + 3] = v.w;
    }
    __syncthreads();
    short* dst = xfT + ((size_t)bt * 256 + tid) * 4096 + n0;
    #pragma unroll
    for (int seg = 0; seg < 8; ++seg) {
      bf16x8 w;
      #pragma unroll
      for (int j = 0; j < 8; ++j) w[j] = f2b(tile[seg * 8 + j][tid]);
      *(bf16x8*)&dst[seg * 8] = w;
    }
  } else {
    const int idx = (blockIdx.x - 712) * 1024 + threadIdx.x * 4;
    *(float4*)&cen[idx] = make_float4(0.f, 0.f, 0.f, 0.f);
  }
}

// ---------------- fused cluster front-end: cl GEMM + cosines + csz GEMM, LDS-only Acat ----------------
// Block = 64 flat rows (b,ti,nn). Phase A: cl = xf @ cwb^T (+coscl fold) -> Acatile[:,0:160].
// Phase B: z columns in regs (+cosz fold) -> Acatile[:,160:320]. Phase C: O = 0.5*Acatile@TT^T.
__global__ __launch_bounds__(256) void fused_csz(
    const float* __restrict__ x, const float* __restrict__ mem, const float* __restrict__ z,
    const short* __restrict__ cwb, const short* __restrict__ TT,
    const float* __restrict__ p1, const float* __restrict__ p2,
    float* __restrict__ csz, float* __restrict__ asg)
{
  __shared__ __align__(16) short Acatile[64 * 328];
  __shared__ float p1s[160], p2s[160];
  __shared__ float sred[4][16][9];
  __shared__ float czs[64];
  const int tid = threadIdx.x;
  const int r0 = blockIdx.x * 64;
  const int b = r0 >> 14;
  const int mmg = r0 & 16383;
  const int ti = mmg >> 12, nn = mmg & 4095;
  const float* Ab = ((ti < 3) ? (mem + (size_t)(b * 3 + ti) * 4096 * 256)
                              : (x + (size_t)b * 4096 * 256)) + (size_t)nn * 256;
  const int wave = tid >> 6, lane = tid & 63;
  const int t16 = lane & 15, quad = lane >> 4, k8 = quad * 8;

  // ---- z loads into regs first (HBM stream overlaps phase A MFMA) ----
  const int kr = tid >> 4, c4 = (tid & 15) * 4;
  float4 zv[10];
  #pragma unroll
  for (int it = 0; it < 10; ++it) {
    const int k = it * 16 + kr;
    zv[it] = make_float4(0.f, 0.f, 0.f, 0.f);
    if (k < 150) zv[it] = *(const float4*)&z[((size_t)b * 150 + k) * 16384 + mmg + c4];
  }
  if (tid < 160) {
    p2s[tid] = (tid < 150) ? p2[tid] : 0.f;
    p1s[tid] = (tid < 150) ? p1[tid] : 0.f;
  }

  // ---- phase A: cl GEMM (each wave: 16 rows x 160 cols, K=256); unroll 2 = verified config ----
  f32x4 acc[10];
  #pragma unroll
  for (int i = 0; i < 10; ++i) acc[i] = (f32x4){0.f, 0.f, 0.f, 0.f};
  {
    const float* ap = Ab + (size_t)(wave * 16 + t16) * 256 + k8;
    const short* bp = cwb + t16 * 256 + k8;
    #pragma unroll 2
    for (int ks = 0; ks < 8; ++ks) {
      float4 v0 = *(const float4*)&ap[ks * 32];
      float4 v1 = *(const float4*)&ap[ks * 32 + 4];
      bf16x8 a;
      a[0] = f2b(v0.x); a[1] = f2b(v0.y); a[2] = f2b(v0.z); a[3] = f2b(v0.w);
      a[4] = f2b(v1.x); a[5] = f2b(v1.y); a[6] = f2b(v1.z); a[7] = f2b(v1.w);
      #pragma unroll
      for (int nf = 0; nf < 10; ++nf) {
        bf16x8 bv = *(const bf16x8*)&bp[nf * 4096 + ks * 32];
        acc[nf] = __builtin_amdgcn_mfma_f32_16x16x32_bf16(a, bv, acc[nf], 0, 0, 0);
      }
    }
  }
  __syncthreads();   // p1s/p2s visible

  // ---- phase A cosine (per row, over 160 cols; padded cols are exact zeros) ----
  {
    float d[4] = {0.f, 0.f, 0.f, 0.f}, s[4] = {0.f, 0.f, 0.f, 0.f};
    float pn = 0.f;
    #pragma unroll
    for (int nf = 0; nf < 10; ++nf) {
      float a2 = p2s[nf * 16 + t16];
      pn += a2 * a2;
      #pragma unroll
      for (int r = 0; r < 4; ++r) {
        float v = acc[nf][r];
        d[r] = fmaf(v, a2, d[r]);
        s[r] = fmaf(v, v, s[r]);
      }
    }
    #pragma unroll
    for (int off = 1; off < 16; off <<= 1) {
      pn += __shfl_xor(pn, off);
      #pragma unroll
      for (int r = 0; r < 4; ++r) {
        d[r] += __shfl_xor(d[r], off);
        s[r] += __shfl_xor(s[r], off);
      }
    }
    const float spn = fmaxf(sqrtf(pn), 1e-12f);
    float cs[4];
    #pragma unroll
    for (int r = 0; r < 4; ++r) {
      float c = d[r] / (fmaxf(sqrtf(s[r]), 1e-12f) * spn);
      cs[r] = fminf(fmaxf(c, 0.f), 1.f);
    }
    #pragma unroll
    for (int nf = 0; nf < 10; ++nf)
      #pragma unroll
      for (int r = 0; r < 4; ++r)
        Acatile[(wave * 16 + quad * 4 + r) * 328 + nf * 16 + t16] = f2b(acc[nf][r] * cs[r]);
  }

  // ---- phase B: cosz reduce over k, scale, transpose-write cols 160:320 ----
  {
    float d[4] = {0.f, 0.f, 0.f, 0.f}, sv[4] = {0.f, 0.f, 0.f, 0.f};
    float pn = 0.f;
    #pragma unroll
    for (int it = 0; it < 10; ++it) {
      const int k = it * 16 + kr;
      const float a = p1s[k];
      d[0] = fmaf(zv[it].x, a, d[0]); d[1] = fmaf(zv[it].y, a, d[1]);
      d[2] = fmaf(zv[it].z, a, d[2]); d[3] = fmaf(zv[it].w, a, d[3]);
      sv[0] = fmaf(zv[it].x, zv[it].x, sv[0]); sv[1] = fmaf(zv[it].y, zv[it].y, sv[1]);
      sv[2] = fmaf(zv[it].z, zv[it].z, sv[2]); sv[3] = fmaf(zv[it].w, zv[it].w, sv[3]);
      pn = fmaf(a, a, pn);
    }
    #pragma unroll
    for (int off = 16; off < 64; off <<= 1) {
      pn += __shfl_xor(pn, off);
      #pragma unroll
      for (int r = 0; r < 4; ++r) {
        d[r] += __shfl_xor(d[r], off);
        sv[r] += __shfl_xor(sv[r], off);
      }
    }
    if ((lane >> 4) == 0) {
      #pragma unroll
      for (int r = 0; r < 4; ++r) {
        sred[wave][lane][r] = d[r];
        sred[wave][lane][4 + r] = sv[r];
      }
      sred[wave][lane][8] = pn;
    }
  }
  __syncthreads();
  if (tid < 64) {
    const int cg = tid >> 2, r = tid & 3;
    float dd = 0.f, ss = 0.f, pp = 0.f;
    #pragma unroll
    for (int w = 0; w < 4; ++w) {
      dd += sred[w][cg][r];
      ss += sred[w][cg][4 + r];
      pp += sred[w][cg][8];
    }
    float c = dd / (fmaxf(sqrtf(ss), 1e-12f) * fmaxf(sqrtf(pp), 1e-12f));
    czs[tid] = fminf(fmaxf(c, 0.f), 1.f);
  }
  __syncthreads();
  {
    const float cz0 = czs[c4 + 0], cz1 = czs[c4 + 1], cz2 = czs[c4 + 2], cz3 = czs[c4 + 3];
    #pragma unroll
    for (int it = 0; it < 10; ++it) {
      const int k = it * 16 + kr;
      Acatile[(c4 + 0) * 328 + 160 + k] = f2b(zv[it].x * cz0);
      Acatile[(c4 + 1) * 328 + 160 + k] = f2b(zv[it].y * cz1);
      Acatile[(c4 + 2) * 328 + 160 + k] = f2b(zv[it].z * cz2);
      Acatile[(c4 + 3) * 328 + 160 + k] = f2b(zv[it].w * cz3);
    }
  }
  __syncthreads();

  // ---- phase C: O = 0.5 * Acatile @ TT^T  (each wave: 32 rows x 80 cols, K=320) ----
  {
    const int wm = wave & 1, wn = wave >> 1;
    f32x4 c2[2][5];
    #pragma unroll
    for (int i = 0; i < 2; ++i)
      #pragma unroll
      for (int j = 0; j < 5; ++j)
        c2[i][j] = (f32x4){0.f, 0.f, 0.f, 0.f};
    const short* bp = TT + (size_t)(wn * 80 + t16) * 320 + k8;
    #pragma unroll 2
    for (int ks = 0; ks < 10; ++ks) {
      bf16x8 a0 = *(const bf16x8*)&Acatile[(wm * 32 + t16) * 328 + ks * 32 + k8];
      bf16x8 a1 = *(const bf16x8*)&Acatile[(wm * 32 + 16 + t16) * 328 + ks * 32 + k8];
      #pragma unroll
      for (int nf = 0; nf < 5; ++nf) {
        bf16x8 bv = *(const bf16x8*)&bp[nf * 5120 + ks * 32];
        c2[0][nf] = __builtin_amdgcn_mfma_f32_16x16x32_bf16(a0, bv, c2[0][nf], 0, 0, 0);
        c2[1][nf] = __builtin_amdgcn_mfma_f32_16x16x32_bf16(a1, bv, c2[1][nf], 0, 0, 0);
      }
    }
    #pragma unroll
    for (int nf = 0; nf < 5; ++nf) {
      const int kc = wn * 80 + nf * 16 + t16;
      if (kc < 150) {
        #pragma unroll
        for (int mf = 0; mf < 2; ++mf) {
          const int moff = wm * 32 + mf * 16 + quad * 4;
          float4 r4;
          r4.x = 0.5f * c2[mf][nf][0];
          r4.y = 0.5f * c2[mf][nf][1];
          r4.z = 0.5f * c2[mf][nf][2];
          r4.w = 0.5f * c2[mf][nf][3];
          *(float4*)&csz[((size_t)b * 150 + kc) * 16384 + mmg + moff] = r4;
          *(float4*)&asg[(((size_t)b * 4 + ti) * 150 + kc) * 4096 + nn + moff] = r4;
        }
      }
    }
  }
}

// ---------------- softmax stats + exp materialization (bf16) ----------------
// row = bt*150+k; writes ecsz[bt][160pad][4096] bf16 = exp(csz - rowmax); lr = rowsum
__global__ __launch_bounds__(256) void softmax_stats_e(
    const float* __restrict__ csz, float* __restrict__ lr_, short* __restrict__ ecsz)
{
  __shared__ float wred[8];
  const int row = blockIdx.x;
  const int bt = row / 150, k = row - bt * 150;
  const int b = bt >> 2, ti = bt & 3;
  const float* p = csz + ((size_t)b * 150 + k) * 16384 + ti * 4096;
  const int base = threadIdx.x * 16;
  float4 v[4];
  #pragma unroll
  for (int i = 0; i < 4; ++i) v[i] = *(const float4*)&p[base + i * 4];
  float mx = -1e30f;
  #pragma unroll
  for (int i = 0; i < 4; ++i)
    mx = fmaxf(mx, fmaxf(fmaxf(v[i].x, v[i].y), fmaxf(v[i].z, v[i].w)));
  #pragma unroll
  for (int off = 1; off < 64; off <<= 1) mx = fmaxf(mx, __shfl_xor(mx, off));
  const int wave = threadIdx.x >> 6, lane = threadIdx.x & 63;
  if (lane == 0) wred[wave] = mx;
  __syncthreads();
  mx = fmaxf(fmaxf(wred[0], wred[1]), fmaxf(wred[2], wred[3]));
  const float L = 1.4426950408889634f;
  float s = 0.f;
  bf16x8 e0, e1;
  #pragma unroll
  for (int i = 0; i < 2; ++i) {
    float a = exp2f((v[i].x - mx) * L);
    float bq = exp2f((v[i].y - mx) * L);
    float cq = exp2f((v[i].z - mx) * L);
    float dq = exp2f((v[i].w - mx) * L);
    s += a + bq + cq + dq;
    e0[i * 4 + 0] = f2b(a); e0[i * 4 + 1] = f2b(bq); e0[i * 4 + 2] = f2b(cq); e0[i * 4 + 3] = f2b(dq);
  }
  #pragma unroll
  for (int i = 2; i < 4; ++i) {
    float a = exp2f((v[i].x - mx) * L);
    float bq = exp2f((v[i].y - mx) * L);
    float cq = exp2f((v[i].z - mx) * L);
    float dq = exp2f((v[i].w - mx) * L);
    s += a + bq + cq + dq;
    e1[(i - 2) * 4 + 0] = f2b(a); e1[(i - 2) * 4 + 1] = f2b(bq);
    e1[(i - 2) * 4 + 2] = f2b(cq); e1[(i - 2) * 4 + 3] = f2b(dq);
  }
  #pragma unroll
  for (int off = 1; off < 64; off <<= 1) s += __shfl_xor(s, off);
  if (lane == 0) wred[4 + wave] = s;
  __syncthreads();
  short* er = ecsz + ((size_t)bt * 160 + k) * 4096 + base;
  *(bf16x8*)&er[0] = e0;
  *(bf16x8*)&er[8] = e1;
  if (threadIdx.x == 0) lr_[row] = wred[4] + wred[5] + wred[6] + wred[7];
}

// ---------------- cen numerator via MFMA + atomic split-K ----------------
// grid (2 chalf, 8 bt, 32 sp); block 256 = 4 waves; M=160(k) x N=128(c-half) x K=128(n)
__global__ __launch_bounds__(256) void gemm_cen_at(
    const short* __restrict__ ecsz, const short* __restrict__ xfT,
    float* __restrict__ cen)
{
  __shared__ __align__(16) short As[160 * 136];
  const int tid = threadIdx.x;
  const int chalf = blockIdx.x;
  const int bt = blockIdx.y;
  const int sp = blockIdx.z;
  const int n0 = sp * 128;
  const int wave = tid >> 6, lane = tid & 63;
  const int t16 = lane & 15, quad = lane >> 4, k8 = quad * 8;
  const int cbase = chalf * 128 + wave * 32;

  f32x4 acc[10][2];
  #pragma unroll
  for (int i = 0; i < 10; ++i) {
    acc[i][0] = (f32x4){0.f, 0.f, 0.f, 0.f};
    acc[i][1] = (f32x4){0.f, 0.f, 0.f, 0.f};
  }

  const short* erow = ecsz + (size_t)bt * 160 * 4096 + n0;
  // stage A: 160 rows x 128 k-cols (b128 in/out)
  #pragma unroll
  for (int p = 0; p < 10; ++p) {
    const int g = p * 256 + tid;
    const int row = g >> 4;
    const int col8 = (g & 15) * 8;
    *(bf16x8*)&As[row * 136 + col8] = *(const bf16x8*)&erow[(size_t)row * 4096 + col8];
  }
  __syncthreads();
  const short* xrow = xfT + (size_t)bt * 256 * 4096 + n0;
  #pragma unroll
  for (int kc = 0; kc < 4; ++kc) {
    bf16x8 b0 = *(const bf16x8*)&xrow[(size_t)(cbase + t16) * 4096 + kc * 32 + k8];
    bf16x8 b1 = *(const bf16x8*)&xrow[(size_t)(cbase + 16 + t16) * 4096 + kc * 32 + k8];
    #pragma unroll
    for (int mt = 0; mt < 10; ++mt) {
      bf16x8 aA = *(const bf16x8*)&As[(mt * 16 + t16) * 136 + kc * 32 + k8];
      acc[mt][0] = __builtin_amdgcn_mfma_f32_16x16x32_bf16(aA, b0, acc[mt][0], 0, 0, 0);
      acc[mt][1] = __builtin_amdgcn_mfma_f32_16x16x32_bf16(aA, b1, acc[mt][1], 0, 0, 0);
    }
  }
  #pragma unroll
  for (int mt = 0; mt < 10; ++mt) {
    #pragma unroll
    for (int r = 0; r < 4; ++r) {
      const int grow = mt * 16 + quad * 4 + r;
      if (grow < 150) {
        atomicAdd(&cen[((size_t)bt * 150 + grow) * 256 + cbase + t16], acc[mt][0][r]);
        atomicAdd(&cen[((size_t)bt * 150 + grow) * 256 + cbase + 16 + t16], acc[mt][1][r]);
      }
    }
  }
}

// ---------------- similarity gate + LN -> C_in (shuffle-based reductions, 4 barriers) ----------------
__global__ __launch_bounds__(256) void gate_ln(
    const float* __restrict__ cen, const float* __restrict__ lr_,
    const float* __restrict__ alpha_, const float* __restrict__ beta_,
    const float* __restrict__ nw, const float* __restrict__ nb, float* __restrict__ cin)
{
  __shared__ float xw[4][8];
  int bk = blockIdx.x;
  int b = bk / 150, k = bk % 150;
  int c = threadIdx.x;
  const int wave = threadIdx.x >> 6, lane = threadIdx.x & 63;
  const float* base = cen + ((size_t)b * 4 * 150) * 256;
  const float* lrb = lr_ + (size_t)b * 4 * 150;
  float lc  = base[((size_t)3 * 150 + k) * 256 + c] / lrb[3 * 150 + k];
  float p0  = base[((size_t)0 * 150 + k) * 256 + c] / lrb[0 * 150 + k];
  float p1v = base[((size_t)1 * 150 + k) * 256 + c] / lrb[1 * 150 + k];
  float p2v = base[((size_t)2 * 150 + k) * 256 + c] / lrb[2 * 150 + k];
  // 7 simultaneous reductions: nl, q0, q1, q2, d0, d1, d2
  float v0 = lc * lc, v1 = p0 * p0, v2 = p1v * p1v, v3 = p2v * p2v;
  float v4 = lc * p0, v5 = lc * p1v, v6 = lc * p2v;
  #pragma unroll
  for (int off = 1; off < 64; off <<= 1) {
    v0 += __shfl_xor(v0, off); v1 += __shfl_xor(v1, off);
    v2 += __shfl_xor(v2, off); v3 += __shfl_xor(v3, off);
    v4 += __shfl_xor(v4, off); v5 += __shfl_xor(v5, off);
    v6 += __shfl_xor(v6, off);
  }
  if (lane == 0) {
    xw[wave][0] = v0; xw[wave][1] = v1; xw[wave][2] = v2; xw[wave][3] = v3;
    xw[wave][4] = v4; xw[wave][5] = v5; xw[wave][6] = v6;
  }
  __syncthreads();
  float nl = xw[0][0] + xw[1][0] + xw[2][0] + xw[3][0];
  float q0 = xw[0][1] + xw[1][1] + xw[2][1] + xw[3][1];
  float q1 = xw[0][2] + xw[1][2] + xw[2][2] + xw[3][2];
  float q2 = xw[0][3] + xw[1][3] + xw[2][3] + xw[3][3];
  float d0 = xw[0][4] + xw[1][4] + xw[2][4] + xw[3][4];
  float d1 = xw[0][5] + xw[1][5] + xw[2][5] + xw[3][5];
  float d2 = xw[0][6] + xw[1][6] + xw[2][6] + xw[3][6];
  float al = alpha_[0], be = beta_[0];
  float snl = sqrtf(nl);
  float g0 = 1.f / (1.f + expf(-(be + al * (d0 / fmaxf(snl * sqrtf(q0), 1e-8f)))));
  float g1 = 1.f / (1.f + expf(-(be + al * (d1 / fmaxf(snl * sqrtf(q1), 1e-8f)))));
  float g2 = 1.f / (1.f + expf(-(be + al * (d2 / fmaxf(snl * sqrtf(q2), 1e-8f)))));
  float ci = lc + g0 * p0 + g1 * p1v + g2 * p2v;
  // mu/var reduction
  float s = ci, s2 = ci * ci;
  #pragma unroll
  for (int off = 1; off < 64; off <<= 1) {
    s += __shfl_xor(s, off);
    s2 += __shfl_xor(s2, off);
  }
  __syncthreads();   // WAR: all reads of xw done before rewrite
  if (lane == 0) { xw[wave][0] = s; xw[wave][1] = s2; }
  __syncthreads();
  float st  = xw[0][0] + xw[1][0] + xw[2][0] + xw[3][0];
  float st2 = xw[0][1] + xw[1][1] + xw[2][1] + xw[3][1];
  float mu = st * (1.f / 256.f);
  float var = st2 * (1.f / 256.f) - mu * mu;
  cin[(size_t)bk * 256 + c] = (ci - mu) * rsqrtf(var + 1e-5f) * nw[c] + nb[c];
}

// ---------------- merged k/v fp32 GEMM (M=300, N=256, K=256) ----------------
// grid (3, 8): blockIdx.y<4 -> K-proj, else V-proj; n0 = (y&3)*64
__global__ __launch_bounds__(256) void gemm_kv(
    const float* __restrict__ A,
    const float* __restrict__ Wk, const float* __restrict__ bk, float* __restrict__ outk,
    const float* __restrict__ Wv, const float* __restrict__ bv_, float* __restrict__ outv)
{
  __shared__ __align__(16) float As[16][132];
  __shared__ __align__(16) float Ws[16][68];
  const int tid = threadIdx.x;
  const int m0 = blockIdx.x * 128;
  const bool isv = blockIdx.y >= 4;
  const float* W = isv ? Wv : Wk;
  const float* bias = isv ? bv_ : bk;
  float* out = isv ? outv : outk;
  const int n0 = (blockIdx.y & 3) * 64;
  const int M = 300, K = 256;
  const int tm = tid & 15;
  const int tn = tid >> 4;
  float acc[8][4];
  #pragma unroll
  for (int i = 0; i < 8; ++i)
    #pragma unroll
    for (int j = 0; j < 4; ++j) acc[i][j] = 0.f;

  const int lr = tid >> 2;
  const int lk = (tid & 3) * 4;

  for (int k0 = 0; k0 < K; k0 += 16) {
    #pragma unroll
    for (int p = 0; p < 2; ++p) {
      int r = lr + p * 64;
      int gm = m0 + r;
      float4 v = make_float4(0.f, 0.f, 0.f, 0.f);
      if (gm < M) v = *(const float4*)&A[(size_t)gm * K + k0 + lk];
      As[lk + 0][r] = v.x; As[lk + 1][r] = v.y; As[lk + 2][r] = v.z; As[lk + 3][r] = v.w;
    }
    {
      float4 v = *(const float4*)&W[(size_t)(n0 + lr) * K + k0 + lk];
      Ws[lk + 0][lr] = v.x; Ws[lk + 1][lr] = v.y; Ws[lk + 2][lr] = v.z; Ws[lk + 3][lr] = v.w;
    }
    __syncthreads();
    #pragma unroll
    for (int kk = 0; kk < 16; ++kk) {
      float4 a0 = *(const float4*)&As[kk][tm * 8];
      float4 a1 = *(const float4*)&As[kk][tm * 8 + 4];
      float4 w0 = *(const float4*)&Ws[kk][tn * 4];
      float av[8] = {a0.x, a0.y, a0.z, a0.w, a1.x, a1.y, a1.z, a1.w};
      float wv[4] = {w0.x, w0.y, w0.z, w0.w};
      #pragma unroll
      for (int i = 0; i < 8; ++i)
        #pragma unroll
        for (int j = 0; j < 4; ++j)
          acc[i][j] = fmaf(av[i], wv[j], acc[i][j]);
    }
    __syncthreads();
  }
  float4 bv4 = *(const float4*)&bias[n0 + tn * 4];
  float bb[4] = {bv4.x, bv4.y, bv4.z, bv4.w};
  #pragma unroll
  for (int i = 0; i < 8; ++i) {
    int gm = m0 + tm * 8 + i;
    if (gm >= M) continue;
    float4 r;
    r.x = acc[i][0] + bb[0];
    r.y = acc[i][1] + bb[1];
    r.z = acc[i][2] + bb[2];
    r.w = acc[i][3] + bb[3];
    *(float4*)&out[(size_t)gm * 256 + n0 + tn * 4] = r;
  }
}

// ---------------- MFMA attention: 128 Q-rows/block, per (b,h); q bf16 in, o bf16 out ----------------
__global__ __launch_bounds__(256) void attn_mfma(
    const short* __restrict__ q, const float* __restrict__ ks, const float* __restrict__ vs,
    short* __restrict__ o)
{
  __shared__ __align__(16) short Ps[128 * 168];
  __shared__ __align__(16) short VT[32 * 168];
  __shared__ float lrow[128];
  const int tid = threadIdx.x;
  const int bid = blockIdx.x;
  const int ntile = bid & 31;
  const int bh = bid >> 5;
  const int b = bh >> 3, h = bh & 7;
  const int n0 = ntile * 128;
  const int wave = tid >> 6, lane = tid & 63;
  const int t16 = lane & 15, quad = lane >> 4;
  const int k8 = quad * 8;
  const int wr = wave * 32;

  for (int i = tid; i < 5120; i += 256) {
    int d = i / 160, kc = i - d * 160;
    VT[d * 168 + kc] = (kc < 150) ? f2b(vs[((size_t)b * 150 + kc) * 256 + h * 32 + d]) : (short)0;
  }

  bf16x8 aQ[2];
  #pragma unroll
  for (int mt = 0; mt < 2; ++mt)
    aQ[mt] = *(const bf16x8*)&q[((size_t)b * 4096 + n0 + wr + mt * 16 + t16) * 256 + h * 32 + k8];

  f32x4 s[2][10];
  #pragma unroll
  for (int ct = 0; ct < 10; ++ct) {
    const int c = ct * 16 + t16;
    bf16x8 bK = {0, 0, 0, 0, 0, 0, 0, 0};
    if (c < 150) {
      const float* kp = &ks[((size_t)b * 150 + c) * 256 + h * 32 + k8];
      float4 v0 = *(const float4*)&kp[0];
      float4 v1 = *(const float4*)&kp[4];
      bK[0] = f2b(v0.x); bK[1] = f2b(v0.y); bK[2] = f2b(v0.z); bK[3] = f2b(v0.w);
      bK[4] = f2b(v1.x); bK[5] = f2b(v1.y); bK[6] = f2b(v1.z); bK[7] = f2b(v1.w);
    }
    f32x4 zero = (f32x4){0.f, 0.f, 0.f, 0.f};
    s[0][ct] = __builtin_amdgcn_mfma_f32_16x16x32_bf16(aQ[0], bK, zero, 0, 0, 0);
    s[1][ct] = __builtin_amdgcn_mfma_f32_16x16x32_bf16(aQ[1], bK, zero, 0, 0, 0);
  }

  #pragma unroll
  for (int mt = 0; mt < 2; ++mt) {
    #pragma unroll
    for (int r = 0; r < 4; ++r) {
      float mx = -1e30f;
      #pragma unroll
      for (int ct = 0; ct < 10; ++ct) {
        float v = s[mt][ct][r];
        if (ct == 9 && t16 >= 6) { v = -1e30f; s[mt][ct][r] = v; }
        mx = fmaxf(mx, v);
      }
      mx = fmaxf(mx, __shfl_xor(mx, 1));
      mx = fmaxf(mx, __shfl_xor(mx, 2));
      mx = fmaxf(mx, __shfl_xor(mx, 4));
      mx = fmaxf(mx, __shfl_xor(mx, 8));
      float ls = 0.f;
      #pragma unroll
      for (int ct = 0; ct < 10; ++ct) {
        float e = expf(s[mt][ct][r] - mx);
        s[mt][ct][r] = e;
        ls += e;
      }
      ls += __shfl_xor(ls, 1);
      ls += __shfl_xor(ls, 2);
      ls += __shfl_xor(ls, 4);
      ls += __shfl_xor(ls, 8);
      if (t16 == 0) lrow[wr + mt * 16 + quad * 4 + r] = 1.f / ls;
      #pragma unroll
      for (int ct = 0; ct < 10; ++ct)
        Ps[(wr + mt * 16 + quad * 4 + r) * 168 + ct * 16 + t16] = f2b(s[mt][ct][r]);
    }
  }
  __syncthreads();

  f32x4 oacc[2][2];
  #pragma unroll
  for (int i = 0; i < 2; ++i)
    #pragma unroll
    for (int j = 0; j < 2; ++j)
      oacc[i][j] = (f32x4){0.f, 0.f, 0.f, 0.f};
  #pragma unroll
  for (int kstep = 0; kstep < 5; ++kstep) {
    bf16x8 bV0 = *(const bf16x8*)&VT[( 0 + t16) * 168 + kstep * 32 + k8];
    bf16x8 bV1 = *(const bf16x8*)&VT[(16 + t16) * 168 + kstep * 32 + k8];
    #pragma unroll
    for (int mt = 0; mt < 2; ++mt) {
      bf16x8 aP = *(const bf16x8*)&Ps[(wr + mt * 16 + t16) * 168 + kstep * 32 + k8];
      oacc[mt][0] = __builtin_amdgcn_mfma_f32_16x16x32_bf16(aP, bV0, oacc[mt][0], 0, 0, 0);
      oacc[mt][1] = __builtin_amdgcn_mfma_f32_16x16x32_bf16(aP, bV1, oacc[mt][1], 0, 0, 0);
    }
  }
  #pragma unroll
  for (int mt = 0; mt < 2; ++mt) {
    #pragma unroll
    for (int nt = 0; nt < 2; ++nt) {
      const int d = nt * 16 + t16;
      #pragma unroll
      for (int r = 0; r < 4; ++r) {
        const int row = wr + mt * 16 + quad * 4 + r;
        o[((size_t)b * 4096 + n0 + row) * 256 + h * 32 + d] = f2b(oacc[mt][nt][r] * lrow[row]);
      }
    }
  }
}

// ---------------- dst = res + LN(src), wave-per-row (row=256 cols) ----------------
__global__ __launch_bounds__(256) void ln_res(
    const float* __restrict__ src, const float* __restrict__ res,
    const float* __restrict__ nw, const float* __restrict__ nb, float* __restrict__ dst)
{
  const int wave = threadIdx.x >> 6;
  const int lane = threadIdx.x & 63;
  const size_t row = (size_t)blockIdx.x * 4 + wave;
  const int c = lane * 4;
  float4 v = *(const float4*)&src[row * 256 + c];
  float s  = v.x + v.y + v.z + v.w;
  float s2 = v.x * v.x + v.y * v.y + v.z * v.z + v.w * v.w;
  #pragma unroll
  for (int off = 1; off < 64; off <<= 1) {
    s  += __shfl_xor(s, off);
    s2 += __shfl_xor(s2, off);
  }
  const float mu = s * (1.f / 256.f);
  const float var = s2 * (1.f / 256.f) - mu * mu;
  const float inv = rsqrtf(var + 1e-5f);
  float4 w = *(const float4*)&nw[c];
  float4 bb = *(const float4*)&nb[c];
  float4 rr = *(const float4*)&res[row * 256 + c];
  float4 d;
  d.x = rr.x + (v.x - mu) * inv * w.x + bb.x;
  d.y = rr.y + (v.y - mu) * inv * w.y + bb.y;
  d.z = rr.z + (v.z - mu) * inv * w.z + bb.z;
  d.w = rr.w + (v.w - mu) * inv * w.w + bb.w;
  *(float4*)&dst[row * 256 + c] = d;
}

// ---------------- dual-output ln_res: fp32 dst + bf16 dstb (for fc1's bfA path) ----------------
__global__ __launch_bounds__(256) void ln_res_dual(
    const float* __restrict__ src, const float* __restrict__ res,
    const float* __restrict__ nw, const float* __restrict__ nb,
    float* __restrict__ dst, short* __restrict__ dstb)
{
  const int wave = threadIdx.x >> 6;
  const int lane = threadIdx.x & 63;
  const size_t row = (size_t)blockIdx.x * 4 + wave;
  const int c = lane * 4;
  float4 v = *(const float4*)&src[row * 256 + c];
  float s  = v.x + v.y + v.z + v.w;
  float s2 = v.x * v.x + v.y * v.y + v.z * v.z + v.w * v.w;
  #pragma unroll
  for (int off = 1; off < 64; off <<= 1) {
    s  += __shfl_xor(s, off);
    s2 += __shfl_xor(s2, off);
  }
  const float mu = s * (1.f / 256.f);
  const float var = s2 * (1.f / 256.f) - mu * mu;
  const float inv = rsqrtf(var + 1e-5f);
  float4 w = *(const float4*)&nw[c];
  float4 bb = *(const float4*)&nb[c];
  float4 rr = *(const float4*)&res[row * 256 + c];
  float4 d;
  d.x = rr.x + (v.x - mu) * inv * w.x + bb.x;
  d.y = rr.y + (v.y - mu) * inv * w.y + bb.y;
  d.z = rr.z + (v.z - mu) * inv * w.z + bb.z;
  d.w = rr.w + (v.w - mu) * inv * w.w + bb.w;
  *(float4*)&dst[row * 256 + c] = d;
  bf16x4 db;
  db[0] = f2b(d.x); db[1] = f2b(d.y); db[2] = f2b(d.z); db[3] = f2b(d.w);
  *(bf16x4*)&dstb[row * 256 + c] = db;
}

// ---------------- depthwise 3x3 conv + bias + exact gelu, 4 pixels/block, bf16 out ----------------
// grid 2048 = b(2) x y(64) x xg(16); each block does pixels (y, 4*xg .. 4*xg+3),
// 256 threads x 4 channels. 3x6 tap window shared across the 4 outputs.
__global__ __launch_bounds__(256) void conv_gelu(
    const float* __restrict__ h, const float* __restrict__ wt, const float* __restrict__ bias,
    short* __restrict__ hc)
{
  const int bid = blockIdx.x;
  const int xg = bid & 15;
  const int y  = (bid >> 4) & 63;
  const int b  = bid >> 10;
  const int x0 = xg * 4;
  const int c4 = threadIdx.x * 4;
  const float* hb = h + ((size_t)b * 4096) * 1024 + c4;

  float4 tap[3][6];
  #pragma unroll
  for (int dy = 0; dy < 3; ++dy) {
    const int yy = y + dy - 1;
    #pragma unroll
    for (int dx = 0; dx < 6; ++dx) {
      const int xv = x0 + dx - 1;
      tap[dy][dx] = make_float4(0.f, 0.f, 0.f, 0.f);
      if (yy >= 0 && yy <= 63 && xv >= 0 && xv <= 63)
        tap[dy][dx] = *(const float4*)&hb[(size_t)(yy * 64 + xv) * 1024];
    }
  }
  float4 wv[3][3];
  #pragma unroll
  for (int dy = 0; dy < 3; ++dy)
    #pragma unroll
    for (int dx = 0; dx < 3; ++dx)
      wv[dy][dx] = *(const float4*)&wt[(dy * 3 + dx) * 1024 + c4];
  const float4 bv = *(const float4*)&bias[c4];

  #pragma unroll
  for (int p = 0; p < 4; ++p) {
    float4 acc = bv;
    #pragma unroll
    for (int dy = 0; dy < 3; ++dy) {
      #pragma unroll
      for (int dx = 0; dx < 3; ++dx) {
        const float4 hv = tap[dy][p + dx];
        const float4 w = wv[dy][dx];
        acc.x = fmaf(hv.x, w.x, acc.x);
        acc.y = fmaf(hv.y, w.y, acc.y);
        acc.z = fmaf(hv.z, w.z, acc.z);
        acc.w = fmaf(hv.w, w.w, acc.w);
      }
    }
    bf16x4 g;
    g[0] = f2b(0.5f * acc.x * (1.f + erff(acc.x * 0.70710678118654752f)));
    g[1] = f2b(0.5f * acc.y * (1.f + erff(acc.y * 0.70710678118654752f)));
    g[2] = f2b(0.5f * acc.z * (1.f + erff(acc.z * 0.70710678118654752f)));
    g[3] = f2b(0.5f * acc.w * (1.f + erff(acc.w * 0.70710678118654752f)));
    *(bf16x4*)&hc[((size_t)b * 4096 + y * 64 + x0 + p) * 1024 + c4] = g;
  }
}

extern "C" void kernel_launch(void* const* d_in, const int* in_sizes, int n_in,
                              void* d_out, int out_size, void* d_ws, size_t ws_size,
                              hipStream_t stream)
{
  (void)in_sizes; (void)n_in; (void)out_size; (void)ws_size;
  const float* x    = (const float*)d_in[0];
  const float* z    = (const float*)d_in[1];
  const float* mem  = (const float*)d_in[2];
  const float* cw   = (const float*)d_in[3];
  const float* p1   = (const float*)d_in[4];
  const float* tdt1 = (const float*)d_in[5];
  const float* p2   = (const float*)d_in[6];
  const float* tdt2 = (const float*)d_in[7];
  const float* sal  = (const float*)d_in[8];
  const float* sbe  = (const float*)d_in[9];
  const float* q_w  = (const float*)d_in[10];
  const float* q_b  = (const float*)d_in[11];
  const float* k_w  = (const float*)d_in[12];
  const float* k_b  = (const float*)d_in[13];
  const float* v_w  = (const float*)d_in[14];
  const float* v_b  = (const float*)d_in[15];
  const float* pj_w = (const float*)d_in[16];
  const float* pj_b = (const float*)d_in[17];
  const float* nw   = (const float*)d_in[18];
  const float* nb   = (const float*)d_in[19];
  const float* f1w  = (const float*)d_in[20];
  const float* f1b  = (const float*)d_in[21];
  const float* dww  = (const float*)d_in[22];
  const float* dwb  = (const float*)d_in[23];
  const float* f2w  = (const float*)d_in[24];
  const float* f2b_ = (const float*)d_in[25];

  float* out = (float*)d_out;                  // (2,4096,256)
  float* csz = out + 2097152;                  // (2,150,16384)
  float* asg = csz + 4915200;                  // (2,4,150,4096)

  float* ws    = (float*)d_ws;
  short* ecsz  = (short*)ws;         // 5,242,880 shorts, written by softmax step
  short* TT    = (short*)(ws + 5242880);   // 160x320 bf16 = 25,600 float-slots
  short* cwb   = (short*)(ws + 5275648);   // 160x256 bf16 = 20,480 float-slots
  float* lr_   = ws + 5308416;       // 1,200
  float* cen   = ws + 5310816;       // 307,200
  float* cin   = ws + 5618016;       // 76,800
  short* q     = (short*)(ws + 5694816);   // 8192x256 bf16 = 1,048,576 float-slots
  float* ksb   = ws + 7791968;       // 76,800
  float* vsb   = ws + 7868768;       // 76,800
  short* o     = (short*)(ws + 7945568);   // 8192x256 bf16 (ends 8,994,144)
  short* xfT   = (short*)(ws + 10042720);  // 8x256x4096 bf16 = 4,194,304 float-slots (ends 14,237,024; dead after cen)
  float* h     = ws;                 // 8,388,608 reuse (ecsz/TT/cwb/q dead by fc1)
  short* hc    = (short*)(ws + 8388608);   // 8,388,608 shorts = 4,194,304 float-slots
  short* out1b = (short*)(ws + 14237024);  // 8192x256 bf16 = 1,048,576 float-slots (ends 15,285,600; xfT dead)
  float* tmp   = ws + 16777216;
  float* out1  = ws + 18874368;
  float* wt    = ws + 20971520;      // 9,216

  dim3 blk(256);
  // 1. merged weight packs (cwb/TT/wt) + xf bf16 transpose + cen zero — one launch
  prep_all<<<dim3(1012), blk, 0, stream>>>(cw, tdt2, tdt1, dww, x, mem, cwb, TT, wt, xfT, cen);
  // 2. fused cluster front-end: cl GEMM + cosines + csz GEMM (unroll-2 phase A — verified config)
  fused_csz<<<dim3(512), blk, 0, stream>>>(x, mem, z, cwb, TT, p1, p2, csz, asg);
  // 3. softmax stats + exp(csz-m) materialized bf16
  softmax_stats_e<<<dim3(1200), blk, 0, stream>>>(csz, lr_, ecsz);
  // 4. cen numerators via MFMA + atomics (cen zeroed in prep_all)
  gemm_cen_at<<<dim3(2, 8, 32), blk, 0, stream>>>(ecsz, xfT, cen);
  // 5. gate + LN -> C_in (shuffle-based reductions)
  gate_ln<<<dim3(300), blk, 0, stream>>>(cen, lr_, sal, sbe, nw, nb, cin);
  // 6. q (MFMA, bf16 out) + merged k/v (one launch)
  gemm_mfma_bfout<<<dim3(128, 4), blk, 0, stream>>>(x, q_w, q_b, q, 8192, 256, 256, 0.17677669529663687f);
  gemm_kv<<<dim3(3, 8), blk, 0, stream>>>(cin, k_w, k_b, ksb, v_w, v_b, vsb);
  // 7. attention [MFMA]; o bf16
  attn_mfma<<<dim3(512), blk, 0, stream>>>(q, ksb, vsb, o);
  // 8. proj (bf16 A) + LN + residual (dual out: fp32 for residual, bf16 for fc1 A)
  gemm_mfma_bfA<<<dim3(128, 4), blk, 0, stream>>>(o, pj_w, pj_b, tmp, 8192, 256, 256, 1.f);
  ln_res_dual<<<dim3(2048), blk, 0, stream>>>(tmp, x, nw, nb, out1, out1b);
  // 9. MLP (fc1 consumes bf16 out1b — same f2b rounding, applied once instead of 16x)
  gemm_mfma_bfA<<<dim3(128, 16), blk, 0, stream>>>(out1b, f1w, f1b, h, 8192, 1024, 256, 1.f);
  conv_gelu<<<dim3(2048), blk, 0, stream>>>(h, wt, dwb, hc);
  gemm_mfma_bfA<<<dim3(128, 4), blk, 0, stream>>>(hc, f2w, f2b_, tmp, 8192, 256, 1024, 1.f);
  ln_res<<<dim3(2048), blk, 0, stream>>>(tmp, out1, nw, nb, out);
}